// Round 3
// baseline (693.347 us; speedup 1.0000x reference)
//
#include <hip/hip_runtime.h>
#include <cstdint>
#include <cstddef>

typedef __bf16 bf16_t;
typedef __bf16 bf16x8 __attribute__((ext_vector_type(8)));
typedef __bf16 bf16x4 __attribute__((ext_vector_type(4)));
typedef float f32x4 __attribute__((ext_vector_type(4)));

#define MFMA16(a, b, c) __builtin_amdgcn_mfma_f32_16x16x32_bf16(a, b, c, 0, 0, 0)

// async global->LDS, 16B per lane. LDS dest = wave-uniform base + lane*16.
__device__ __forceinline__ void gll16(const bf16_t* g, bf16_t* l) {
  __builtin_amdgcn_global_load_lds(
      (__attribute__((address_space(1))) uint32_t*)((uintptr_t)g),
      (__attribute__((address_space(3))) uint32_t*)((uint32_t)(uintptr_t)l),
      16, 0, 0);
}

// Diagnostic: absmax ~1000 => ws_size too small.
__global__ void fill_diag(uint32_t* out, int n_u32) {
  int i = blockIdx.x * 256 + threadIdx.x;
  if (i < n_u32) out[i] = 0x447A0000u;  // f32 1000.0
}

// ---------------------------------------------------------------------------
// f32 -> bf16 vector convert (x, cos/sin tables). One bf16x8 per thread.
// ---------------------------------------------------------------------------
__global__ void conv_vec_f32(const float* __restrict__ in, bf16_t* __restrict__ out,
                             int n8) {
  const int i = blockIdx.x * 256 + threadIdx.x;
  if (i >= n8) return;
  const float* p = in + (size_t)i * 8;
  const f32x4 a = *(const f32x4*)p;
  const f32x4 b = *(const f32x4*)(p + 4);
  bf16x8 o;
#pragma unroll
  for (int j = 0; j < 4; ++j) {
    o[j] = (bf16_t)a[j];
    o[4 + j] = (bf16_t)b[j];
  }
  ((bf16x8*)out)[i] = o;
}

// ---------------------------------------------------------------------------
// 64x64 tiled transpose+convert: in R x C f32 -> out C x R bf16.
// ---------------------------------------------------------------------------
__global__ __launch_bounds__(256) void conv_transpose_f32(
    const float* __restrict__ in, bf16_t* __restrict__ out, int R, int C) {
  __shared__ bf16_t tile[64][72];
  const int bc = blockIdx.x * 64;
  const int br = blockIdx.y * 64;
  const int t = threadIdx.x;
  const int r = t >> 3;
  const int c8 = (t & 7) * 8;
#pragma unroll
  for (int ii = 0; ii < 2; ++ii) {
    const int rr = r + ii * 32;
    const float* p = in + (size_t)(br + rr) * C + bc + c8;
    const f32x4 a = *(const f32x4*)p;
    const f32x4 b = *(const f32x4*)(p + 4);
    bf16x8 v;
#pragma unroll
    for (int j = 0; j < 4; ++j) {
      v[j] = (bf16_t)a[j];
      v[4 + j] = (bf16_t)b[j];
    }
    *(bf16x8*)(&tile[rr][c8]) = v;
  }
  __syncthreads();
#pragma unroll
  for (int ii = 0; ii < 2; ++ii) {
    const int rr = r + ii * 32;
    bf16x8 o;
#pragma unroll
    for (int jj = 0; jj < 8; ++jj) o[jj] = tile[c8 + jj][rr];
    *(bf16x8*)(out + (size_t)(bc + rr) * R + br + c8) = o;
  }
}

// ---------------------------------------------------------------------------
// 256x256 8-phase GEMM (HK-style template, plain HIP). See round-0 notes.
// ---------------------------------------------------------------------------
#define MF8(MLO, AARR, BARR, NLO)                                           \
  do {                                                                      \
    _Pragma("unroll") for (int m_ = 0; m_ < 4; ++m_) {                      \
      _Pragma("unroll") for (int n_ = 0; n_ < 2; ++n_) {                    \
        acc[(MLO) + m_][(NLO) + n_] =                                       \
            MFMA16(AARR[m_][0], BARR[n_][0], acc[(MLO) + m_][(NLO) + n_]);  \
        acc[(MLO) + m_][(NLO) + n_] =                                       \
            MFMA16(AARR[m_][1], BARR[n_][1], acc[(MLO) + m_][(NLO) + n_]);  \
      }                                                                     \
    }                                                                       \
  } while (0)

template <bool C32>
__global__ __launch_bounds__(512, 2) void gemm8(
    const bf16_t* __restrict__ A, const bf16_t* __restrict__ Bt,
    void* __restrict__ C, int M, int N, int K, int nbn) {
  __shared__ __align__(1024) bf16_t lds8[65536];  // A: [0,32768), B: [32768,65536)
  bf16_t* As = lds8;
  bf16_t* Bs = lds8 + 32768;

  const int tid = threadIdx.x;
  const int lane = tid & 63;
  const int wave = tid >> 6;
  const int wr = wave >> 2;  // 0..1 (M half)
  const int wc = wave & 3;   // 0..3 (N quarter)
  const int fr = lane & 15;
  const int fg = lane >> 4;

  // XCD-aware bijective swizzle (nwg % 8 == 0 by construction).
  const int nwg = gridDim.x;
  const int bid = blockIdx.x;
  const int swz = (bid & 7) * (nwg >> 3) + (bid >> 3);
  const int m0 = (swz / nbn) * 256;
  const int n0 = (swz % nbn) * 256;

  const int NT = K >> 6;  // BK=64 tiles (assumed even; K=2048 -> 32)

  // staging geometry: wave covers segs {2w, 2w+1}; seg = 8 rows of 128B.
  const int sseg0 = wave * 2;
  const int srow = lane >> 3;
  const int sj = lane & 7;

  auto stage = [&](const bf16_t* __restrict__ G, int row0, bf16_t* L, int kt,
                   int h) {
#pragma unroll
    for (int l = 0; l < 2; ++l) {
      const int seg = sseg0 + l;
      const int r = seg * 8 + srow;       // row in half-tile 0..127
      const int j = sj ^ (r & 7);         // inverse-swizzled source chunk
      const bf16_t* src = G + (size_t)(row0 + h * 128 + r) * K + kt * 64 + j * 8;
      gll16(src, L + ((2 * kt + h) & 3) * 8192 + seg * 512 + lane * 8);
    }
  };

  const int cb0 = (fg * 16) ^ ((fr & 7) << 4);  // kk=0 byte col (swizzled)

  auto lda = [&](bf16x8(&af)[4][2], int kt, int mlo) {
    const char* base = (const char*)(As + ((2 * kt + wr) & 3) * 8192);
#pragma unroll
    for (int m = 0; m < 4; ++m) {
      const char* p = base + ((mlo + m) * 16 + fr) * 128;
      af[m][0] = *(const bf16x8*)(p + cb0);
      af[m][1] = *(const bf16x8*)(p + (cb0 ^ 64));
    }
  };
  auto ldb = [&](bf16x8(&bf)[2][2], int kt, int nlo) {
    const char* base = (const char*)(Bs + ((2 * kt + (wc >> 1)) & 3) * 8192);
#pragma unroll
    for (int n = 0; n < 2; ++n) {
      const char* p = base + ((wc & 1) * 64 + (nlo + n) * 16 + fr) * 128;
      bf[n][0] = *(const bf16x8*)(p + cb0);
      bf[n][1] = *(const bf16x8*)(p + (cb0 ^ 64));
    }
  };

  f32x4 acc[8][4] = {};

  // Prologue: A(0), B(0), B(1); drain A(0)+B(0), keep B(1) in flight.
  stage(A, m0, As, 0, 0);
  stage(A, m0, As, 0, 1);
  stage(Bt, n0, Bs, 0, 0);
  stage(Bt, n0, Bs, 0, 1);
  stage(Bt, n0, Bs, 1, 0);
  stage(Bt, n0, Bs, 1, 1);
  asm volatile("s_waitcnt vmcnt(4)" ::: "memory");
  __builtin_amdgcn_s_barrier();

  bf16x8 af[4][2], bfA[2][2], bfB[2][2];

  for (int u = 0; u < NT; u += 2) {
    const bool st2 = (u + 2 < NT);
    const bool st3 = (u + 3 < NT);
    // ---------------- tile u ----------------
    lda(af, u, 0);
    ldb(bfA, u, 0);
    stage(A, m0, As, u + 1, 0);
    asm volatile("s_waitcnt lgkmcnt(8)" ::: "memory");
    __builtin_amdgcn_s_barrier();
    asm volatile("s_waitcnt lgkmcnt(0)" ::: "memory");
    __builtin_amdgcn_sched_barrier(0);
    __builtin_amdgcn_s_setprio(1);
    MF8(0, af, bfA, 0);
    __builtin_amdgcn_s_setprio(0);
    __builtin_amdgcn_s_barrier();
    ldb(bfB, u, 2);
    stage(A, m0, As, u + 1, 1);
    __builtin_amdgcn_s_barrier();
    asm volatile("s_waitcnt lgkmcnt(0)" ::: "memory");
    __builtin_amdgcn_sched_barrier(0);
    __builtin_amdgcn_s_setprio(1);
    MF8(0, af, bfB, 2);
    __builtin_amdgcn_s_setprio(0);
    __builtin_amdgcn_s_barrier();
    lda(af, u, 4);
    if (st2) stage(Bt, n0, Bs, u + 2, 0);
    __builtin_amdgcn_s_barrier();
    asm volatile("s_waitcnt lgkmcnt(0)" ::: "memory");
    __builtin_amdgcn_sched_barrier(0);
    __builtin_amdgcn_s_setprio(1);
    MF8(4, af, bfB, 2);
    __builtin_amdgcn_s_setprio(0);
    __builtin_amdgcn_s_barrier();
    if (st2) stage(Bt, n0, Bs, u + 2, 1);
    __builtin_amdgcn_s_barrier();
    __builtin_amdgcn_s_setprio(1);
    MF8(4, af, bfA, 0);
    __builtin_amdgcn_s_setprio(0);
    asm volatile("s_waitcnt vmcnt(4)" ::: "memory");
    __builtin_amdgcn_s_barrier();
    // ---------------- tile u+1 ----------------
    lda(af, u + 1, 0);
    ldb(bfA, u + 1, 0);
    if (st2) stage(A, m0, As, u + 2, 0);
    asm volatile("s_waitcnt lgkmcnt(8)" ::: "memory");
    __builtin_amdgcn_s_barrier();
    asm volatile("s_waitcnt lgkmcnt(0)" ::: "memory");
    __builtin_amdgcn_sched_barrier(0);
    __builtin_amdgcn_s_setprio(1);
    MF8(0, af, bfA, 0);
    __builtin_amdgcn_s_setprio(0);
    __builtin_amdgcn_s_barrier();
    ldb(bfB, u + 1, 2);
    if (st2) stage(A, m0, As, u + 2, 1);
    __builtin_amdgcn_s_barrier();
    asm volatile("s_waitcnt lgkmcnt(0)" ::: "memory");
    __builtin_amdgcn_sched_barrier(0);
    __builtin_amdgcn_s_setprio(1);
    MF8(0, af, bfB, 2);
    __builtin_amdgcn_s_setprio(0);
    __builtin_amdgcn_s_barrier();
    lda(af, u + 1, 4);
    if (st3) stage(Bt, n0, Bs, u + 3, 0);
    __builtin_amdgcn_s_barrier();
    asm volatile("s_waitcnt lgkmcnt(0)" ::: "memory");
    __builtin_amdgcn_sched_barrier(0);
    __builtin_amdgcn_s_setprio(1);
    MF8(4, af, bfB, 2);
    __builtin_amdgcn_s_setprio(0);
    __builtin_amdgcn_s_barrier();
    if (st3) stage(Bt, n0, Bs, u + 3, 1);
    __builtin_amdgcn_s_barrier();
    __builtin_amdgcn_s_setprio(1);
    MF8(4, af, bfA, 0);
    __builtin_amdgcn_s_setprio(0);
    asm volatile("s_waitcnt vmcnt(4)" ::: "memory");
    __builtin_amdgcn_s_barrier();
  }

#pragma unroll
  for (int m = 0; m < 8; ++m) {
#pragma unroll
    for (int n = 0; n < 4; ++n) {
#pragma unroll
      for (int r = 0; r < 4; ++r) {
        const int row = m0 + wr * 128 + m * 16 + fg * 4 + r;
        const int col = n0 + wc * 64 + n * 16 + fr;
        const size_t idx = (size_t)row * N + col;
        if (C32)
          ((float*)C)[idx] = acc[m][n][r];
        else
          ((bf16_t*)C)[idx] = (bf16_t)acc[m][n][r];
      }
    }
  }
  (void)M;
}

// ---------------------------------------------------------------------------
// m97-style GEMM: kept for proj GEMM (N=2048 -> 256^2 grid only 128 blocks).
// ---------------------------------------------------------------------------
template <bool C32>
__global__ __launch_bounds__(256) void gemm_lds(
    const bf16_t* __restrict__ A, const bf16_t* __restrict__ Bt,
    void* __restrict__ C, int M, int N, int K) {
  __shared__ __align__(16) bf16_t As[128 * 32];
  __shared__ __align__(16) bf16_t Bs[128 * 32];
  const int tid = threadIdx.x;
  const int lane = tid & 63;
  const int wave = tid >> 6;
  const int m0 = blockIdx.x * 128;
  const int n0 = blockIdx.y * 128;
  const int wm = (wave & 1) * 64;
  const int wn = (wave >> 1) * 64;
  const int fr = lane & 15;
  const int fk = (lane >> 4) * 8;

  f32x4 acc[4][4] = {};

  const bf16_t* ga = A + (size_t)(m0 + (tid >> 2)) * K + (tid & 3) * 8;
  const bf16_t* gb = Bt + (size_t)(n0 + (tid >> 2)) * K + (tid & 3) * 8;
  bf16_t* lA = As + tid * 8;
  bf16_t* lB = Bs + tid * 8;
  const size_t half = (size_t)64 * K;

  for (int k0 = 0; k0 < K; k0 += 32) {
    __syncthreads();
    gll16(ga, lA);
    gll16(ga + half, lA + 2048);
    gll16(gb, lB);
    gll16(gb + half, lB + 2048);
    ga += 32;
    gb += 32;
    __syncthreads();
    bf16x8 af[4], bfr[4];
#pragma unroll
    for (int i = 0; i < 4; ++i)
      af[i] = *(const bf16x8*)(As + (wm + i * 16 + fr) * 32 + fk);
#pragma unroll
    for (int j = 0; j < 4; ++j)
      bfr[j] = *(const bf16x8*)(Bs + (wn + j * 16 + fr) * 32 + fk);
#pragma unroll
    for (int i = 0; i < 4; ++i)
#pragma unroll
      for (int j = 0; j < 4; ++j)
        acc[i][j] = MFMA16(af[i], bfr[j], acc[i][j]);
  }

  const int fg = lane >> 4;
#pragma unroll
  for (int i = 0; i < 4; ++i) {
#pragma unroll
    for (int j = 0; j < 4; ++j) {
#pragma unroll
      for (int r = 0; r < 4; ++r) {
        const int row = m0 + wm + i * 16 + fg * 4 + r;
        const int col = n0 + wn + j * 16 + fr;
        const size_t idx = (size_t)row * N + col;
        if (C32)
          ((float*)C)[idx] = acc[i][j][r];
        else
          ((bf16_t*)C)[idx] = (bf16_t)acc[i][j][r];
      }
    }
  }
}

// ---------------------------------------------------------------------------
// Register-staged GEMM (fallback path only): A f32 option, C f32 option.
// ---------------------------------------------------------------------------
template <bool A32, bool C32>
__global__ __launch_bounds__(256) void gemm_t(
    const void* __restrict__ A, const bf16_t* __restrict__ Bt,
    void* __restrict__ C, int M, int N, int K) {
  __shared__ bf16_t As[128 * 32];
  __shared__ bf16_t Bs[128 * 32];
  const int tid = threadIdx.x;
  const int lane = tid & 63;
  const int wave = tid >> 6;
  const int m0 = blockIdx.x * 128;
  const int n0 = blockIdx.y * 128;
  const int wm = (wave & 1) * 64;
  const int wn = (wave >> 1) * 64;
  const int fr = lane & 15;
  const int fk = (lane >> 4) * 8;

  f32x4 acc[4][4] = {};

  const size_t ea0 = (size_t)(m0 + (tid >> 2)) * K + (tid & 3) * 8;
  const bf16_t* gb = Bt + (size_t)(n0 + (tid >> 2)) * K + (tid & 3) * 8;
  bf16_t* lA = As + tid * 8;
  bf16_t* lB = Bs + tid * 8;
  const size_t half = (size_t)64 * K;

  for (int k0 = 0; k0 < K; k0 += 32) {
    bf16x8 ra0, ra1;
    if (A32) {
      const float* pa = (const float*)A + ea0 + k0;
      const f32x4 x0 = *(const f32x4*)pa;
      const f32x4 x1 = *(const f32x4*)(pa + 4);
      const f32x4 x2 = *(const f32x4*)(pa + half);
      const f32x4 x3 = *(const f32x4*)(pa + half + 4);
#pragma unroll
      for (int j = 0; j < 4; ++j) {
        ra0[j] = (bf16_t)x0[j];
        ra0[4 + j] = (bf16_t)x1[j];
        ra1[j] = (bf16_t)x2[j];
        ra1[4 + j] = (bf16_t)x3[j];
      }
    } else {
      const bf16_t* pa = (const bf16_t*)A + ea0 + k0;
      ra0 = *(const bf16x8*)pa;
      ra1 = *(const bf16x8*)(pa + half);
    }
    const bf16x8 rb0 = *(const bf16x8*)gb;
    const bf16x8 rb1 = *(const bf16x8*)(gb + half);
    gb += 32;
    __syncthreads();
    *(bf16x8*)lA = ra0;
    *(bf16x8*)(lA + 2048) = ra1;
    *(bf16x8*)lB = rb0;
    *(bf16x8*)(lB + 2048) = rb1;
    __syncthreads();
    bf16x8 af[4], bfr[4];
#pragma unroll
    for (int i = 0; i < 4; ++i)
      af[i] = *(const bf16x8*)(As + (wm + i * 16 + fr) * 32 + fk);
#pragma unroll
    for (int j = 0; j < 4; ++j)
      bfr[j] = *(const bf16x8*)(Bs + (wn + j * 16 + fr) * 32 + fk);
#pragma unroll
    for (int i = 0; i < 4; ++i)
#pragma unroll
      for (int j = 0; j < 4; ++j)
        acc[i][j] = MFMA16(af[i], bfr[j], acc[i][j]);
  }

  const int fg = lane >> 4;
#pragma unroll
  for (int i = 0; i < 4; ++i) {
#pragma unroll
    for (int j = 0; j < 4; ++j) {
#pragma unroll
      for (int r = 0; r < 4; ++r) {
        const int row = m0 + wm + i * 16 + fg * 4 + r;
        const int col = n0 + wn + j * 16 + fr;
        const size_t idx = (size_t)row * N + col;
        if (C32)
          ((float*)C)[idx] = acc[i][j][r];
        else
          ((bf16_t*)C)[idx] = (bf16_t)acc[i][j][r];
      }
    }
  }
}

// ---------------------------------------------------------------------------
// K rope extract: qkv (B*T,6144) -> Kr (B,H,T,D) bf16 rope'd.
// ---------------------------------------------------------------------------
__global__ __launch_bounds__(256) void rope_k(
    const bf16_t* __restrict__ qkv, const bf16_t* __restrict__ cosb,
    const bf16_t* __restrict__ sinb, bf16_t* __restrict__ Kr) {
  const int row = blockIdx.x;  // b*2048 + t
  const int t = row & 2047;
  const int b = row >> 11;
  const int idx = threadIdx.x * 8;
  const int h = idx >> 7;
  const int d = idx & 127;
  const float sgn = (d < 64) ? -1.f : 1.f;
  const bf16_t* base = qkv + (size_t)row * 6144 + 2048;
  const bf16x8 kv = *(const bf16x8*)(base + idx);
  const bf16x8 kp = *(const bf16x8*)(base + (idx ^ 64));
  const bf16x8 cv = *(const bf16x8*)(cosb + t * 128 + d);
  const bf16x8 sv = *(const bf16x8*)(sinb + t * 128 + d);
  bf16x8 o;
#pragma unroll
  for (int jj = 0; jj < 8; ++jj)
    o[jj] = (bf16_t)(((float)kv[jj]) * ((float)cv[jj]) +
                     sgn * ((float)kp[jj]) * ((float)sv[jj]));
  *(bf16x8*)(Kr + ((size_t)(b * 16 + h) * 2048 + t) * 128 + d) = o;
}

// ---------------------------------------------------------------------------
// V extract + transpose: qkv cols 4096.. -> Vt (B,H,D,T).
// ---------------------------------------------------------------------------
__global__ __launch_bounds__(256) void transpose_v(
    const bf16_t* __restrict__ qkv, bf16_t* __restrict__ Vt) {
  __shared__ bf16_t tile[64][72];
  const int bh = blockIdx.z;
  const int b = bh >> 4, h = bh & 15;
  const int t0 = blockIdx.x * 64;
  const int d0 = blockIdx.y * 64;
  const int t = threadIdx.x;
  const int r = t >> 3;
  const int c8 = (t & 7) * 8;
#pragma unroll
  for (int ii = 0; ii < 2; ++ii) {
    const int rr = r + ii * 32;
    *(bf16x8*)(&tile[rr][c8]) =
        *(const bf16x8*)(qkv + (size_t)(b * 2048 + t0 + rr) * 6144 + 4096 + h * 128 + d0 + c8);
  }
  __syncthreads();
#pragma unroll
  for (int ii = 0; ii < 2; ++ii) {
    const int rr = r + ii * 32;
    bf16x8 o;
#pragma unroll
    for (int jj = 0; jj < 8; ++jj) o[jj] = tile[c8 + jj][rr];
    *(bf16x8*)(Vt + ((size_t)bh * 128 + d0 + rr) * 2048 + t0 + c8) = o;
  }
}

// ---------------------------------------------------------------------------
// Flash round-3: ZERO-LDS streaming flash. Swapped QK^T keeps P lane-local;
// both kf and vf B-fragments are loaded DIRECTLY from global (L1/L2 serves
// the per-block-shared 32KB K/V tile). No LDS, no barriers -> waves free-run
// and next-iter loads overlap current PV. π-permuted k-order makes vf two
// contiguous b64 loads; kf is one contiguous b128 per (n,ks).
// ---------------------------------------------------------------------------
__global__ __launch_bounds__(256, 2) void flash_stream(
    const bf16_t* __restrict__ qkv, const bf16_t* __restrict__ cosb,
    const bf16_t* __restrict__ sinb, const bf16_t* __restrict__ Kr,
    const bf16_t* __restrict__ Vt, bf16_t* __restrict__ Y) {
  constexpr int T = 2048;
  const int tid = threadIdx.x;
  const int lane = tid & 63;
  const int wave = tid >> 6;
  const int fr = lane & 15;
  const int fg = lane >> 4;
  const int qt = blockIdx.x;
  const int bh = blockIdx.y;
  const int b = bh >> 4, h = bh & 15;

  // Q rope'd on the fly; scale = rsqrt(128) * log2(e) folded in.
  const bf16_t* qbase = qkv + (size_t)b * T * 6144 + h * 128;
  bf16x8 qf[2][4];
#pragma unroll
  for (int i = 0; i < 2; ++i) {
    const int trow = qt * 128 + wave * 32 + i * 16 + fr;
    const bf16_t* qrow = qbase + (size_t)trow * 6144;
#pragma unroll
    for (int ks = 0; ks < 4; ++ks) {
      const int d = ks * 32 + fg * 8;
      const float sgn = (d < 64) ? -1.f : 1.f;
      const bf16x8 qv = *(const bf16x8*)(qrow + d);
      const bf16x8 qp = *(const bf16x8*)(qrow + (d ^ 64));
      const bf16x8 cv = *(const bf16x8*)(cosb + trow * 128 + d);
      const bf16x8 sv = *(const bf16x8*)(sinb + trow * 128 + d);
      bf16x8 o;
#pragma unroll
      for (int jj = 0; jj < 8; ++jj)
        o[jj] = (bf16_t)((((float)qv[jj]) * ((float)cv[jj]) +
                          sgn * ((float)qp[jj]) * ((float)sv[jj])) *
                         0.1275174825f);  // (1/sqrt(128)) * log2(e)
      qf[i][ks] = o;
    }
  }

  f32x4 acc[2][8] = {};
  float l_i[2] = {0.f, 0.f};

  // Per-lane streaming pointers.
  // K fragment (n,ks): Kr row t0+n*16+fr, cols ks*32+fg*8 (.. +8)  [b128]
  // V fragment (n,ks2): Vt row n*16+fr, cols t0+ks2*32+{fg*4, 16+fg*4} [2x b64]
  const bf16_t* Kh = Kr + (size_t)bh * T * 128 + (size_t)fr * 128 + fg * 8;
  const bf16_t* Vh = Vt + (size_t)bh * 128 * T + (size_t)fr * T + fg * 4;

  for (int j = 0; j < T / 64; ++j) {
    const int t0 = j * 64;
    // ---- QK^T (swapped): lane holds P[q=fr][k=n*16+fg*4+r] ----
    f32x4 sacc[2][4] = {};
#pragma unroll
    for (int n = 0; n < 4; ++n) {
      const bf16_t* krow = Kh + (size_t)(t0 + n * 16) * 128;
#pragma unroll
      for (int ks = 0; ks < 4; ++ks) {
        const bf16x8 kf = *(const bf16x8*)(krow + ks * 32);
        sacc[0][n] = MFMA16(kf, qf[0][ks], sacc[0][n]);
        sacc[1][n] = MFMA16(kf, qf[1][ks], sacc[1][n]);
      }
    }

    // ---- exp + in-register pack into PV A-fragments ----
    // paf[i][ks2][jj] = P[q=fr][k = (2*ks2+(jj>>2))*16 + fg*4 + (jj&3)]
    bf16x8 paf[2][2];
#pragma unroll
    for (int i = 0; i < 2; ++i) {
      float lsum = 0.f;
#pragma unroll
      for (int ks2 = 0; ks2 < 2; ++ks2) {
#pragma unroll
        for (int jj = 0; jj < 8; ++jj) {
          const float p = exp2f(sacc[i][ks2 * 2 + (jj >> 2)][jj & 3]);
          lsum += p;
          paf[i][ks2][jj] = (bf16_t)p;
        }
      }
      l_i[i] += lsum;
    }

    // ---- PV: vf direct from global, π-matched k order ----
#pragma unroll
    for (int ks2 = 0; ks2 < 2; ++ks2) {
#pragma unroll
      for (int n = 0; n < 8; ++n) {
        const bf16_t* vrow = Vh + (size_t)(n * 16) * T + t0 + ks2 * 32;
        const bf16x4 lo = *(const bf16x4*)(vrow);
        const bf16x4 hi = *(const bf16x4*)(vrow + 16);
        const bf16x8 vf = __builtin_shufflevector(lo, hi, 0, 1, 2, 3, 4, 5, 6, 7);
        acc[0][n] = MFMA16(paf[0][ks2], vf, acc[0][n]);
        acc[1][n] = MFMA16(paf[1][ks2], vf, acc[1][n]);
      }
    }
  }

  // epilogue: l reduce across fg groups, then fetch 1/l per output row.
#pragma unroll
  for (int i = 0; i < 2; ++i) {
    float l = l_i[i];
    l += __shfl_xor(l, 16, 64);
    l += __shfl_xor(l, 32, 64);  // lanes with same fr now hold l_full(q=fr)
#pragma unroll
    for (int r = 0; r < 4; ++r) {
      const float inv = 1.0f / __shfl(l, fg * 4 + r, 64);
      const int t = qt * 128 + wave * 32 + i * 16 + fg * 4 + r;
      bf16_t* yrow = Y + (size_t)(b * T + t) * 2048 + h * 128;
#pragma unroll
      for (int n = 0; n < 8; ++n)
        yrow[n * 16 + fr] = (bf16_t)(acc[i][n][r] * inv);
    }
  }
}

// ---------------------------------------------------------------------------
// Flash fallback (ws-lean): fused rope, exp-only softmax. (unchanged)
// ---------------------------------------------------------------------------
__global__ __launch_bounds__(256) void flash_fused_v2(
    const bf16_t* __restrict__ qkv, const bf16_t* __restrict__ cosb,
    const bf16_t* __restrict__ sinb, bf16_t* __restrict__ Y) {
  constexpr int T = 2048;
  __shared__ bf16_t Ks[64][136];
  __shared__ bf16_t Vs[128][72];
  __shared__ bf16_t Ps[128][72];
  const int tid = threadIdx.x;
  const int lane = tid & 63;
  const int wave = tid >> 6;
  const int fr = lane & 15;
  const int fg = lane >> 4;
  const int qt = blockIdx.x;
  const int bh = blockIdx.y;
  const int b = bh >> 4, h = bh & 15;

  const bf16_t* qbase = qkv + (size_t)b * T * 6144 + h * 128;
  bf16x8 qf[2][4];
#pragma unroll
  for (int i = 0; i < 2; ++i) {
    const int trow = qt * 128 + wave * 32 + i * 16 + fr;
    const bf16_t* qrow = qbase + (size_t)trow * 6144;
#pragma unroll
    for (int ks = 0; ks < 4; ++ks) {
      const int d = ks * 32 + fg * 8;
      const float sgn = (d < 64) ? -1.f : 1.f;
      const bf16x8 qv = *(const bf16x8*)(qrow + d);
      const bf16x8 qp = *(const bf16x8*)(qrow + (d ^ 64));
      const bf16x8 cv = *(const bf16x8*)(cosb + trow * 128 + d);
      const bf16x8 sv = *(const bf16x8*)(sinb + trow * 128 + d);
      bf16x8 o;
#pragma unroll
      for (int jj = 0; jj < 8; ++jj)
        o[jj] = (bf16_t)((((float)qv[jj]) * ((float)cv[jj]) +
                          sgn * ((float)qp[jj]) * ((float)sv[jj])) *
                         0.08838834764831845f);
      qf[i][ks] = o;
    }
  }

  f32x4 acc[2][8] = {};
  float l_i[2][4] = {};

  const int kr = tid >> 4;
  const int kc = (tid & 15) * 8;
  const float sgnk = (kc < 64) ? -1.f : 1.f;
  const int tp = tid & 63;

  for (int j = 0; j < T / 64; ++j) {
    const int t0 = j * 64;
#pragma unroll
    for (int it = 0; it < 4; ++it) {
      const int row = it * 16 + kr;
      const int tg = t0 + row;
      const bf16_t* krow = qkv + ((size_t)(b * T + tg)) * 6144 + 2048 + h * 128;
      const bf16x8 kv = *(const bf16x8*)(krow + kc);
      const bf16x8 kp = *(const bf16x8*)(krow + (kc ^ 64));
      const bf16x8 cv = *(const bf16x8*)(cosb + tg * 128 + kc);
      const bf16x8 sv = *(const bf16x8*)(sinb + tg * 128 + kc);
      bf16x8 o;
#pragma unroll
      for (int jj = 0; jj < 8; ++jj)
        o[jj] = (bf16_t)(((float)kv[jj]) * ((float)cv[jj]) +
                         sgnk * ((float)kp[jj]) * ((float)sv[jj]));
      *(bf16x8*)(&Ks[row][kc]) = o;
    }
#pragma unroll
    for (int cc = 0; cc < 4; ++cc) {
      const int d8 = (cc * 4 + (tid >> 6)) * 8;
      const bf16x8 vv = *(const bf16x8*)(qkv + ((size_t)(b * T + t0 + tp)) * 6144 +
                                         4096 + h * 128 + d8);
#pragma unroll
      for (int jj = 0; jj < 8; ++jj) Vs[d8 + jj][tp] = vv[jj];
    }
    __syncthreads();

    f32x4 sacc[2][4] = {};
#pragma unroll
    for (int n = 0; n < 4; ++n) {
#pragma unroll
      for (int ks = 0; ks < 4; ++ks) {
        const bf16x8 kf = *(const bf16x8*)(&Ks[n * 16 + fr][ks * 32 + fg * 8]);
        sacc[0][n] = MFMA16(qf[0][ks], kf, sacc[0][n]);
        sacc[1][n] = MFMA16(qf[1][ks], kf, sacc[1][n]);
      }
    }

#pragma unroll
    for (int i = 0; i < 2; ++i) {
#pragma unroll
      for (int r = 0; r < 4; ++r) {
        const float p0 = __expf(sacc[i][0][r]);
        const float p1 = __expf(sacc[i][1][r]);
        const float p2 = __expf(sacc[i][2][r]);
        const float p3 = __expf(sacc[i][3][r]);
        l_i[i][r] += (p0 + p1) + (p2 + p3);
        const int prow = wave * 32 + i * 16 + fg * 4 + r;
        Ps[prow][0 + fr] = (bf16_t)p0;
        Ps[prow][16 + fr] = (bf16_t)p1;
        Ps[prow][32 + fr] = (bf16_t)p2;
        Ps[prow][48 + fr] = (bf16_t)p3;
      }
    }

#pragma unroll
    for (int ks = 0; ks < 2; ++ks) {
      const bf16x8 pf0 = *(const bf16x8*)(&Ps[wave * 32 + fr][ks * 32 + fg * 8]);
      const bf16x8 pf1 = *(const bf16x8*)(&Ps[wave * 32 + 16 + fr][ks * 32 + fg * 8]);
#pragma unroll
      for (int n = 0; n < 8; ++n) {
        const bf16x8 vf = *(const bf16x8*)(&Vs[n * 16 + fr][ks * 32 + fg * 8]);
        acc[0][n] = MFMA16(pf0, vf, acc[0][n]);
        acc[1][n] = MFMA16(pf1, vf, acc[1][n]);
      }
    }
    __syncthreads();
  }

#pragma unroll
  for (int i = 0; i < 2; ++i) {
#pragma unroll
    for (int r = 0; r < 4; ++r) {
      float l = l_i[i][r];
#pragma unroll
      for (int msk = 1; msk < 16; msk <<= 1) l += __shfl_xor(l, msk, 64);
      const float inv = 1.0f / l;
      const int t = qt * 128 + wave * 32 + i * 16 + fg * 4 + r;
      bf16_t* yrow = Y + (size_t)(b * T + t) * 2048 + h * 128;
#pragma unroll
      for (int n = 0; n < 8; ++n)
        yrow[n * 16 + fr] = (bf16_t)(acc[i][n][r] * inv);
    }
  }
}

// ---------------------------------------------------------------------------
extern "C" void kernel_launch(void* const* d_in, const int* in_sizes, int n_in,
                              void* d_out, int out_size, void* d_ws, size_t ws_size,
                              hipStream_t stream) {
  const float* x = (const float*)d_in[0];
  const float* cosi = (const float*)d_in[1];
  const float* sini = (const float*)d_in[2];
  const float* Wqkv = (const float*)d_in[3];
  const float* Wproj = (const float*)d_in[4];

  const size_t NEED_FAST = sizeof(bf16_t) *
      ((size_t)12582912 + 262144 + 262144 + 25165824 + 8388608 + 8388608);
  const size_t NEED_BASE = 256 + sizeof(bf16_t) *
      ((size_t)12582912 + 4194304 + 262144 + 262144 + 25165824);

  if (ws_size >= NEED_FAST) {
    bf16_t* base = (bf16_t*)d_ws;
    bf16_t* WqkvT = base;                    // dead after gemm1
    bf16_t* y = base;                        // alias
    bf16_t* cosb = base + 12582912;
    bf16_t* sinb = cosb + 262144;
    bf16_t* qkv = sinb + 262144;             // live through flash
    bf16_t* WprojT = qkv;                    // alias head, written after flash
    bf16_t* Kr = qkv + 25165824;
    bf16_t* xb = Kr;                         // alias: x-bf16, dead before rope_k
    bf16_t* Vt = Kr + 8388608;

    conv_vec_f32<<<128, 256, 0, stream>>>(cosi, cosb, 32768);
    conv_vec_f32<<<128, 256, 0, stream>>>(sini, sinb, 32768);
    conv_vec_f32<<<4096, 256, 0, stream>>>(x, xb, 1048576);  // x -> bf16
    conv_transpose_f32<<<dim3(96, 32), 256, 0, stream>>>(Wqkv, WqkvT, 2048, 6144);
    gemm8<false><<<384, 512, 0, stream>>>(xb, WqkvT, qkv, 4096, 6144, 2048, 24);
    rope_k<<<4096, 256, 0, stream>>>(qkv, cosb, sinb, Kr);  // overwrites xb (dead)
    transpose_v<<<dim3(32, 2, 32), 256, 0, stream>>>(qkv, Vt);
    flash_stream<<<dim3(16, 32), 256, 0, stream>>>(qkv, cosb, sinb, Kr, Vt, y);
    conv_transpose_f32<<<dim3(32, 32), 256, 0, stream>>>(Wproj, WprojT, 2048, 2048);
    gemm_lds<true><<<dim3(32, 16), 256, 0, stream>>>(y, WprojT, d_out, 4096, 2048, 2048);
  } else if (ws_size >= NEED_BASE) {
    bf16_t* base = (bf16_t*)((char*)d_ws + 256);
    bf16_t* WqkvT = base;
    bf16_t* y = base;
    bf16_t* WprojT = base + 12582912;
    bf16_t* cosb = WprojT + 4194304;
    bf16_t* sinb = cosb + 262144;
    bf16_t* qkv = sinb + 262144;

    conv_vec_f32<<<128, 256, 0, stream>>>(cosi, cosb, 32768);
    conv_vec_f32<<<128, 256, 0, stream>>>(sini, sinb, 32768);
    conv_transpose_f32<<<dim3(96, 32), 256, 0, stream>>>(Wqkv, WqkvT, 2048, 6144);
    gemm_t<true, false><<<dim3(32, 48), 256, 0, stream>>>(x, WqkvT, qkv, 4096, 6144, 2048);
    flash_fused_v2<<<dim3(16, 32), 256, 0, stream>>>(qkv, cosb, sinb, y);
    conv_transpose_f32<<<dim3(32, 32), 256, 0, stream>>>(Wproj, WprojT, 2048, 2048);
    gemm_t<false, true><<<dim3(32, 16), 256, 0, stream>>>(y, WprojT, d_out, 4096, 2048, 2048);
  } else {
    fill_diag<<<(out_size + 255) / 256, 256, 0, stream>>>((uint32_t*)d_out, out_size);
  }
}

// Round 4
// 457.705 us; speedup vs baseline: 1.5148x; 1.5148x over previous
//
#include <hip/hip_runtime.h>
#include <cstdint>
#include <cstddef>

typedef __bf16 bf16_t;
typedef __bf16 bf16x8 __attribute__((ext_vector_type(8)));
typedef __bf16 bf16x4 __attribute__((ext_vector_type(4)));
typedef float f32x4 __attribute__((ext_vector_type(4)));

#define MFMA16(a, b, c) __builtin_amdgcn_mfma_f32_16x16x32_bf16(a, b, c, 0, 0, 0)

// async global->LDS, 16B per lane. LDS dest = wave-uniform base + lane*16.
__device__ __forceinline__ void gll16(const bf16_t* g, bf16_t* l) {
  __builtin_amdgcn_global_load_lds(
      (__attribute__((address_space(1))) uint32_t*)((uintptr_t)g),
      (__attribute__((address_space(3))) uint32_t*)((uint32_t)(uintptr_t)l),
      16, 0, 0);
}

// Diagnostic: absmax ~1000 => ws_size too small.
__global__ void fill_diag(uint32_t* out, int n_u32) {
  int i = blockIdx.x * 256 + threadIdx.x;
  if (i < n_u32) out[i] = 0x447A0000u;  // f32 1000.0
}

// ---------------------------------------------------------------------------
// f32 -> bf16 vector convert (x, cos/sin tables). One bf16x8 per thread.
// ---------------------------------------------------------------------------
__global__ void conv_vec_f32(const float* __restrict__ in, bf16_t* __restrict__ out,
                             int n8) {
  const int i = blockIdx.x * 256 + threadIdx.x;
  if (i >= n8) return;
  const float* p = in + (size_t)i * 8;
  const f32x4 a = *(const f32x4*)p;
  const f32x4 b = *(const f32x4*)(p + 4);
  bf16x8 o;
#pragma unroll
  for (int j = 0; j < 4; ++j) {
    o[j] = (bf16_t)a[j];
    o[4 + j] = (bf16_t)b[j];
  }
  ((bf16x8*)out)[i] = o;
}

// ---------------------------------------------------------------------------
// 64x64 tiled transpose+convert: in R x C f32 -> out C x R bf16.
// ---------------------------------------------------------------------------
__global__ __launch_bounds__(256) void conv_transpose_f32(
    const float* __restrict__ in, bf16_t* __restrict__ out, int R, int C) {
  __shared__ bf16_t tile[64][72];
  const int bc = blockIdx.x * 64;
  const int br = blockIdx.y * 64;
  const int t = threadIdx.x;
  const int r = t >> 3;
  const int c8 = (t & 7) * 8;
#pragma unroll
  for (int ii = 0; ii < 2; ++ii) {
    const int rr = r + ii * 32;
    const float* p = in + (size_t)(br + rr) * C + bc + c8;
    const f32x4 a = *(const f32x4*)p;
    const f32x4 b = *(const f32x4*)(p + 4);
    bf16x8 v;
#pragma unroll
    for (int j = 0; j < 4; ++j) {
      v[j] = (bf16_t)a[j];
      v[4 + j] = (bf16_t)b[j];
    }
    *(bf16x8*)(&tile[rr][c8]) = v;
  }
  __syncthreads();
#pragma unroll
  for (int ii = 0; ii < 2; ++ii) {
    const int rr = r + ii * 32;
    bf16x8 o;
#pragma unroll
    for (int jj = 0; jj < 8; ++jj) o[jj] = tile[c8 + jj][rr];
    *(bf16x8*)(out + (size_t)(bc + rr) * R + br + c8) = o;
  }
}

// ---------------------------------------------------------------------------
// 256x256 8-phase GEMM (HK-style template, plain HIP). See round-0 notes.
// ---------------------------------------------------------------------------
#define MF8(MLO, AARR, BARR, NLO)                                           \
  do {                                                                      \
    _Pragma("unroll") for (int m_ = 0; m_ < 4; ++m_) {                      \
      _Pragma("unroll") for (int n_ = 0; n_ < 2; ++n_) {                    \
        acc[(MLO) + m_][(NLO) + n_] =                                       \
            MFMA16(AARR[m_][0], BARR[n_][0], acc[(MLO) + m_][(NLO) + n_]);  \
        acc[(MLO) + m_][(NLO) + n_] =                                       \
            MFMA16(AARR[m_][1], BARR[n_][1], acc[(MLO) + m_][(NLO) + n_]);  \
      }                                                                     \
    }                                                                       \
  } while (0)

template <bool C32>
__global__ __launch_bounds__(512, 2) void gemm8(
    const bf16_t* __restrict__ A, const bf16_t* __restrict__ Bt,
    void* __restrict__ C, int M, int N, int K, int nbn) {
  __shared__ __align__(1024) bf16_t lds8[65536];  // A: [0,32768), B: [32768,65536)
  bf16_t* As = lds8;
  bf16_t* Bs = lds8 + 32768;

  const int tid = threadIdx.x;
  const int lane = tid & 63;
  const int wave = tid >> 6;
  const int wr = wave >> 2;  // 0..1 (M half)
  const int wc = wave & 3;   // 0..3 (N quarter)
  const int fr = lane & 15;
  const int fg = lane >> 4;

  // XCD-aware bijective swizzle (nwg % 8 == 0 by construction).
  const int nwg = gridDim.x;
  const int bid = blockIdx.x;
  const int swz = (bid & 7) * (nwg >> 3) + (bid >> 3);
  const int m0 = (swz / nbn) * 256;
  const int n0 = (swz % nbn) * 256;

  const int NT = K >> 6;  // BK=64 tiles (assumed even; K=2048 -> 32)

  // staging geometry: wave covers segs {2w, 2w+1}; seg = 8 rows of 128B.
  const int sseg0 = wave * 2;
  const int srow = lane >> 3;
  const int sj = lane & 7;

  auto stage = [&](const bf16_t* __restrict__ G, int row0, bf16_t* L, int kt,
                   int h) {
#pragma unroll
    for (int l = 0; l < 2; ++l) {
      const int seg = sseg0 + l;
      const int r = seg * 8 + srow;       // row in half-tile 0..127
      const int j = sj ^ (r & 7);         // inverse-swizzled source chunk
      const bf16_t* src = G + (size_t)(row0 + h * 128 + r) * K + kt * 64 + j * 8;
      gll16(src, L + ((2 * kt + h) & 3) * 8192 + seg * 512 + lane * 8);
    }
  };

  const int cb0 = (fg * 16) ^ ((fr & 7) << 4);  // kk=0 byte col (swizzled)

  auto lda = [&](bf16x8(&af)[4][2], int kt, int mlo) {
    const char* base = (const char*)(As + ((2 * kt + wr) & 3) * 8192);
#pragma unroll
    for (int m = 0; m < 4; ++m) {
      const char* p = base + ((mlo + m) * 16 + fr) * 128;
      af[m][0] = *(const bf16x8*)(p + cb0);
      af[m][1] = *(const bf16x8*)(p + (cb0 ^ 64));
    }
  };
  auto ldb = [&](bf16x8(&bf)[2][2], int kt, int nlo) {
    const char* base = (const char*)(Bs + ((2 * kt + (wc >> 1)) & 3) * 8192);
#pragma unroll
    for (int n = 0; n < 2; ++n) {
      const char* p = base + ((wc & 1) * 64 + (nlo + n) * 16 + fr) * 128;
      bf[n][0] = *(const bf16x8*)(p + cb0);
      bf[n][1] = *(const bf16x8*)(p + (cb0 ^ 64));
    }
  };

  f32x4 acc[8][4] = {};

  // Prologue: A(0), B(0), B(1); drain A(0)+B(0), keep B(1) in flight.
  stage(A, m0, As, 0, 0);
  stage(A, m0, As, 0, 1);
  stage(Bt, n0, Bs, 0, 0);
  stage(Bt, n0, Bs, 0, 1);
  stage(Bt, n0, Bs, 1, 0);
  stage(Bt, n0, Bs, 1, 1);
  asm volatile("s_waitcnt vmcnt(4)" ::: "memory");
  __builtin_amdgcn_s_barrier();

  bf16x8 af[4][2], bfA[2][2], bfB[2][2];

  for (int u = 0; u < NT; u += 2) {
    const bool st2 = (u + 2 < NT);
    const bool st3 = (u + 3 < NT);
    // ---------------- tile u ----------------
    lda(af, u, 0);
    ldb(bfA, u, 0);
    stage(A, m0, As, u + 1, 0);
    asm volatile("s_waitcnt lgkmcnt(8)" ::: "memory");
    __builtin_amdgcn_s_barrier();
    asm volatile("s_waitcnt lgkmcnt(0)" ::: "memory");
    __builtin_amdgcn_sched_barrier(0);
    __builtin_amdgcn_s_setprio(1);
    MF8(0, af, bfA, 0);
    __builtin_amdgcn_s_setprio(0);
    __builtin_amdgcn_s_barrier();
    ldb(bfB, u, 2);
    stage(A, m0, As, u + 1, 1);
    __builtin_amdgcn_s_barrier();
    asm volatile("s_waitcnt lgkmcnt(0)" ::: "memory");
    __builtin_amdgcn_sched_barrier(0);
    __builtin_amdgcn_s_setprio(1);
    MF8(0, af, bfB, 2);
    __builtin_amdgcn_s_setprio(0);
    __builtin_amdgcn_s_barrier();
    lda(af, u, 4);
    if (st2) stage(Bt, n0, Bs, u + 2, 0);
    __builtin_amdgcn_s_barrier();
    asm volatile("s_waitcnt lgkmcnt(0)" ::: "memory");
    __builtin_amdgcn_sched_barrier(0);
    __builtin_amdgcn_s_setprio(1);
    MF8(4, af, bfB, 2);
    __builtin_amdgcn_s_setprio(0);
    __builtin_amdgcn_s_barrier();
    if (st2) stage(Bt, n0, Bs, u + 2, 1);
    __builtin_amdgcn_s_barrier();
    __builtin_amdgcn_s_setprio(1);
    MF8(4, af, bfA, 0);
    __builtin_amdgcn_s_setprio(0);
    asm volatile("s_waitcnt vmcnt(4)" ::: "memory");
    __builtin_amdgcn_s_barrier();
    // ---------------- tile u+1 ----------------
    lda(af, u + 1, 0);
    ldb(bfA, u + 1, 0);
    if (st2) stage(A, m0, As, u + 2, 0);
    asm volatile("s_waitcnt lgkmcnt(8)" ::: "memory");
    __builtin_amdgcn_s_barrier();
    asm volatile("s_waitcnt lgkmcnt(0)" ::: "memory");
    __builtin_amdgcn_sched_barrier(0);
    __builtin_amdgcn_s_setprio(1);
    MF8(0, af, bfA, 0);
    __builtin_amdgcn_s_setprio(0);
    __builtin_amdgcn_s_barrier();
    ldb(bfB, u + 1, 2);
    if (st2) stage(A, m0, As, u + 2, 1);
    __builtin_amdgcn_s_barrier();
    asm volatile("s_waitcnt lgkmcnt(0)" ::: "memory");
    __builtin_amdgcn_sched_barrier(0);
    __builtin_amdgcn_s_setprio(1);
    MF8(0, af, bfB, 2);
    __builtin_amdgcn_s_setprio(0);
    __builtin_amdgcn_s_barrier();
    lda(af, u + 1, 4);
    if (st3) stage(Bt, n0, Bs, u + 3, 0);
    __builtin_amdgcn_s_barrier();
    asm volatile("s_waitcnt lgkmcnt(0)" ::: "memory");
    __builtin_amdgcn_sched_barrier(0);
    __builtin_amdgcn_s_setprio(1);
    MF8(4, af, bfB, 2);
    __builtin_amdgcn_s_setprio(0);
    __builtin_amdgcn_s_barrier();
    if (st3) stage(Bt, n0, Bs, u + 3, 1);
    __builtin_amdgcn_s_barrier();
    __builtin_amdgcn_s_setprio(1);
    MF8(4, af, bfA, 0);
    __builtin_amdgcn_s_setprio(0);
    asm volatile("s_waitcnt vmcnt(4)" ::: "memory");
    __builtin_amdgcn_s_barrier();
  }

#pragma unroll
  for (int m = 0; m < 8; ++m) {
#pragma unroll
    for (int n = 0; n < 4; ++n) {
#pragma unroll
      for (int r = 0; r < 4; ++r) {
        const int row = m0 + wr * 128 + m * 16 + fg * 4 + r;
        const int col = n0 + wc * 64 + n * 16 + fr;
        const size_t idx = (size_t)row * N + col;
        if (C32)
          ((float*)C)[idx] = acc[m][n][r];
        else
          ((bf16_t*)C)[idx] = (bf16_t)acc[m][n][r];
      }
    }
  }
  (void)M;
}

// ---------------------------------------------------------------------------
// m97-style GEMM: kept for proj GEMM (N=2048 -> 256^2 grid only 128 blocks).
// ---------------------------------------------------------------------------
template <bool C32>
__global__ __launch_bounds__(256) void gemm_lds(
    const bf16_t* __restrict__ A, const bf16_t* __restrict__ Bt,
    void* __restrict__ C, int M, int N, int K) {
  __shared__ __align__(16) bf16_t As[128 * 32];
  __shared__ __align__(16) bf16_t Bs[128 * 32];
  const int tid = threadIdx.x;
  const int lane = tid & 63;
  const int wave = tid >> 6;
  const int m0 = blockIdx.x * 128;
  const int n0 = blockIdx.y * 128;
  const int wm = (wave & 1) * 64;
  const int wn = (wave >> 1) * 64;
  const int fr = lane & 15;
  const int fk = (lane >> 4) * 8;

  f32x4 acc[4][4] = {};

  const bf16_t* ga = A + (size_t)(m0 + (tid >> 2)) * K + (tid & 3) * 8;
  const bf16_t* gb = Bt + (size_t)(n0 + (tid >> 2)) * K + (tid & 3) * 8;
  bf16_t* lA = As + tid * 8;
  bf16_t* lB = Bs + tid * 8;
  const size_t half = (size_t)64 * K;

  for (int k0 = 0; k0 < K; k0 += 32) {
    __syncthreads();
    gll16(ga, lA);
    gll16(ga + half, lA + 2048);
    gll16(gb, lB);
    gll16(gb + half, lB + 2048);
    ga += 32;
    gb += 32;
    __syncthreads();
    bf16x8 af[4], bfr[4];
#pragma unroll
    for (int i = 0; i < 4; ++i)
      af[i] = *(const bf16x8*)(As + (wm + i * 16 + fr) * 32 + fk);
#pragma unroll
    for (int j = 0; j < 4; ++j)
      bfr[j] = *(const bf16x8*)(Bs + (wn + j * 16 + fr) * 32 + fk);
#pragma unroll
    for (int i = 0; i < 4; ++i)
#pragma unroll
      for (int j = 0; j < 4; ++j)
        acc[i][j] = MFMA16(af[i], bfr[j], acc[i][j]);
  }

  const int fg = lane >> 4;
#pragma unroll
  for (int i = 0; i < 4; ++i) {
#pragma unroll
    for (int j = 0; j < 4; ++j) {
#pragma unroll
      for (int r = 0; r < 4; ++r) {
        const int row = m0 + wm + i * 16 + fg * 4 + r;
        const int col = n0 + wn + j * 16 + fr;
        const size_t idx = (size_t)row * N + col;
        if (C32)
          ((float*)C)[idx] = acc[i][j][r];
        else
          ((bf16_t*)C)[idx] = (bf16_t)acc[i][j][r];
      }
    }
  }
}

// ---------------------------------------------------------------------------
// Register-staged GEMM (fallback path only): A f32 option, C f32 option.
// ---------------------------------------------------------------------------
template <bool A32, bool C32>
__global__ __launch_bounds__(256) void gemm_t(
    const void* __restrict__ A, const bf16_t* __restrict__ Bt,
    void* __restrict__ C, int M, int N, int K) {
  __shared__ bf16_t As[128 * 32];
  __shared__ bf16_t Bs[128 * 32];
  const int tid = threadIdx.x;
  const int lane = tid & 63;
  const int wave = tid >> 6;
  const int m0 = blockIdx.x * 128;
  const int n0 = blockIdx.y * 128;
  const int wm = (wave & 1) * 64;
  const int wn = (wave >> 1) * 64;
  const int fr = lane & 15;
  const int fk = (lane >> 4) * 8;

  f32x4 acc[4][4] = {};

  const size_t ea0 = (size_t)(m0 + (tid >> 2)) * K + (tid & 3) * 8;
  const bf16_t* gb = Bt + (size_t)(n0 + (tid >> 2)) * K + (tid & 3) * 8;
  bf16_t* lA = As + tid * 8;
  bf16_t* lB = Bs + tid * 8;
  const size_t half = (size_t)64 * K;

  for (int k0 = 0; k0 < K; k0 += 32) {
    bf16x8 ra0, ra1;
    if (A32) {
      const float* pa = (const float*)A + ea0 + k0;
      const f32x4 x0 = *(const f32x4*)pa;
      const f32x4 x1 = *(const f32x4*)(pa + 4);
      const f32x4 x2 = *(const f32x4*)(pa + half);
      const f32x4 x3 = *(const f32x4*)(pa + half + 4);
#pragma unroll
      for (int j = 0; j < 4; ++j) {
        ra0[j] = (bf16_t)x0[j];
        ra0[4 + j] = (bf16_t)x1[j];
        ra1[j] = (bf16_t)x2[j];
        ra1[4 + j] = (bf16_t)x3[j];
      }
    } else {
      const bf16_t* pa = (const bf16_t*)A + ea0 + k0;
      ra0 = *(const bf16x8*)pa;
      ra1 = *(const bf16x8*)(pa + half);
    }
    const bf16x8 rb0 = *(const bf16x8*)gb;
    const bf16x8 rb1 = *(const bf16x8*)(gb + half);
    gb += 32;
    __syncthreads();
    *(bf16x8*)lA = ra0;
    *(bf16x8*)(lA + 2048) = ra1;
    *(bf16x8*)lB = rb0;
    *(bf16x8*)(lB + 2048) = rb1;
    __syncthreads();
    bf16x8 af[4], bfr[4];
#pragma unroll
    for (int i = 0; i < 4; ++i)
      af[i] = *(const bf16x8*)(As + (wm + i * 16 + fr) * 32 + fk);
#pragma unroll
    for (int j = 0; j < 4; ++j)
      bfr[j] = *(const bf16x8*)(Bs + (wn + j * 16 + fr) * 32 + fk);
#pragma unroll
    for (int i = 0; i < 4; ++i)
#pragma unroll
      for (int j = 0; j < 4; ++j)
        acc[i][j] = MFMA16(af[i], bfr[j], acc[i][j]);
  }

  const int fg = lane >> 4;
#pragma unroll
  for (int i = 0; i < 4; ++i) {
#pragma unroll
    for (int j = 0; j < 4; ++j) {
#pragma unroll
      for (int r = 0; r < 4; ++r) {
        const int row = m0 + wm + i * 16 + fg * 4 + r;
        const int col = n0 + wn + j * 16 + fr;
        const size_t idx = (size_t)row * N + col;
        if (C32)
          ((float*)C)[idx] = acc[i][j][r];
        else
          ((bf16_t*)C)[idx] = (bf16_t)acc[i][j][r];
      }
    }
  }
}

// ---------------------------------------------------------------------------
// K rope extract: qkv (B*T,6144) -> Kr (B,H,T,D) bf16 rope'd.
// ---------------------------------------------------------------------------
__global__ __launch_bounds__(256) void rope_k(
    const bf16_t* __restrict__ qkv, const bf16_t* __restrict__ cosb,
    const bf16_t* __restrict__ sinb, bf16_t* __restrict__ Kr) {
  const int row = blockIdx.x;  // b*2048 + t
  const int t = row & 2047;
  const int b = row >> 11;
  const int idx = threadIdx.x * 8;
  const int h = idx >> 7;
  const int d = idx & 127;
  const float sgn = (d < 64) ? -1.f : 1.f;
  const bf16_t* base = qkv + (size_t)row * 6144 + 2048;
  const bf16x8 kv = *(const bf16x8*)(base + idx);
  const bf16x8 kp = *(const bf16x8*)(base + (idx ^ 64));
  const bf16x8 cv = *(const bf16x8*)(cosb + t * 128 + d);
  const bf16x8 sv = *(const bf16x8*)(sinb + t * 128 + d);
  bf16x8 o;
#pragma unroll
  for (int jj = 0; jj < 8; ++jj)
    o[jj] = (bf16_t)(((float)kv[jj]) * ((float)cv[jj]) +
                     sgn * ((float)kp[jj]) * ((float)sv[jj]));
  *(bf16x8*)(Kr + ((size_t)(b * 16 + h) * 2048 + t) * 128 + d) = o;
}

// ---------------------------------------------------------------------------
// V extract + transpose: qkv cols 4096.. -> Vt (B,H,D,T).
// ---------------------------------------------------------------------------
__global__ __launch_bounds__(256) void transpose_v(
    const bf16_t* __restrict__ qkv, bf16_t* __restrict__ Vt) {
  __shared__ bf16_t tile[64][72];
  const int bh = blockIdx.z;
  const int b = bh >> 4, h = bh & 15;
  const int t0 = blockIdx.x * 64;
  const int d0 = blockIdx.y * 64;
  const int t = threadIdx.x;
  const int r = t >> 3;
  const int c8 = (t & 7) * 8;
#pragma unroll
  for (int ii = 0; ii < 2; ++ii) {
    const int rr = r + ii * 32;
    *(bf16x8*)(&tile[rr][c8]) =
        *(const bf16x8*)(qkv + (size_t)(b * 2048 + t0 + rr) * 6144 + 4096 + h * 128 + d0 + c8);
  }
  __syncthreads();
#pragma unroll
  for (int ii = 0; ii < 2; ++ii) {
    const int rr = r + ii * 32;
    bf16x8 o;
#pragma unroll
    for (int jj = 0; jj < 8; ++jj) o[jj] = tile[c8 + jj][rr];
    *(bf16x8*)(Vt + ((size_t)bh * 128 + d0 + rr) * 2048 + t0 + c8) = o;
  }
}

// ---------------------------------------------------------------------------
// Flash round-4: QBLK=64 for occupancy. Round-2 LDS structure (swapped QK^T,
// in-register P, π-permuted Vs), but each block handles 64 q-rows -> grid
// 1024 blocks = 4 blocks/CU = 4 waves/SIMD (latency-bound fix). Per-wave
// state halved; __launch_bounds__(256,4) pins VGPR <= 128.
// ---------------------------------------------------------------------------
__global__ __launch_bounds__(256, 4) void flash_q64(
    const bf16_t* __restrict__ qkv, const bf16_t* __restrict__ cosb,
    const bf16_t* __restrict__ sinb, const bf16_t* __restrict__ Kr,
    const bf16_t* __restrict__ Vt, bf16_t* __restrict__ Y) {
  constexpr int T = 2048;
  __shared__ bf16_t Ks[64][136];
  __shared__ bf16_t Vs[128][72];
  const int tid = threadIdx.x;
  const int lane = tid & 63;
  const int wave = tid >> 6;
  const int fr = lane & 15;
  const int fg = lane >> 4;
  const int qt = blockIdx.x;  // 0..31, 64 q-rows each
  const int bh = blockIdx.y;
  const int b = bh >> 4, h = bh & 15;

  // Q rope'd on the fly; scale = rsqrt(128) * log2(e) folded in.
  const int trow = qt * 64 + wave * 16 + fr;
  const bf16_t* qrow = qkv + (size_t)(b * T + trow) * 6144 + h * 128;
  bf16x8 qf[4];
#pragma unroll
  for (int ks = 0; ks < 4; ++ks) {
    const int d = ks * 32 + fg * 8;
    const float sgn = (d < 64) ? -1.f : 1.f;
    const bf16x8 qv = *(const bf16x8*)(qrow + d);
    const bf16x8 qp = *(const bf16x8*)(qrow + (d ^ 64));
    const bf16x8 cv = *(const bf16x8*)(cosb + trow * 128 + d);
    const bf16x8 sv = *(const bf16x8*)(sinb + trow * 128 + d);
    bf16x8 o;
#pragma unroll
    for (int jj = 0; jj < 8; ++jj)
      o[jj] = (bf16_t)((((float)qv[jj]) * ((float)cv[jj]) +
                        sgn * ((float)qp[jj]) * ((float)sv[jj])) *
                       0.1275174825f);  // (1/sqrt(128)) * log2(e)
    qf[ks] = o;
  }

  f32x4 acc[8] = {};
  float l_i = 0.f;

  // staging geometry
  const int krow = tid >> 4;        // 0..15
  const int kcol = (tid & 15) * 8;  // 0..120
  const int vrow = tid >> 3;        // 0..31 (d rows, +32*it)
  const int vu = tid & 7;           // t-chunk index (8 consecutive t)
  // permuted base column for t = vu*8: c = b5*32 + b3*16 + b2*8 + b4*4 + b1b0
  const int vc0 = ((vu >> 2) * 32) + ((vu & 1) * 16) + (((vu >> 1) & 1) * 4);
  const bf16_t* Kh = Kr + (size_t)bh * T * 128;
  const bf16_t* Vh = Vt + (size_t)bh * 128 * T;

  for (int j = 0; j < T / 64; ++j) {
    const int t0 = j * 64;
    // stage K (64x128) and V (128x64, π-permuted columns)
#pragma unroll
    for (int it = 0; it < 4; ++it)
      *(bf16x8*)(&Ks[it * 16 + krow][kcol]) =
          *(const bf16x8*)(Kh + (size_t)(t0 + it * 16 + krow) * 128 + kcol);
#pragma unroll
    for (int it = 0; it < 4; ++it) {
      const int row = it * 32 + vrow;
      const bf16x8 v = *(const bf16x8*)(Vh + (size_t)row * T + t0 + vu * 8);
      bf16x4 lo, hi;
#pragma unroll
      for (int jj = 0; jj < 4; ++jj) {
        lo[jj] = v[jj];
        hi[jj] = v[4 + jj];
      }
      *(bf16x4*)(&Vs[row][vc0]) = lo;      // t = base+0..3  (b2=0)
      *(bf16x4*)(&Vs[row][vc0 + 8]) = hi;  // t = base+4..7  (b2=1)
    }
    __syncthreads();

    // QK^T swapped: lane holds P[q=fr][k=n*16+fg*4+r]
    f32x4 sacc[4] = {};
#pragma unroll
    for (int n = 0; n < 4; ++n) {
#pragma unroll
      for (int ks = 0; ks < 4; ++ks) {
        const bf16x8 kf = *(const bf16x8*)(&Ks[n * 16 + fr][ks * 32 + fg * 8]);
        sacc[n] = MFMA16(kf, qf[ks], sacc[n]);
      }
    }

    // exp + in-register pack into PV A-fragments:
    // paf[ks2][jj] = P[q=fr][k = (2*ks2+(jj>>2))*16 + fg*4 + (jj&3)]
    bf16x8 paf[2];
    float lsum = 0.f;
#pragma unroll
    for (int ks2 = 0; ks2 < 2; ++ks2) {
#pragma unroll
      for (int jj = 0; jj < 8; ++jj) {
        const float p = exp2f(sacc[ks2 * 2 + (jj >> 2)][jj & 3]);
        lsum += p;
        paf[ks2][jj] = (bf16_t)p;
      }
    }
    l_i += lsum;

    // PV: Vs column order matches paf's k order by construction.
#pragma unroll
    for (int ks2 = 0; ks2 < 2; ++ks2) {
#pragma unroll
      for (int n = 0; n < 8; ++n) {
        const bf16x8 vf = *(const bf16x8*)(&Vs[n * 16 + fr][ks2 * 32 + fg * 8]);
        acc[n] = MFMA16(paf[ks2], vf, acc[n]);
      }
    }
    __syncthreads();
  }

  // epilogue: l reduce across fg groups (lanes fr, fr+16, fr+32, fr+48 hold
  // disjoint k-subsets of q=fr), then fetch 1/l for this lane's output rows.
  float l = l_i;
  l += __shfl_xor(l, 16, 64);
  l += __shfl_xor(l, 32, 64);  // lanes with same fr now hold l_full(q=fr)
#pragma unroll
  for (int r = 0; r < 4; ++r) {
    const float inv = 1.0f / __shfl(l, fg * 4 + r, 64);
    const int t = qt * 64 + wave * 16 + fg * 4 + r;
    bf16_t* yrow = Y + (size_t)(b * T + t) * 2048 + h * 128;
#pragma unroll
    for (int n = 0; n < 8; ++n)
      yrow[n * 16 + fr] = (bf16_t)(acc[n][r] * inv);
  }
}

// ---------------------------------------------------------------------------
// Flash fallback (ws-lean): fused rope, exp-only softmax. (unchanged)
// ---------------------------------------------------------------------------
__global__ __launch_bounds__(256) void flash_fused_v2(
    const bf16_t* __restrict__ qkv, const bf16_t* __restrict__ cosb,
    const bf16_t* __restrict__ sinb, bf16_t* __restrict__ Y) {
  constexpr int T = 2048;
  __shared__ bf16_t Ks[64][136];
  __shared__ bf16_t Vs[128][72];
  __shared__ bf16_t Ps[128][72];
  const int tid = threadIdx.x;
  const int lane = tid & 63;
  const int wave = tid >> 6;
  const int fr = lane & 15;
  const int fg = lane >> 4;
  const int qt = blockIdx.x;
  const int bh = blockIdx.y;
  const int b = bh >> 4, h = bh & 15;

  const bf16_t* qbase = qkv + (size_t)b * T * 6144 + h * 128;
  bf16x8 qf[2][4];
#pragma unroll
  for (int i = 0; i < 2; ++i) {
    const int trow = qt * 128 + wave * 32 + i * 16 + fr;
    const bf16_t* qrow = qbase + (size_t)trow * 6144;
#pragma unroll
    for (int ks = 0; ks < 4; ++ks) {
      const int d = ks * 32 + fg * 8;
      const float sgn = (d < 64) ? -1.f : 1.f;
      const bf16x8 qv = *(const bf16x8*)(qrow + d);
      const bf16x8 qp = *(const bf16x8*)(qrow + (d ^ 64));
      const bf16x8 cv = *(const bf16x8*)(cosb + trow * 128 + d);
      const bf16x8 sv = *(const bf16x8*)(sinb + trow * 128 + d);
      bf16x8 o;
#pragma unroll
      for (int jj = 0; jj < 8; ++jj)
        o[jj] = (bf16_t)((((float)qv[jj]) * ((float)cv[jj]) +
                          sgn * ((float)qp[jj]) * ((float)sv[jj])) *
                         0.08838834764831845f);
      qf[i][ks] = o;
    }
  }

  f32x4 acc[2][8] = {};
  float l_i[2][4] = {};

  const int kr = tid >> 4;
  const int kc = (tid & 15) * 8;
  const float sgnk = (kc < 64) ? -1.f : 1.f;
  const int tp = tid & 63;

  for (int j = 0; j < T / 64; ++j) {
    const int t0 = j * 64;
#pragma unroll
    for (int it = 0; it < 4; ++it) {
      const int row = it * 16 + kr;
      const int tg = t0 + row;
      const bf16_t* krow = qkv + ((size_t)(b * T + tg)) * 6144 + 2048 + h * 128;
      const bf16x8 kv = *(const bf16x8*)(krow + kc);
      const bf16x8 kp = *(const bf16x8*)(krow + (kc ^ 64));
      const bf16x8 cv = *(const bf16x8*)(cosb + tg * 128 + kc);
      const bf16x8 sv = *(const bf16x8*)(sinb + tg * 128 + kc);
      bf16x8 o;
#pragma unroll
      for (int jj = 0; jj < 8; ++jj)
        o[jj] = (bf16_t)(((float)kv[jj]) * ((float)cv[jj]) +
                         sgnk * ((float)kp[jj]) * ((float)sv[jj]));
      *(bf16x8*)(&Ks[row][kc]) = o;
    }
#pragma unroll
    for (int cc = 0; cc < 4; ++cc) {
      const int d8 = (cc * 4 + (tid >> 6)) * 8;
      const bf16x8 vv = *(const bf16x8*)(qkv + ((size_t)(b * T + t0 + tp)) * 6144 +
                                         4096 + h * 128 + d8);
#pragma unroll
      for (int jj = 0; jj < 8; ++jj) Vs[d8 + jj][tp] = vv[jj];
    }
    __syncthreads();

    f32x4 sacc[2][4] = {};
#pragma unroll
    for (int n = 0; n < 4; ++n) {
#pragma unroll
      for (int ks = 0; ks < 4; ++ks) {
        const bf16x8 kf = *(const bf16x8*)(&Ks[n * 16 + fr][ks * 32 + fg * 8]);
        sacc[0][n] = MFMA16(qf[0][ks], kf, sacc[0][n]);
        sacc[1][n] = MFMA16(qf[1][ks], kf, sacc[1][n]);
      }
    }

#pragma unroll
    for (int i = 0; i < 2; ++i) {
#pragma unroll
      for (int r = 0; r < 4; ++r) {
        const float p0 = __expf(sacc[i][0][r]);
        const float p1 = __expf(sacc[i][1][r]);
        const float p2 = __expf(sacc[i][2][r]);
        const float p3 = __expf(sacc[i][3][r]);
        l_i[i][r] += (p0 + p1) + (p2 + p3);
        const int prow = wave * 32 + i * 16 + fg * 4 + r;
        Ps[prow][0 + fr] = (bf16_t)p0;
        Ps[prow][16 + fr] = (bf16_t)p1;
        Ps[prow][32 + fr] = (bf16_t)p2;
        Ps[prow][48 + fr] = (bf16_t)p3;
      }
    }

#pragma unroll
    for (int ks = 0; ks < 2; ++ks) {
      const bf16x8 pf0 = *(const bf16x8*)(&Ps[wave * 32 + fr][ks * 32 + fg * 8]);
      const bf16x8 pf1 = *(const bf16x8*)(&Ps[wave * 32 + 16 + fr][ks * 32 + fg * 8]);
#pragma unroll
      for (int n = 0; n < 8; ++n) {
        const bf16x8 vf = *(const bf16x8*)(&Vs[n * 16 + fr][ks * 32 + fg * 8]);
        acc[0][n] = MFMA16(pf0, vf, acc[0][n]);
        acc[1][n] = MFMA16(pf1, vf, acc[1][n]);
      }
    }
    __syncthreads();
  }

#pragma unroll
  for (int i = 0; i < 2; ++i) {
#pragma unroll
    for (int r = 0; r < 4; ++r) {
      float l = l_i[i][r];
#pragma unroll
      for (int msk = 1; msk < 16; msk <<= 1) l += __shfl_xor(l, msk, 64);
      const float inv = 1.0f / l;
      const int t = qt * 128 + wave * 32 + i * 16 + fg * 4 + r;
      bf16_t* yrow = Y + (size_t)(b * T + t) * 2048 + h * 128;
#pragma unroll
      for (int n = 0; n < 8; ++n)
        yrow[n * 16 + fr] = (bf16_t)(acc[i][n][r] * inv);
    }
  }
}

// ---------------------------------------------------------------------------
extern "C" void kernel_launch(void* const* d_in, const int* in_sizes, int n_in,
                              void* d_out, int out_size, void* d_ws, size_t ws_size,
                              hipStream_t stream) {
  const float* x = (const float*)d_in[0];
  const float* cosi = (const float*)d_in[1];
  const float* sini = (const float*)d_in[2];
  const float* Wqkv = (const float*)d_in[3];
  const float* Wproj = (const float*)d_in[4];

  const size_t NEED_FAST = sizeof(bf16_t) *
      ((size_t)12582912 + 262144 + 262144 + 25165824 + 8388608 + 8388608);
  const size_t NEED_BASE = 256 + sizeof(bf16_t) *
      ((size_t)12582912 + 4194304 + 262144 + 262144 + 25165824);

  if (ws_size >= NEED_FAST) {
    bf16_t* base = (bf16_t*)d_ws;
    bf16_t* WqkvT = base;                    // dead after gemm1
    bf16_t* y = base;                        // alias
    bf16_t* cosb = base + 12582912;
    bf16_t* sinb = cosb + 262144;
    bf16_t* qkv = sinb + 262144;             // live through flash
    bf16_t* WprojT = qkv;                    // alias head, written after flash
    bf16_t* Kr = qkv + 25165824;
    bf16_t* xb = Kr;                         // alias: x-bf16, dead before rope_k
    bf16_t* Vt = Kr + 8388608;

    conv_vec_f32<<<128, 256, 0, stream>>>(cosi, cosb, 32768);
    conv_vec_f32<<<128, 256, 0, stream>>>(sini, sinb, 32768);
    conv_vec_f32<<<4096, 256, 0, stream>>>(x, xb, 1048576);  // x -> bf16
    conv_transpose_f32<<<dim3(96, 32), 256, 0, stream>>>(Wqkv, WqkvT, 2048, 6144);
    gemm8<false><<<384, 512, 0, stream>>>(xb, WqkvT, qkv, 4096, 6144, 2048, 24);
    rope_k<<<4096, 256, 0, stream>>>(qkv, cosb, sinb, Kr);  // overwrites xb (dead)
    transpose_v<<<dim3(32, 2, 32), 256, 0, stream>>>(qkv, Vt);
    flash_q64<<<dim3(32, 32), 256, 0, stream>>>(qkv, cosb, sinb, Kr, Vt, y);
    conv_transpose_f32<<<dim3(32, 32), 256, 0, stream>>>(Wproj, WprojT, 2048, 2048);
    gemm_lds<true><<<dim3(32, 16), 256, 0, stream>>>(y, WprojT, d_out, 4096, 2048, 2048);
  } else if (ws_size >= NEED_BASE) {
    bf16_t* base = (bf16_t*)((char*)d_ws + 256);
    bf16_t* WqkvT = base;
    bf16_t* y = base;
    bf16_t* WprojT = base + 12582912;
    bf16_t* cosb = WprojT + 4194304;
    bf16_t* sinb = cosb + 262144;
    bf16_t* qkv = sinb + 262144;

    conv_vec_f32<<<128, 256, 0, stream>>>(cosi, cosb, 32768);
    conv_vec_f32<<<128, 256, 0, stream>>>(sini, sinb, 32768);
    conv_transpose_f32<<<dim3(96, 32), 256, 0, stream>>>(Wqkv, WqkvT, 2048, 6144);
    gemm_t<true, false><<<dim3(32, 48), 256, 0, stream>>>(x, WqkvT, qkv, 4096, 6144, 2048);
    flash_fused_v2<<<dim3(16, 32), 256, 0, stream>>>(qkv, cosb, sinb, y);
    conv_transpose_f32<<<dim3(32, 32), 256, 0, stream>>>(Wproj, WprojT, 2048, 2048);
    gemm_t<false, true><<<dim3(32, 16), 256, 0, stream>>>(y, WprojT, d_out, 4096, 2048, 2048);
  } else {
    fill_diag<<<(out_size + 255) / 256, 256, 0, stream>>>((uint32_t*)d_out, out_size);
  }
}

// Round 5
// 437.883 us; speedup vs baseline: 1.5834x; 1.0453x over previous
//
#include <hip/hip_runtime.h>
#include <cstdint>
#include <cstddef>

typedef __bf16 bf16_t;
typedef __bf16 bf16x8 __attribute__((ext_vector_type(8)));
typedef __bf16 bf16x4 __attribute__((ext_vector_type(4)));
typedef float f32x4 __attribute__((ext_vector_type(4)));

#define MFMA16(a, b, c) __builtin_amdgcn_mfma_f32_16x16x32_bf16(a, b, c, 0, 0, 0)

// async global->LDS, 16B per lane. LDS dest = wave-uniform base + lane*16.
__device__ __forceinline__ void gll16(const bf16_t* g, bf16_t* l) {
  __builtin_amdgcn_global_load_lds(
      (__attribute__((address_space(1))) uint32_t*)((uintptr_t)g),
      (__attribute__((address_space(3))) uint32_t*)((uint32_t)(uintptr_t)l),
      16, 0, 0);
}

// Diagnostic: absmax ~1000 => ws_size too small.
__global__ void fill_diag(uint32_t* out, int n_u32) {
  int i = blockIdx.x * 256 + threadIdx.x;
  if (i < n_u32) out[i] = 0x447A0000u;  // f32 1000.0
}

// ---------------------------------------------------------------------------
// f32 -> bf16 vector convert (x, cos/sin tables). One bf16x8 per thread.
// ---------------------------------------------------------------------------
__global__ void conv_vec_f32(const float* __restrict__ in, bf16_t* __restrict__ out,
                             int n8) {
  const int i = blockIdx.x * 256 + threadIdx.x;
  if (i >= n8) return;
  const float* p = in + (size_t)i * 8;
  const f32x4 a = *(const f32x4*)p;
  const f32x4 b = *(const f32x4*)(p + 4);
  bf16x8 o;
#pragma unroll
  for (int j = 0; j < 4; ++j) {
    o[j] = (bf16_t)a[j];
    o[4 + j] = (bf16_t)b[j];
  }
  ((bf16x8*)out)[i] = o;
}

// ---------------------------------------------------------------------------
// 64x64 tiled transpose+convert: in R x C f32 -> out C x R bf16.
// ---------------------------------------------------------------------------
__global__ __launch_bounds__(256) void conv_transpose_f32(
    const float* __restrict__ in, bf16_t* __restrict__ out, int R, int C) {
  __shared__ bf16_t tile[64][72];
  const int bc = blockIdx.x * 64;
  const int br = blockIdx.y * 64;
  const int t = threadIdx.x;
  const int r = t >> 3;
  const int c8 = (t & 7) * 8;
#pragma unroll
  for (int ii = 0; ii < 2; ++ii) {
    const int rr = r + ii * 32;
    const float* p = in + (size_t)(br + rr) * C + bc + c8;
    const f32x4 a = *(const f32x4*)p;
    const f32x4 b = *(const f32x4*)(p + 4);
    bf16x8 v;
#pragma unroll
    for (int j = 0; j < 4; ++j) {
      v[j] = (bf16_t)a[j];
      v[4 + j] = (bf16_t)b[j];
    }
    *(bf16x8*)(&tile[rr][c8]) = v;
  }
  __syncthreads();
#pragma unroll
  for (int ii = 0; ii < 2; ++ii) {
    const int rr = r + ii * 32;
    bf16x8 o;
#pragma unroll
    for (int jj = 0; jj < 8; ++jj) o[jj] = tile[c8 + jj][rr];
    *(bf16x8*)(out + (size_t)(bc + rr) * R + br + c8) = o;
  }
}

// ---------------------------------------------------------------------------
// 256x256 8-phase GEMM (HK-style template, plain HIP). See round-0 notes.
// ---------------------------------------------------------------------------
#define MF8(MLO, AARR, BARR, NLO)                                           \
  do {                                                                      \
    _Pragma("unroll") for (int m_ = 0; m_ < 4; ++m_) {                      \
      _Pragma("unroll") for (int n_ = 0; n_ < 2; ++n_) {                    \
        acc[(MLO) + m_][(NLO) + n_] =                                       \
            MFMA16(AARR[m_][0], BARR[n_][0], acc[(MLO) + m_][(NLO) + n_]);  \
        acc[(MLO) + m_][(NLO) + n_] =                                       \
            MFMA16(AARR[m_][1], BARR[n_][1], acc[(MLO) + m_][(NLO) + n_]);  \
      }                                                                     \
    }                                                                       \
  } while (0)

template <bool C32>
__global__ __launch_bounds__(512, 2) void gemm8(
    const bf16_t* __restrict__ A, const bf16_t* __restrict__ Bt,
    void* __restrict__ C, int M, int N, int K, int nbn) {
  __shared__ __align__(1024) bf16_t lds8[65536];  // A: [0,32768), B: [32768,65536)
  bf16_t* As = lds8;
  bf16_t* Bs = lds8 + 32768;

  const int tid = threadIdx.x;
  const int lane = tid & 63;
  const int wave = tid >> 6;
  const int wr = wave >> 2;  // 0..1 (M half)
  const int wc = wave & 3;   // 0..3 (N quarter)
  const int fr = lane & 15;
  const int fg = lane >> 4;

  // XCD-aware bijective swizzle (nwg % 8 == 0 by construction).
  const int nwg = gridDim.x;
  const int bid = blockIdx.x;
  const int swz = (bid & 7) * (nwg >> 3) + (bid >> 3);
  const int m0 = (swz / nbn) * 256;
  const int n0 = (swz % nbn) * 256;

  const int NT = K >> 6;  // BK=64 tiles (assumed even; K=2048 -> 32)

  // staging geometry: wave covers segs {2w, 2w+1}; seg = 8 rows of 128B.
  const int sseg0 = wave * 2;
  const int srow = lane >> 3;
  const int sj = lane & 7;

  auto stage = [&](const bf16_t* __restrict__ G, int row0, bf16_t* L, int kt,
                   int h) {
#pragma unroll
    for (int l = 0; l < 2; ++l) {
      const int seg = sseg0 + l;
      const int r = seg * 8 + srow;       // row in half-tile 0..127
      const int j = sj ^ (r & 7);         // inverse-swizzled source chunk
      const bf16_t* src = G + (size_t)(row0 + h * 128 + r) * K + kt * 64 + j * 8;
      gll16(src, L + ((2 * kt + h) & 3) * 8192 + seg * 512 + lane * 8);
    }
  };

  const int cb0 = (fg * 16) ^ ((fr & 7) << 4);  // kk=0 byte col (swizzled)

  auto lda = [&](bf16x8(&af)[4][2], int kt, int mlo) {
    const char* base = (const char*)(As + ((2 * kt + wr) & 3) * 8192);
#pragma unroll
    for (int m = 0; m < 4; ++m) {
      const char* p = base + ((mlo + m) * 16 + fr) * 128;
      af[m][0] = *(const bf16x8*)(p + cb0);
      af[m][1] = *(const bf16x8*)(p + (cb0 ^ 64));
    }
  };
  auto ldb = [&](bf16x8(&bf)[2][2], int kt, int nlo) {
    const char* base = (const char*)(Bs + ((2 * kt + (wc >> 1)) & 3) * 8192);
#pragma unroll
    for (int n = 0; n < 2; ++n) {
      const char* p = base + ((wc & 1) * 64 + (nlo + n) * 16 + fr) * 128;
      bf[n][0] = *(const bf16x8*)(p + cb0);
      bf[n][1] = *(const bf16x8*)(p + (cb0 ^ 64));
    }
  };

  f32x4 acc[8][4] = {};

  // Prologue: A(0), B(0), B(1); drain A(0)+B(0), keep B(1) in flight.
  stage(A, m0, As, 0, 0);
  stage(A, m0, As, 0, 1);
  stage(Bt, n0, Bs, 0, 0);
  stage(Bt, n0, Bs, 0, 1);
  stage(Bt, n0, Bs, 1, 0);
  stage(Bt, n0, Bs, 1, 1);
  asm volatile("s_waitcnt vmcnt(4)" ::: "memory");
  __builtin_amdgcn_s_barrier();

  bf16x8 af[4][2], bfA[2][2], bfB[2][2];

  for (int u = 0; u < NT; u += 2) {
    const bool st2 = (u + 2 < NT);
    const bool st3 = (u + 3 < NT);
    // ---------------- tile u ----------------
    lda(af, u, 0);
    ldb(bfA, u, 0);
    stage(A, m0, As, u + 1, 0);
    asm volatile("s_waitcnt lgkmcnt(8)" ::: "memory");
    __builtin_amdgcn_s_barrier();
    asm volatile("s_waitcnt lgkmcnt(0)" ::: "memory");
    __builtin_amdgcn_sched_barrier(0);
    __builtin_amdgcn_s_setprio(1);
    MF8(0, af, bfA, 0);
    __builtin_amdgcn_s_setprio(0);
    __builtin_amdgcn_s_barrier();
    ldb(bfB, u, 2);
    stage(A, m0, As, u + 1, 1);
    __builtin_amdgcn_s_barrier();
    asm volatile("s_waitcnt lgkmcnt(0)" ::: "memory");
    __builtin_amdgcn_sched_barrier(0);
    __builtin_amdgcn_s_setprio(1);
    MF8(0, af, bfB, 2);
    __builtin_amdgcn_s_setprio(0);
    __builtin_amdgcn_s_barrier();
    lda(af, u, 4);
    if (st2) stage(Bt, n0, Bs, u + 2, 0);
    __builtin_amdgcn_s_barrier();
    asm volatile("s_waitcnt lgkmcnt(0)" ::: "memory");
    __builtin_amdgcn_sched_barrier(0);
    __builtin_amdgcn_s_setprio(1);
    MF8(4, af, bfB, 2);
    __builtin_amdgcn_s_setprio(0);
    __builtin_amdgcn_s_barrier();
    if (st2) stage(Bt, n0, Bs, u + 2, 1);
    __builtin_amdgcn_s_barrier();
    __builtin_amdgcn_s_setprio(1);
    MF8(4, af, bfA, 0);
    __builtin_amdgcn_s_setprio(0);
    asm volatile("s_waitcnt vmcnt(4)" ::: "memory");
    __builtin_amdgcn_s_barrier();
    // ---------------- tile u+1 ----------------
    lda(af, u + 1, 0);
    ldb(bfA, u + 1, 0);
    if (st2) stage(A, m0, As, u + 2, 0);
    asm volatile("s_waitcnt lgkmcnt(8)" ::: "memory");
    __builtin_amdgcn_s_barrier();
    asm volatile("s_waitcnt lgkmcnt(0)" ::: "memory");
    __builtin_amdgcn_sched_barrier(0);
    __builtin_amdgcn_s_setprio(1);
    MF8(0, af, bfA, 0);
    __builtin_amdgcn_s_setprio(0);
    __builtin_amdgcn_s_barrier();
    ldb(bfB, u + 1, 2);
    if (st2) stage(A, m0, As, u + 2, 1);
    __builtin_amdgcn_s_barrier();
    asm volatile("s_waitcnt lgkmcnt(0)" ::: "memory");
    __builtin_amdgcn_sched_barrier(0);
    __builtin_amdgcn_s_setprio(1);
    MF8(0, af, bfB, 2);
    __builtin_amdgcn_s_setprio(0);
    __builtin_amdgcn_s_barrier();
    lda(af, u + 1, 4);
    if (st3) stage(Bt, n0, Bs, u + 3, 0);
    __builtin_amdgcn_s_barrier();
    asm volatile("s_waitcnt lgkmcnt(0)" ::: "memory");
    __builtin_amdgcn_sched_barrier(0);
    __builtin_amdgcn_s_setprio(1);
    MF8(4, af, bfB, 2);
    __builtin_amdgcn_s_setprio(0);
    __builtin_amdgcn_s_barrier();
    if (st3) stage(Bt, n0, Bs, u + 3, 1);
    __builtin_amdgcn_s_barrier();
    __builtin_amdgcn_s_setprio(1);
    MF8(4, af, bfA, 0);
    __builtin_amdgcn_s_setprio(0);
    asm volatile("s_waitcnt vmcnt(4)" ::: "memory");
    __builtin_amdgcn_s_barrier();
  }

#pragma unroll
  for (int m = 0; m < 8; ++m) {
#pragma unroll
    for (int n = 0; n < 4; ++n) {
#pragma unroll
      for (int r = 0; r < 4; ++r) {
        const int row = m0 + wr * 128 + m * 16 + fg * 4 + r;
        const int col = n0 + wc * 64 + n * 16 + fr;
        const size_t idx = (size_t)row * N + col;
        if (C32)
          ((float*)C)[idx] = acc[m][n][r];
        else
          ((bf16_t*)C)[idx] = (bf16_t)acc[m][n][r];
      }
    }
  }
  (void)M;
}

// ---------------------------------------------------------------------------
// m97-style GEMM: kept for proj GEMM (N=2048 -> 256^2 grid only 128 blocks).
// ---------------------------------------------------------------------------
template <bool C32>
__global__ __launch_bounds__(256) void gemm_lds(
    const bf16_t* __restrict__ A, const bf16_t* __restrict__ Bt,
    void* __restrict__ C, int M, int N, int K) {
  __shared__ __align__(16) bf16_t As[128 * 32];
  __shared__ __align__(16) bf16_t Bs[128 * 32];
  const int tid = threadIdx.x;
  const int lane = tid & 63;
  const int wave = tid >> 6;
  const int m0 = blockIdx.x * 128;
  const int n0 = blockIdx.y * 128;
  const int wm = (wave & 1) * 64;
  const int wn = (wave >> 1) * 64;
  const int fr = lane & 15;
  const int fk = (lane >> 4) * 8;

  f32x4 acc[4][4] = {};

  const bf16_t* ga = A + (size_t)(m0 + (tid >> 2)) * K + (tid & 3) * 8;
  const bf16_t* gb = Bt + (size_t)(n0 + (tid >> 2)) * K + (tid & 3) * 8;
  bf16_t* lA = As + tid * 8;
  bf16_t* lB = Bs + tid * 8;
  const size_t half = (size_t)64 * K;

  for (int k0 = 0; k0 < K; k0 += 32) {
    __syncthreads();
    gll16(ga, lA);
    gll16(ga + half, lA + 2048);
    gll16(gb, lB);
    gll16(gb + half, lB + 2048);
    ga += 32;
    gb += 32;
    __syncthreads();
    bf16x8 af[4], bfr[4];
#pragma unroll
    for (int i = 0; i < 4; ++i)
      af[i] = *(const bf16x8*)(As + (wm + i * 16 + fr) * 32 + fk);
#pragma unroll
    for (int j = 0; j < 4; ++j)
      bfr[j] = *(const bf16x8*)(Bs + (wn + j * 16 + fr) * 32 + fk);
#pragma unroll
    for (int i = 0; i < 4; ++i)
#pragma unroll
      for (int j = 0; j < 4; ++j)
        acc[i][j] = MFMA16(af[i], bfr[j], acc[i][j]);
  }

  const int fg = lane >> 4;
#pragma unroll
  for (int i = 0; i < 4; ++i) {
#pragma unroll
    for (int j = 0; j < 4; ++j) {
#pragma unroll
      for (int r = 0; r < 4; ++r) {
        const int row = m0 + wm + i * 16 + fg * 4 + r;
        const int col = n0 + wn + j * 16 + fr;
        const size_t idx = (size_t)row * N + col;
        if (C32)
          ((float*)C)[idx] = acc[i][j][r];
        else
          ((bf16_t*)C)[idx] = (bf16_t)acc[i][j][r];
      }
    }
  }
}

// ---------------------------------------------------------------------------
// Register-staged GEMM (fallback path only): A f32 option, C f32 option.
// ---------------------------------------------------------------------------
template <bool A32, bool C32>
__global__ __launch_bounds__(256) void gemm_t(
    const void* __restrict__ A, const bf16_t* __restrict__ Bt,
    void* __restrict__ C, int M, int N, int K) {
  __shared__ bf16_t As[128 * 32];
  __shared__ bf16_t Bs[128 * 32];
  const int tid = threadIdx.x;
  const int lane = tid & 63;
  const int wave = tid >> 6;
  const int m0 = blockIdx.x * 128;
  const int n0 = blockIdx.y * 128;
  const int wm = (wave & 1) * 64;
  const int wn = (wave >> 1) * 64;
  const int fr = lane & 15;
  const int fk = (lane >> 4) * 8;

  f32x4 acc[4][4] = {};

  const size_t ea0 = (size_t)(m0 + (tid >> 2)) * K + (tid & 3) * 8;
  const bf16_t* gb = Bt + (size_t)(n0 + (tid >> 2)) * K + (tid & 3) * 8;
  bf16_t* lA = As + tid * 8;
  bf16_t* lB = Bs + tid * 8;
  const size_t half = (size_t)64 * K;

  for (int k0 = 0; k0 < K; k0 += 32) {
    bf16x8 ra0, ra1;
    if (A32) {
      const float* pa = (const float*)A + ea0 + k0;
      const f32x4 x0 = *(const f32x4*)pa;
      const f32x4 x1 = *(const f32x4*)(pa + 4);
      const f32x4 x2 = *(const f32x4*)(pa + half);
      const f32x4 x3 = *(const f32x4*)(pa + half + 4);
#pragma unroll
      for (int j = 0; j < 4; ++j) {
        ra0[j] = (bf16_t)x0[j];
        ra0[4 + j] = (bf16_t)x1[j];
        ra1[j] = (bf16_t)x2[j];
        ra1[4 + j] = (bf16_t)x3[j];
      }
    } else {
      const bf16_t* pa = (const bf16_t*)A + ea0 + k0;
      ra0 = *(const bf16x8*)pa;
      ra1 = *(const bf16x8*)(pa + half);
    }
    const bf16x8 rb0 = *(const bf16x8*)gb;
    const bf16x8 rb1 = *(const bf16x8*)(gb + half);
    gb += 32;
    __syncthreads();
    *(bf16x8*)lA = ra0;
    *(bf16x8*)(lA + 2048) = ra1;
    *(bf16x8*)lB = rb0;
    *(bf16x8*)(lB + 2048) = rb1;
    __syncthreads();
    bf16x8 af[4], bfr[4];
#pragma unroll
    for (int i = 0; i < 4; ++i)
      af[i] = *(const bf16x8*)(As + (wm + i * 16 + fr) * 32 + fk);
#pragma unroll
    for (int j = 0; j < 4; ++j)
      bfr[j] = *(const bf16x8*)(Bs + (wn + j * 16 + fr) * 32 + fk);
#pragma unroll
    for (int i = 0; i < 4; ++i)
#pragma unroll
      for (int j = 0; j < 4; ++j)
        acc[i][j] = MFMA16(af[i], bfr[j], acc[i][j]);
  }

  const int fg = lane >> 4;
#pragma unroll
  for (int i = 0; i < 4; ++i) {
#pragma unroll
    for (int j = 0; j < 4; ++j) {
#pragma unroll
      for (int r = 0; r < 4; ++r) {
        const int row = m0 + wm + i * 16 + fg * 4 + r;
        const int col = n0 + wn + j * 16 + fr;
        const size_t idx = (size_t)row * N + col;
        if (C32)
          ((float*)C)[idx] = acc[i][j][r];
        else
          ((bf16_t*)C)[idx] = (bf16_t)acc[i][j][r];
      }
    }
  }
}

// ---------------------------------------------------------------------------
// K rope extract: qkv (B*T,6144) -> Kr (B,H,T,D) bf16 rope'd.
// ---------------------------------------------------------------------------
__global__ __launch_bounds__(256) void rope_k(
    const bf16_t* __restrict__ qkv, const bf16_t* __restrict__ cosb,
    const bf16_t* __restrict__ sinb, bf16_t* __restrict__ Kr) {
  const int row = blockIdx.x;  // b*2048 + t
  const int t = row & 2047;
  const int b = row >> 11;
  const int idx = threadIdx.x * 8;
  const int h = idx >> 7;
  const int d = idx & 127;
  const float sgn = (d < 64) ? -1.f : 1.f;
  const bf16_t* base = qkv + (size_t)row * 6144 + 2048;
  const bf16x8 kv = *(const bf16x8*)(base + idx);
  const bf16x8 kp = *(const bf16x8*)(base + (idx ^ 64));
  const bf16x8 cv = *(const bf16x8*)(cosb + t * 128 + d);
  const bf16x8 sv = *(const bf16x8*)(sinb + t * 128 + d);
  bf16x8 o;
#pragma unroll
  for (int jj = 0; jj < 8; ++jj)
    o[jj] = (bf16_t)(((float)kv[jj]) * ((float)cv[jj]) +
                     sgn * ((float)kp[jj]) * ((float)sv[jj]));
  *(bf16x8*)(Kr + ((size_t)(b * 16 + h) * 2048 + t) * 128 + d) = o;
}

// ---------------------------------------------------------------------------
// V extract + transpose: qkv cols 4096.. -> Vt (B,H,D,T).
// ---------------------------------------------------------------------------
__global__ __launch_bounds__(256) void transpose_v(
    const bf16_t* __restrict__ qkv, bf16_t* __restrict__ Vt) {
  __shared__ bf16_t tile[64][72];
  const int bh = blockIdx.z;
  const int b = bh >> 4, h = bh & 15;
  const int t0 = blockIdx.x * 64;
  const int d0 = blockIdx.y * 64;
  const int t = threadIdx.x;
  const int r = t >> 3;
  const int c8 = (t & 7) * 8;
#pragma unroll
  for (int ii = 0; ii < 2; ++ii) {
    const int rr = r + ii * 32;
    *(bf16x8*)(&tile[rr][c8]) =
        *(const bf16x8*)(qkv + (size_t)(b * 2048 + t0 + rr) * 6144 + 4096 + h * 128 + d0 + c8);
  }
  __syncthreads();
#pragma unroll
  for (int ii = 0; ii < 2; ++ii) {
    const int rr = r + ii * 32;
    bf16x8 o;
#pragma unroll
    for (int jj = 0; jj < 8; ++jj) o[jj] = tile[c8 + jj][rr];
    *(bf16x8*)(Vt + ((size_t)bh * 128 + d0 + rr) * 2048 + t0 + c8) = o;
  }
}

// ---------------------------------------------------------------------------
// Flash round-5: round-4 structure (QBLK=64, swapped QK^T, in-register P,
// π-permuted Vs) + three fixes:
//  (1) K staged via global_load_lds into UNPADDED Ks[64][128] with rule-#21
//      both-sides XOR involution: source chunk ^= (row&7), read byte-col
//      ^= (fr&7)<<4  -> kf reads <=2-way bank (free), no ds_write for K.
//  (2) Software pipeline: K(j+1) DMA + V(j+1) reg loads issued right after
//      the post-QK^T barrier (Ks dead), landing under exp+PV; vmcnt(0) at
//      tile end only.
//  (3) Vs write deferred to after PV (own barrier), T14 style.
// ---------------------------------------------------------------------------
__global__ __launch_bounds__(256, 4) void flash_q64p(
    const bf16_t* __restrict__ qkv, const bf16_t* __restrict__ cosb,
    const bf16_t* __restrict__ sinb, const bf16_t* __restrict__ Kr,
    const bf16_t* __restrict__ Vt, bf16_t* __restrict__ Y) {
  constexpr int T = 2048;
  __shared__ __align__(1024) bf16_t Ks[64 * 128];  // swizzled linear tile
  __shared__ bf16_t Vs[128][72];
  const int tid = threadIdx.x;
  const int lane = tid & 63;
  const int fr = lane & 15;
  const int fg = lane >> 4;
  const int qt = blockIdx.x;  // 0..31, 64 q-rows each
  const int bh = blockIdx.y;
  const int b = bh >> 4, h = bh & 15;

  // Q rope'd on the fly; scale = rsqrt(128) * log2(e) folded in.
  const int wave = tid >> 6;
  const int trow = qt * 64 + wave * 16 + fr;
  const bf16_t* qrow = qkv + (size_t)(b * T + trow) * 6144 + h * 128;
  bf16x8 qf[4];
#pragma unroll
  for (int ks = 0; ks < 4; ++ks) {
    const int d = ks * 32 + fg * 8;
    const float sgn = (d < 64) ? -1.f : 1.f;
    const bf16x8 qv = *(const bf16x8*)(qrow + d);
    const bf16x8 qp = *(const bf16x8*)(qrow + (d ^ 64));
    const bf16x8 cv = *(const bf16x8*)(cosb + trow * 128 + d);
    const bf16x8 sv = *(const bf16x8*)(sinb + trow * 128 + d);
    bf16x8 o;
#pragma unroll
    for (int jj = 0; jj < 8; ++jj)
      o[jj] = (bf16_t)((((float)qv[jj]) * ((float)cv[jj]) +
                        sgn * ((float)qp[jj]) * ((float)sv[jj])) *
                       0.1275174825f);  // (1/sqrt(128)) * log2(e)
    qf[ks] = o;
  }

  f32x4 acc[8] = {};
  float l_i = 0.f;

  // K staging: thread covers row r = it*16 + (tid>>4), source chunk
  // pre-swizzled sc = (tid&15) ^ (r&7); LDS dest linear tid*16B per it.
  const int krow = tid >> 4;                    // 0..15
  const int sc = (tid & 15) ^ (krow & 7);       // (r&7) == (krow&7) for all it
  // V staging geometry (reg-staged, π-permuted columns)
  const int vrow = tid >> 3;        // 0..31 (d rows, +32*it)
  const int vu = tid & 7;           // t-chunk index (8 consecutive t)
  const int vc0 = ((vu >> 2) * 32) + ((vu & 1) * 16) + (((vu >> 1) & 1) * 4);
  const bf16_t* Kh = Kr + (size_t)bh * T * 128;
  const bf16_t* Vh = Vt + (size_t)bh * 128 * T;

  auto stageK = [&](int t0) {
#pragma unroll
    for (int it = 0; it < 4; ++it)
      gll16(Kh + (size_t)(t0 + it * 16 + krow) * 128 + sc * 8,
            Ks + it * 2048 + tid * 8);
  };
  bf16x8 vreg[4];
  auto loadV = [&](int t0) {
#pragma unroll
    for (int it = 0; it < 4; ++it)
      vreg[it] = *(const bf16x8*)(Vh + (size_t)(it * 32 + vrow) * T + t0 + vu * 8);
  };
  auto writeV = [&]() {
#pragma unroll
    for (int it = 0; it < 4; ++it) {
      const int row = it * 32 + vrow;
      const bf16x8 v = vreg[it];
      bf16x4 lo, hi;
#pragma unroll
      for (int jj = 0; jj < 4; ++jj) {
        lo[jj] = v[jj];
        hi[jj] = v[4 + jj];
      }
      *(bf16x4*)(&Vs[row][vc0]) = lo;      // t = base+0..3  (b2=0)
      *(bf16x4*)(&Vs[row][vc0 + 8]) = hi;  // t = base+4..7  (b2=1)
    }
  };

  // prologue: stage tile 0
  stageK(0);
  loadV(0);
  asm volatile("s_waitcnt vmcnt(0)" ::: "memory");
  __builtin_amdgcn_sched_barrier(0);
  writeV();
  __syncthreads();

  const int cswz = (fr & 7) << 4;  // read-side XOR for Ks
  const char* kbase = (const char*)Ks;

  for (int j = 0; j < T / 64; ++j) {
    // QK^T swapped: lane holds P[q=fr][k=n*16+fg*4+r]
    f32x4 sacc[4] = {};
#pragma unroll
    for (int n = 0; n < 4; ++n) {
      const char* krowp = kbase + (n * 16 + fr) * 256;
#pragma unroll
      for (int ks = 0; ks < 4; ++ks) {
        const bf16x8 kf = *(const bf16x8*)(krowp + ((ks * 64 + fg * 16) ^ cswz));
        sacc[n] = MFMA16(kf, qf[ks], sacc[n]);
      }
    }
    __syncthreads();  // Ks consumed by all waves

    const bool more = (j + 1 < T / 64);
    if (more) {
      stageK((j + 1) * 64);  // DMA into Ks (dead) while exp+PV run
      loadV((j + 1) * 64);
    }

    // exp + in-register pack into PV A-fragments:
    // paf[ks2][jj] = P[q=fr][k = (2*ks2+(jj>>2))*16 + fg*4 + (jj&3)]
    bf16x8 paf[2];
    float lsum = 0.f;
#pragma unroll
    for (int ks2 = 0; ks2 < 2; ++ks2) {
#pragma unroll
      for (int jj = 0; jj < 8; ++jj) {
        const float p = exp2f(sacc[ks2 * 2 + (jj >> 2)][jj & 3]);
        lsum += p;
        paf[ks2][jj] = (bf16_t)p;
      }
    }
    l_i += lsum;

    // PV: Vs column order matches paf's k order by construction.
#pragma unroll
    for (int ks2 = 0; ks2 < 2; ++ks2) {
#pragma unroll
      for (int n = 0; n < 8; ++n) {
        const bf16x8 vf = *(const bf16x8*)(&Vs[n * 16 + fr][ks2 * 32 + fg * 8]);
        acc[n] = MFMA16(paf[ks2], vf, acc[n]);
      }
    }

    asm volatile("s_waitcnt vmcnt(0)" ::: "memory");  // K DMA + V regs landed
    __builtin_amdgcn_sched_barrier(0);
    __syncthreads();  // Vs consumed by all; Ks(j+1) visible
    if (more) {
      writeV();
      __syncthreads();  // Vs(j+1) ready
    }
  }

  // epilogue: l reduce across fg groups (lanes fr, fr+16, fr+32, fr+48 hold
  // disjoint k-subsets of q=fr), then fetch 1/l for this lane's output rows.
  float l = l_i;
  l += __shfl_xor(l, 16, 64);
  l += __shfl_xor(l, 32, 64);  // lanes with same fr now hold l_full(q=fr)
#pragma unroll
  for (int r = 0; r < 4; ++r) {
    const float inv = 1.0f / __shfl(l, fg * 4 + r, 64);
    const int t = qt * 64 + wave * 16 + fg * 4 + r;
    bf16_t* yrow = Y + (size_t)(b * T + t) * 2048 + h * 128;
#pragma unroll
    for (int n = 0; n < 8; ++n)
      yrow[n * 16 + fr] = (bf16_t)(acc[n][r] * inv);
  }
}

// ---------------------------------------------------------------------------
// Flash fallback (ws-lean): fused rope, exp-only softmax. (unchanged)
// ---------------------------------------------------------------------------
__global__ __launch_bounds__(256) void flash_fused_v2(
    const bf16_t* __restrict__ qkv, const bf16_t* __restrict__ cosb,
    const bf16_t* __restrict__ sinb, bf16_t* __restrict__ Y) {
  constexpr int T = 2048;
  __shared__ bf16_t Ks[64][136];
  __shared__ bf16_t Vs[128][72];
  __shared__ bf16_t Ps[128][72];
  const int tid = threadIdx.x;
  const int lane = tid & 63;
  const int wave = tid >> 6;
  const int fr = lane & 15;
  const int fg = lane >> 4;
  const int qt = blockIdx.x;
  const int bh = blockIdx.y;
  const int b = bh >> 4, h = bh & 15;

  const bf16_t* qbase = qkv + (size_t)b * T * 6144 + h * 128;
  bf16x8 qf[2][4];
#pragma unroll
  for (int i = 0; i < 2; ++i) {
    const int trow = qt * 128 + wave * 32 + i * 16 + fr;
    const bf16_t* qrow = qbase + (size_t)trow * 6144;
#pragma unroll
    for (int ks = 0; ks < 4; ++ks) {
      const int d = ks * 32 + fg * 8;
      const float sgn = (d < 64) ? -1.f : 1.f;
      const bf16x8 qv = *(const bf16x8*)(qrow + d);
      const bf16x8 qp = *(const bf16x8*)(qrow + (d ^ 64));
      const bf16x8 cv = *(const bf16x8*)(cosb + trow * 128 + d);
      const bf16x8 sv = *(const bf16x8*)(sinb + trow * 128 + d);
      bf16x8 o;
#pragma unroll
      for (int jj = 0; jj < 8; ++jj)
        o[jj] = (bf16_t)((((float)qv[jj]) * ((float)cv[jj]) +
                          sgn * ((float)qp[jj]) * ((float)sv[jj])) *
                         0.08838834764831845f);
      qf[i][ks] = o;
    }
  }

  f32x4 acc[2][8] = {};
  float l_i[2][4] = {};

  const int kr = tid >> 4;
  const int kc = (tid & 15) * 8;
  const float sgnk = (kc < 64) ? -1.f : 1.f;
  const int tp = tid & 63;

  for (int j = 0; j < T / 64; ++j) {
    const int t0 = j * 64;
#pragma unroll
    for (int it = 0; it < 4; ++it) {
      const int row = it * 16 + kr;
      const int tg = t0 + row;
      const bf16_t* krow = qkv + ((size_t)(b * T + tg)) * 6144 + 2048 + h * 128;
      const bf16x8 kv = *(const bf16x8*)(krow + kc);
      const bf16x8 kp = *(const bf16x8*)(krow + (kc ^ 64));
      const bf16x8 cv = *(const bf16x8*)(cosb + tg * 128 + kc);
      const bf16x8 sv = *(const bf16x8*)(sinb + tg * 128 + kc);
      bf16x8 o;
#pragma unroll
      for (int jj = 0; jj < 8; ++jj)
        o[jj] = (bf16_t)(((float)kv[jj]) * ((float)cv[jj]) +
                         sgnk * ((float)kp[jj]) * ((float)sv[jj]));
      *(bf16x8*)(&Ks[row][kc]) = o;
    }
#pragma unroll
    for (int cc = 0; cc < 4; ++cc) {
      const int d8 = (cc * 4 + (tid >> 6)) * 8;
      const bf16x8 vv = *(const bf16x8*)(qkv + ((size_t)(b * T + t0 + tp)) * 6144 +
                                         4096 + h * 128 + d8);
#pragma unroll
      for (int jj = 0; jj < 8; ++jj) Vs[d8 + jj][tp] = vv[jj];
    }
    __syncthreads();

    f32x4 sacc[2][4] = {};
#pragma unroll
    for (int n = 0; n < 4; ++n) {
#pragma unroll
      for (int ks = 0; ks < 4; ++ks) {
        const bf16x8 kf = *(const bf16x8*)(&Ks[n * 16 + fr][ks * 32 + fg * 8]);
        sacc[0][n] = MFMA16(qf[0][ks], kf, sacc[0][n]);
        sacc[1][n] = MFMA16(qf[1][ks], kf, sacc[1][n]);
      }
    }

#pragma unroll
    for (int i = 0; i < 2; ++i) {
#pragma unroll
      for (int r = 0; r < 4; ++r) {
        const float p0 = __expf(sacc[i][0][r]);
        const float p1 = __expf(sacc[i][1][r]);
        const float p2 = __expf(sacc[i][2][r]);
        const float p3 = __expf(sacc[i][3][r]);
        l_i[i][r] += (p0 + p1) + (p2 + p3);
        const int prow = wave * 32 + i * 16 + fg * 4 + r;
        Ps[prow][0 + fr] = (bf16_t)p0;
        Ps[prow][16 + fr] = (bf16_t)p1;
        Ps[prow][32 + fr] = (bf16_t)p2;
        Ps[prow][48 + fr] = (bf16_t)p3;
      }
    }

#pragma unroll
    for (int ks = 0; ks < 2; ++ks) {
      const bf16x8 pf0 = *(const bf16x8*)(&Ps[wave * 32 + fr][ks * 32 + fg * 8]);
      const bf16x8 pf1 = *(const bf16x8*)(&Ps[wave * 32 + 16 + fr][ks * 32 + fg * 8]);
#pragma unroll
      for (int n = 0; n < 8; ++n) {
        const bf16x8 vf = *(const bf16x8*)(&Vs[n * 16 + fr][ks * 32 + fg * 8]);
        acc[0][n] = MFMA16(pf0, vf, acc[0][n]);
        acc[1][n] = MFMA16(pf1, vf, acc[1][n]);
      }
    }
    __syncthreads();
  }

#pragma unroll
  for (int i = 0; i < 2; ++i) {
#pragma unroll
    for (int r = 0; r < 4; ++r) {
      float l = l_i[i][r];
#pragma unroll
      for (int msk = 1; msk < 16; msk <<= 1) l += __shfl_xor(l, msk, 64);
      const float inv = 1.0f / l;
      const int t = qt * 128 + wave * 32 + i * 16 + fg * 4 + r;
      bf16_t* yrow = Y + (size_t)(b * T + t) * 2048 + h * 128;
#pragma unroll
      for (int n = 0; n < 8; ++n)
        yrow[n * 16 + fr] = (bf16_t)(acc[i][n][r] * inv);
    }
  }
}

// ---------------------------------------------------------------------------
extern "C" void kernel_launch(void* const* d_in, const int* in_sizes, int n_in,
                              void* d_out, int out_size, void* d_ws, size_t ws_size,
                              hipStream_t stream) {
  const float* x = (const float*)d_in[0];
  const float* cosi = (const float*)d_in[1];
  const float* sini = (const float*)d_in[2];
  const float* Wqkv = (const float*)d_in[3];
  const float* Wproj = (const float*)d_in[4];

  const size_t NEED_FAST = sizeof(bf16_t) *
      ((size_t)12582912 + 262144 + 262144 + 25165824 + 8388608 + 8388608);
  const size_t NEED_BASE = 256 + sizeof(bf16_t) *
      ((size_t)12582912 + 4194304 + 262144 + 262144 + 25165824);

  if (ws_size >= NEED_FAST) {
    bf16_t* base = (bf16_t*)d_ws;
    bf16_t* WqkvT = base;                    // dead after gemm1
    bf16_t* y = base;                        // alias
    bf16_t* cosb = base + 12582912;
    bf16_t* sinb = cosb + 262144;
    bf16_t* qkv = sinb + 262144;             // live through flash
    bf16_t* WprojT = qkv;                    // alias head, written after flash
    bf16_t* Kr = qkv + 25165824;
    bf16_t* xb = Kr;                         // alias: x-bf16, dead before rope_k
    bf16_t* Vt = Kr + 8388608;

    conv_vec_f32<<<128, 256, 0, stream>>>(cosi, cosb, 32768);
    conv_vec_f32<<<128, 256, 0, stream>>>(sini, sinb, 32768);
    conv_vec_f32<<<4096, 256, 0, stream>>>(x, xb, 1048576);  // x -> bf16
    conv_transpose_f32<<<dim3(96, 32), 256, 0, stream>>>(Wqkv, WqkvT, 2048, 6144);
    gemm8<false><<<384, 512, 0, stream>>>(xb, WqkvT, qkv, 4096, 6144, 2048, 24);
    rope_k<<<4096, 256, 0, stream>>>(qkv, cosb, sinb, Kr);  // overwrites xb (dead)
    transpose_v<<<dim3(32, 2, 32), 256, 0, stream>>>(qkv, Vt);
    flash_q64p<<<dim3(32, 32), 256, 0, stream>>>(qkv, cosb, sinb, Kr, Vt, y);
    conv_transpose_f32<<<dim3(32, 32), 256, 0, stream>>>(Wproj, WprojT, 2048, 2048);
    gemm_lds<true><<<dim3(32, 16), 256, 0, stream>>>(y, WprojT, d_out, 4096, 2048, 2048);
  } else if (ws_size >= NEED_BASE) {
    bf16_t* base = (bf16_t*)((char*)d_ws + 256);
    bf16_t* WqkvT = base;
    bf16_t* y = base;
    bf16_t* WprojT = base + 12582912;
    bf16_t* cosb = WprojT + 4194304;
    bf16_t* sinb = cosb + 262144;
    bf16_t* qkv = sinb + 262144;

    conv_vec_f32<<<128, 256, 0, stream>>>(cosi, cosb, 32768);
    conv_vec_f32<<<128, 256, 0, stream>>>(sini, sinb, 32768);
    conv_transpose_f32<<<dim3(96, 32), 256, 0, stream>>>(Wqkv, WqkvT, 2048, 6144);
    gemm_t<true, false><<<dim3(32, 48), 256, 0, stream>>>(x, WqkvT, qkv, 4096, 6144, 2048);
    flash_fused_v2<<<dim3(16, 32), 256, 0, stream>>>(qkv, cosb, sinb, y);
    conv_transpose_f32<<<dim3(32, 32), 256, 0, stream>>>(Wproj, WprojT, 2048, 2048);
    gemm_t<false, true><<<dim3(32, 16), 256, 0, stream>>>(y, WprojT, d_out, 4096, 2048, 2048);
  } else {
    fill_diag<<<(out_size + 255) / 256, 256, 0, stream>>>((uint32_t*)d_out, out_size);
  }
}

// Round 6
// 424.180 us; speedup vs baseline: 1.6346x; 1.0323x over previous
//
#include <hip/hip_runtime.h>
#include <cstdint>
#include <cstddef>

typedef __bf16 bf16_t;
typedef __bf16 bf16x8 __attribute__((ext_vector_type(8)));
typedef __bf16 bf16x4 __attribute__((ext_vector_type(4)));
typedef float f32x4 __attribute__((ext_vector_type(4)));

#define MFMA16(a, b, c) __builtin_amdgcn_mfma_f32_16x16x32_bf16(a, b, c, 0, 0, 0)

// async global->LDS, 16B per lane. LDS dest = wave-uniform base + lane*16.
__device__ __forceinline__ void gll16(const bf16_t* g, bf16_t* l) {
  __builtin_amdgcn_global_load_lds(
      (__attribute__((address_space(1))) uint32_t*)((uintptr_t)g),
      (__attribute__((address_space(3))) uint32_t*)((uint32_t)(uintptr_t)l),
      16, 0, 0);
}

// Diagnostic: absmax ~1000 => ws_size too small.
__global__ void fill_diag(uint32_t* out, int n_u32) {
  int i = blockIdx.x * 256 + threadIdx.x;
  if (i < n_u32) out[i] = 0x447A0000u;  // f32 1000.0
}

// ---------------------------------------------------------------------------
// f32 -> bf16 vector convert (x, cos/sin tables). One bf16x8 per thread.
// ---------------------------------------------------------------------------
__global__ void conv_vec_f32(const float* __restrict__ in, bf16_t* __restrict__ out,
                             int n8) {
  const int i = blockIdx.x * 256 + threadIdx.x;
  if (i >= n8) return;
  const float* p = in + (size_t)i * 8;
  const f32x4 a = *(const f32x4*)p;
  const f32x4 b = *(const f32x4*)(p + 4);
  bf16x8 o;
#pragma unroll
  for (int j = 0; j < 4; ++j) {
    o[j] = (bf16_t)a[j];
    o[4 + j] = (bf16_t)b[j];
  }
  ((bf16x8*)out)[i] = o;
}

// ---------------------------------------------------------------------------
// 64x64 tiled transpose+convert: in R x C f32 -> out C x R bf16.
// ---------------------------------------------------------------------------
__global__ __launch_bounds__(256) void conv_transpose_f32(
    const float* __restrict__ in, bf16_t* __restrict__ out, int R, int C) {
  __shared__ bf16_t tile[64][72];
  const int bc = blockIdx.x * 64;
  const int br = blockIdx.y * 64;
  const int t = threadIdx.x;
  const int r = t >> 3;
  const int c8 = (t & 7) * 8;
#pragma unroll
  for (int ii = 0; ii < 2; ++ii) {
    const int rr = r + ii * 32;
    const float* p = in + (size_t)(br + rr) * C + bc + c8;
    const f32x4 a = *(const f32x4*)p;
    const f32x4 b = *(const f32x4*)(p + 4);
    bf16x8 v;
#pragma unroll
    for (int j = 0; j < 4; ++j) {
      v[j] = (bf16_t)a[j];
      v[4 + j] = (bf16_t)b[j];
    }
    *(bf16x8*)(&tile[rr][c8]) = v;
  }
  __syncthreads();
#pragma unroll
  for (int ii = 0; ii < 2; ++ii) {
    const int rr = r + ii * 32;
    bf16x8 o;
#pragma unroll
    for (int jj = 0; jj < 8; ++jj) o[jj] = tile[c8 + jj][rr];
    *(bf16x8*)(out + (size_t)(bc + rr) * R + br + c8) = o;
  }
}

// ---------------------------------------------------------------------------
// 256x256 8-phase GEMM (HK-style template, plain HIP). See round-0 notes.
// MF8: kk-OUTER so all 8 acc-updates per kk pass are independent (round-6:
// the kk-inner order made every 2nd MFMA depend on its predecessor -> issue
// stalled on MFMA latency at 2 waves/SIMD).
// ---------------------------------------------------------------------------
#define MF8(MLO, AARR, BARR, NLO)                                              \
  do {                                                                         \
    _Pragma("unroll") for (int k_ = 0; k_ < 2; ++k_) {                         \
      _Pragma("unroll") for (int m_ = 0; m_ < 4; ++m_) {                       \
        _Pragma("unroll") for (int n_ = 0; n_ < 2; ++n_) {                     \
          acc[(MLO) + m_][(NLO) + n_] = MFMA16(AARR[m_][k_], BARR[n_][k_],     \
                                               acc[(MLO) + m_][(NLO) + n_]);   \
        }                                                                      \
      }                                                                        \
    }                                                                          \
  } while (0)

template <bool C32>
__global__ __launch_bounds__(512, 2) void gemm8(
    const bf16_t* __restrict__ A, const bf16_t* __restrict__ Bt,
    void* __restrict__ C, int M, int N, int K, int nbn) {
  __shared__ __align__(1024) bf16_t lds8[65536];  // A: [0,32768), B: [32768,65536)
  bf16_t* As = lds8;
  bf16_t* Bs = lds8 + 32768;

  const int tid = threadIdx.x;
  const int lane = tid & 63;
  const int wave = tid >> 6;
  const int wr = wave >> 2;  // 0..1 (M half)
  const int wc = wave & 3;   // 0..3 (N quarter)
  const int fr = lane & 15;
  const int fg = lane >> 4;

  // XCD-aware bijective swizzle (nwg % 8 == 0 by construction).
  const int nwg = gridDim.x;
  const int bid = blockIdx.x;
  const int swz = (bid & 7) * (nwg >> 3) + (bid >> 3);
  const int m0 = (swz / nbn) * 256;
  const int n0 = (swz % nbn) * 256;

  const int NT = K >> 6;  // BK=64 tiles (assumed even; K=2048 -> 32)

  // staging geometry: wave covers segs {2w, 2w+1}; seg = 8 rows of 128B.
  const int sseg0 = wave * 2;
  const int srow = lane >> 3;
  const int sj = lane & 7;

  auto stage = [&](const bf16_t* __restrict__ G, int row0, bf16_t* L, int kt,
                   int h) {
#pragma unroll
    for (int l = 0; l < 2; ++l) {
      const int seg = sseg0 + l;
      const int r = seg * 8 + srow;       // row in half-tile 0..127
      const int j = sj ^ (r & 7);         // inverse-swizzled source chunk
      const bf16_t* src = G + (size_t)(row0 + h * 128 + r) * K + kt * 64 + j * 8;
      gll16(src, L + ((2 * kt + h) & 3) * 8192 + seg * 512 + lane * 8);
    }
  };

  const int cb0 = (fg * 16) ^ ((fr & 7) << 4);  // kk=0 byte col (swizzled)

  auto lda = [&](bf16x8(&af)[4][2], int kt, int mlo) {
    const char* base = (const char*)(As + ((2 * kt + wr) & 3) * 8192);
#pragma unroll
    for (int m = 0; m < 4; ++m) {
      const char* p = base + ((mlo + m) * 16 + fr) * 128;
      af[m][0] = *(const bf16x8*)(p + cb0);
      af[m][1] = *(const bf16x8*)(p + (cb0 ^ 64));
    }
  };
  auto ldb = [&](bf16x8(&bf)[2][2], int kt, int nlo) {
    const char* base = (const char*)(Bs + ((2 * kt + (wc >> 1)) & 3) * 8192);
#pragma unroll
    for (int n = 0; n < 2; ++n) {
      const char* p = base + ((wc & 1) * 64 + (nlo + n) * 16 + fr) * 128;
      bf[n][0] = *(const bf16x8*)(p + cb0);
      bf[n][1] = *(const bf16x8*)(p + (cb0 ^ 64));
    }
  };

  f32x4 acc[8][4] = {};

  // Prologue: A(0), B(0), B(1); drain A(0)+B(0), keep B(1) in flight.
  stage(A, m0, As, 0, 0);
  stage(A, m0, As, 0, 1);
  stage(Bt, n0, Bs, 0, 0);
  stage(Bt, n0, Bs, 0, 1);
  stage(Bt, n0, Bs, 1, 0);
  stage(Bt, n0, Bs, 1, 1);
  asm volatile("s_waitcnt vmcnt(4)" ::: "memory");
  __builtin_amdgcn_s_barrier();

  bf16x8 af[4][2], bfA[2][2], bfB[2][2];

  for (int u = 0; u < NT; u += 2) {
    const bool st2 = (u + 2 < NT);
    const bool st3 = (u + 3 < NT);
    // ---------------- tile u ----------------
    lda(af, u, 0);
    ldb(bfA, u, 0);
    stage(A, m0, As, u + 1, 0);
    asm volatile("s_waitcnt lgkmcnt(8)" ::: "memory");
    __builtin_amdgcn_s_barrier();
    asm volatile("s_waitcnt lgkmcnt(0)" ::: "memory");
    __builtin_amdgcn_sched_barrier(0);
    __builtin_amdgcn_s_setprio(1);
    MF8(0, af, bfA, 0);
    __builtin_amdgcn_s_setprio(0);
    __builtin_amdgcn_s_barrier();
    ldb(bfB, u, 2);
    stage(A, m0, As, u + 1, 1);
    __builtin_amdgcn_s_barrier();
    asm volatile("s_waitcnt lgkmcnt(0)" ::: "memory");
    __builtin_amdgcn_sched_barrier(0);
    __builtin_amdgcn_s_setprio(1);
    MF8(0, af, bfB, 2);
    __builtin_amdgcn_s_setprio(0);
    __builtin_amdgcn_s_barrier();
    lda(af, u, 4);
    if (st2) stage(Bt, n0, Bs, u + 2, 0);
    __builtin_amdgcn_s_barrier();
    asm volatile("s_waitcnt lgkmcnt(0)" ::: "memory");
    __builtin_amdgcn_sched_barrier(0);
    __builtin_amdgcn_s_setprio(1);
    MF8(4, af, bfB, 2);
    __builtin_amdgcn_s_setprio(0);
    __builtin_amdgcn_s_barrier();
    if (st2) stage(Bt, n0, Bs, u + 2, 1);
    __builtin_amdgcn_s_barrier();
    __builtin_amdgcn_s_setprio(1);
    MF8(4, af, bfA, 0);
    __builtin_amdgcn_s_setprio(0);
    asm volatile("s_waitcnt vmcnt(4)" ::: "memory");
    __builtin_amdgcn_s_barrier();
    // ---------------- tile u+1 ----------------
    lda(af, u + 1, 0);
    ldb(bfA, u + 1, 0);
    if (st2) stage(A, m0, As, u + 2, 0);
    asm volatile("s_waitcnt lgkmcnt(8)" ::: "memory");
    __builtin_amdgcn_s_barrier();
    asm volatile("s_waitcnt lgkmcnt(0)" ::: "memory");
    __builtin_amdgcn_sched_barrier(0);
    __builtin_amdgcn_s_setprio(1);
    MF8(0, af, bfA, 0);
    __builtin_amdgcn_s_setprio(0);
    __builtin_amdgcn_s_barrier();
    ldb(bfB, u + 1, 2);
    if (st2) stage(A, m0, As, u + 2, 1);
    __builtin_amdgcn_s_barrier();
    asm volatile("s_waitcnt lgkmcnt(0)" ::: "memory");
    __builtin_amdgcn_sched_barrier(0);
    __builtin_amdgcn_s_setprio(1);
    MF8(0, af, bfB, 2);
    __builtin_amdgcn_s_setprio(0);
    __builtin_amdgcn_s_barrier();
    lda(af, u + 1, 4);
    if (st3) stage(Bt, n0, Bs, u + 3, 0);
    __builtin_amdgcn_s_barrier();
    asm volatile("s_waitcnt lgkmcnt(0)" ::: "memory");
    __builtin_amdgcn_sched_barrier(0);
    __builtin_amdgcn_s_setprio(1);
    MF8(4, af, bfB, 2);
    __builtin_amdgcn_s_setprio(0);
    __builtin_amdgcn_s_barrier();
    if (st3) stage(Bt, n0, Bs, u + 3, 1);
    __builtin_amdgcn_s_barrier();
    __builtin_amdgcn_s_setprio(1);
    MF8(4, af, bfA, 0);
    __builtin_amdgcn_s_setprio(0);
    asm volatile("s_waitcnt vmcnt(4)" ::: "memory");
    __builtin_amdgcn_s_barrier();
  }

#pragma unroll
  for (int m = 0; m < 8; ++m) {
#pragma unroll
    for (int n = 0; n < 4; ++n) {
#pragma unroll
      for (int r = 0; r < 4; ++r) {
        const int row = m0 + wr * 128 + m * 16 + fg * 4 + r;
        const int col = n0 + wc * 64 + n * 16 + fr;
        const size_t idx = (size_t)row * N + col;
        if (C32)
          ((float*)C)[idx] = acc[m][n][r];
        else
          ((bf16_t*)C)[idx] = (bf16_t)acc[m][n][r];
      }
    }
  }
  (void)M;
}

// ---------------------------------------------------------------------------
// m97-style GEMM: kept for proj GEMM (N=2048 -> 256^2 grid only 128 blocks).
// ---------------------------------------------------------------------------
template <bool C32>
__global__ __launch_bounds__(256) void gemm_lds(
    const bf16_t* __restrict__ A, const bf16_t* __restrict__ Bt,
    void* __restrict__ C, int M, int N, int K) {
  __shared__ __align__(16) bf16_t As[128 * 32];
  __shared__ __align__(16) bf16_t Bs[128 * 32];
  const int tid = threadIdx.x;
  const int lane = tid & 63;
  const int wave = tid >> 6;
  const int m0 = blockIdx.x * 128;
  const int n0 = blockIdx.y * 128;
  const int wm = (wave & 1) * 64;
  const int wn = (wave >> 1) * 64;
  const int fr = lane & 15;
  const int fk = (lane >> 4) * 8;

  f32x4 acc[4][4] = {};

  const bf16_t* ga = A + (size_t)(m0 + (tid >> 2)) * K + (tid & 3) * 8;
  const bf16_t* gb = Bt + (size_t)(n0 + (tid >> 2)) * K + (tid & 3) * 8;
  bf16_t* lA = As + tid * 8;
  bf16_t* lB = Bs + tid * 8;
  const size_t half = (size_t)64 * K;

  for (int k0 = 0; k0 < K; k0 += 32) {
    __syncthreads();
    gll16(ga, lA);
    gll16(ga + half, lA + 2048);
    gll16(gb, lB);
    gll16(gb + half, lB + 2048);
    ga += 32;
    gb += 32;
    __syncthreads();
    bf16x8 af[4], bfr[4];
#pragma unroll
    for (int i = 0; i < 4; ++i)
      af[i] = *(const bf16x8*)(As + (wm + i * 16 + fr) * 32 + fk);
#pragma unroll
    for (int j = 0; j < 4; ++j)
      bfr[j] = *(const bf16x8*)(Bs + (wn + j * 16 + fr) * 32 + fk);
#pragma unroll
    for (int i = 0; i < 4; ++i)
#pragma unroll
      for (int j = 0; j < 4; ++j)
        acc[i][j] = MFMA16(af[i], bfr[j], acc[i][j]);
  }

  const int fg = lane >> 4;
#pragma unroll
  for (int i = 0; i < 4; ++i) {
#pragma unroll
    for (int j = 0; j < 4; ++j) {
#pragma unroll
      for (int r = 0; r < 4; ++r) {
        const int row = m0 + wm + i * 16 + fg * 4 + r;
        const int col = n0 + wn + j * 16 + fr;
        const size_t idx = (size_t)row * N + col;
        if (C32)
          ((float*)C)[idx] = acc[i][j][r];
        else
          ((bf16_t*)C)[idx] = (bf16_t)acc[i][j][r];
      }
    }
  }
}

// ---------------------------------------------------------------------------
// Register-staged GEMM (fallback path only): A f32 option, C f32 option.
// ---------------------------------------------------------------------------
template <bool A32, bool C32>
__global__ __launch_bounds__(256) void gemm_t(
    const void* __restrict__ A, const bf16_t* __restrict__ Bt,
    void* __restrict__ C, int M, int N, int K) {
  __shared__ bf16_t As[128 * 32];
  __shared__ bf16_t Bs[128 * 32];
  const int tid = threadIdx.x;
  const int lane = tid & 63;
  const int wave = tid >> 6;
  const int m0 = blockIdx.x * 128;
  const int n0 = blockIdx.y * 128;
  const int wm = (wave & 1) * 64;
  const int wn = (wave >> 1) * 64;
  const int fr = lane & 15;
  const int fk = (lane >> 4) * 8;

  f32x4 acc[4][4] = {};

  const size_t ea0 = (size_t)(m0 + (tid >> 2)) * K + (tid & 3) * 8;
  const bf16_t* gb = Bt + (size_t)(n0 + (tid >> 2)) * K + (tid & 3) * 8;
  bf16_t* lA = As + tid * 8;
  bf16_t* lB = Bs + tid * 8;
  const size_t half = (size_t)64 * K;

  for (int k0 = 0; k0 < K; k0 += 32) {
    bf16x8 ra0, ra1;
    if (A32) {
      const float* pa = (const float*)A + ea0 + k0;
      const f32x4 x0 = *(const f32x4*)pa;
      const f32x4 x1 = *(const f32x4*)(pa + 4);
      const f32x4 x2 = *(const f32x4*)(pa + half);
      const f32x4 x3 = *(const f32x4*)(pa + half + 4);
#pragma unroll
      for (int j = 0; j < 4; ++j) {
        ra0[j] = (bf16_t)x0[j];
        ra0[4 + j] = (bf16_t)x1[j];
        ra1[j] = (bf16_t)x2[j];
        ra1[4 + j] = (bf16_t)x3[j];
      }
    } else {
      const bf16_t* pa = (const bf16_t*)A + ea0 + k0;
      ra0 = *(const bf16x8*)pa;
      ra1 = *(const bf16x8*)(pa + half);
    }
    const bf16x8 rb0 = *(const bf16x8*)gb;
    const bf16x8 rb1 = *(const bf16x8*)(gb + half);
    gb += 32;
    __syncthreads();
    *(bf16x8*)lA = ra0;
    *(bf16x8*)(lA + 2048) = ra1;
    *(bf16x8*)lB = rb0;
    *(bf16x8*)(lB + 2048) = rb1;
    __syncthreads();
    bf16x8 af[4], bfr[4];
#pragma unroll
    for (int i = 0; i < 4; ++i)
      af[i] = *(const bf16x8*)(As + (wm + i * 16 + fr) * 32 + fk);
#pragma unroll
    for (int j = 0; j < 4; ++j)
      bfr[j] = *(const bf16x8*)(Bs + (wn + j * 16 + fr) * 32 + fk);
#pragma unroll
    for (int i = 0; i < 4; ++i)
#pragma unroll
      for (int j = 0; j < 4; ++j)
        acc[i][j] = MFMA16(af[i], bfr[j], acc[i][j]);
  }

  const int fg = lane >> 4;
#pragma unroll
  for (int i = 0; i < 4; ++i) {
#pragma unroll
    for (int j = 0; j < 4; ++j) {
#pragma unroll
      for (int r = 0; r < 4; ++r) {
        const int row = m0 + wm + i * 16 + fg * 4 + r;
        const int col = n0 + wn + j * 16 + fr;
        const size_t idx = (size_t)row * N + col;
        if (C32)
          ((float*)C)[idx] = acc[i][j][r];
        else
          ((bf16_t*)C)[idx] = (bf16_t)acc[i][j][r];
      }
    }
  }
}

// ---------------------------------------------------------------------------
// K rope extract: qkv (B*T,6144) -> Kr (B,H,T,D) bf16 rope'd.
// ---------------------------------------------------------------------------
__global__ __launch_bounds__(256) void rope_k(
    const bf16_t* __restrict__ qkv, const bf16_t* __restrict__ cosb,
    const bf16_t* __restrict__ sinb, bf16_t* __restrict__ Kr) {
  const int row = blockIdx.x;  // b*2048 + t
  const int t = row & 2047;
  const int b = row >> 11;
  const int idx = threadIdx.x * 8;
  const int h = idx >> 7;
  const int d = idx & 127;
  const float sgn = (d < 64) ? -1.f : 1.f;
  const bf16_t* base = qkv + (size_t)row * 6144 + 2048;
  const bf16x8 kv = *(const bf16x8*)(base + idx);
  const bf16x8 kp = *(const bf16x8*)(base + (idx ^ 64));
  const bf16x8 cv = *(const bf16x8*)(cosb + t * 128 + d);
  const bf16x8 sv = *(const bf16x8*)(sinb + t * 128 + d);
  bf16x8 o;
#pragma unroll
  for (int jj = 0; jj < 8; ++jj)
    o[jj] = (bf16_t)(((float)kv[jj]) * ((float)cv[jj]) +
                     sgn * ((float)kp[jj]) * ((float)sv[jj]));
  *(bf16x8*)(Kr + ((size_t)(b * 16 + h) * 2048 + t) * 128 + d) = o;
}

// ---------------------------------------------------------------------------
// V extract + transpose: qkv cols 4096.. -> Vt (B,H,D,T).
// ---------------------------------------------------------------------------
__global__ __launch_bounds__(256) void transpose_v(
    const bf16_t* __restrict__ qkv, bf16_t* __restrict__ Vt) {
  __shared__ bf16_t tile[64][72];
  const int bh = blockIdx.z;
  const int b = bh >> 4, h = bh & 15;
  const int t0 = blockIdx.x * 64;
  const int d0 = blockIdx.y * 64;
  const int t = threadIdx.x;
  const int r = t >> 3;
  const int c8 = (t & 7) * 8;
#pragma unroll
  for (int ii = 0; ii < 2; ++ii) {
    const int rr = r + ii * 32;
    *(bf16x8*)(&tile[rr][c8]) =
        *(const bf16x8*)(qkv + (size_t)(b * 2048 + t0 + rr) * 6144 + 4096 + h * 128 + d0 + c8);
  }
  __syncthreads();
#pragma unroll
  for (int ii = 0; ii < 2; ++ii) {
    const int rr = r + ii * 32;
    bf16x8 o;
#pragma unroll
    for (int jj = 0; jj < 8; ++jj) o[jj] = tile[c8 + jj][rr];
    *(bf16x8*)(Vt + ((size_t)bh * 128 + d0 + rr) * 2048 + t0 + c8) = o;
  }
}

// ---------------------------------------------------------------------------
// Flash round-6: round-5 structure (QBLK=64, swapped QK^T via global_load_lds
// K staging with rule-#21 involution, in-register P, π-permuted Vs, T14
// pipeline) + QK^T MFMA loop reordered ks-OUTER so consecutive MFMAs hit
// rotating sacc[n] (independent, distance 4) instead of 4-deep dep chains.
// ---------------------------------------------------------------------------
__global__ __launch_bounds__(256, 4) void flash_q64p(
    const bf16_t* __restrict__ qkv, const bf16_t* __restrict__ cosb,
    const bf16_t* __restrict__ sinb, const bf16_t* __restrict__ Kr,
    const bf16_t* __restrict__ Vt, bf16_t* __restrict__ Y) {
  constexpr int T = 2048;
  __shared__ __align__(1024) bf16_t Ks[64 * 128];  // swizzled linear tile
  __shared__ bf16_t Vs[128][72];
  const int tid = threadIdx.x;
  const int lane = tid & 63;
  const int fr = lane & 15;
  const int fg = lane >> 4;
  const int qt = blockIdx.x;  // 0..31, 64 q-rows each
  const int bh = blockIdx.y;
  const int b = bh >> 4, h = bh & 15;

  // Q rope'd on the fly; scale = rsqrt(128) * log2(e) folded in.
  const int wave = tid >> 6;
  const int trow = qt * 64 + wave * 16 + fr;
  const bf16_t* qrow = qkv + (size_t)(b * T + trow) * 6144 + h * 128;
  bf16x8 qf[4];
#pragma unroll
  for (int ks = 0; ks < 4; ++ks) {
    const int d = ks * 32 + fg * 8;
    const float sgn = (d < 64) ? -1.f : 1.f;
    const bf16x8 qv = *(const bf16x8*)(qrow + d);
    const bf16x8 qp = *(const bf16x8*)(qrow + (d ^ 64));
    const bf16x8 cv = *(const bf16x8*)(cosb + trow * 128 + d);
    const bf16x8 sv = *(const bf16x8*)(sinb + trow * 128 + d);
    bf16x8 o;
#pragma unroll
    for (int jj = 0; jj < 8; ++jj)
      o[jj] = (bf16_t)((((float)qv[jj]) * ((float)cv[jj]) +
                        sgn * ((float)qp[jj]) * ((float)sv[jj])) *
                       0.1275174825f);  // (1/sqrt(128)) * log2(e)
    qf[ks] = o;
  }

  f32x4 acc[8] = {};
  float l_i = 0.f;

  // K staging: thread covers row r = it*16 + (tid>>4), source chunk
  // pre-swizzled sc = (tid&15) ^ (r&7); LDS dest linear tid*16B per it.
  const int krow = tid >> 4;                    // 0..15
  const int sc = (tid & 15) ^ (krow & 7);       // (r&7) == (krow&7) for all it
  // V staging geometry (reg-staged, π-permuted columns)
  const int vrow = tid >> 3;        // 0..31 (d rows, +32*it)
  const int vu = tid & 7;           // t-chunk index (8 consecutive t)
  const int vc0 = ((vu >> 2) * 32) + ((vu & 1) * 16) + (((vu >> 1) & 1) * 4);
  const bf16_t* Kh = Kr + (size_t)bh * T * 128;
  const bf16_t* Vh = Vt + (size_t)bh * 128 * T;

  auto stageK = [&](int t0) {
#pragma unroll
    for (int it = 0; it < 4; ++it)
      gll16(Kh + (size_t)(t0 + it * 16 + krow) * 128 + sc * 8,
            Ks + it * 2048 + tid * 8);
  };
  bf16x8 vreg[4];
  auto loadV = [&](int t0) {
#pragma unroll
    for (int it = 0; it < 4; ++it)
      vreg[it] = *(const bf16x8*)(Vh + (size_t)(it * 32 + vrow) * T + t0 + vu * 8);
  };
  auto writeV = [&]() {
#pragma unroll
    for (int it = 0; it < 4; ++it) {
      const int row = it * 32 + vrow;
      const bf16x8 v = vreg[it];
      bf16x4 lo, hi;
#pragma unroll
      for (int jj = 0; jj < 4; ++jj) {
        lo[jj] = v[jj];
        hi[jj] = v[4 + jj];
      }
      *(bf16x4*)(&Vs[row][vc0]) = lo;      // t = base+0..3  (b2=0)
      *(bf16x4*)(&Vs[row][vc0 + 8]) = hi;  // t = base+4..7  (b2=1)
    }
  };

  // prologue: stage tile 0
  stageK(0);
  loadV(0);
  asm volatile("s_waitcnt vmcnt(0)" ::: "memory");
  __builtin_amdgcn_sched_barrier(0);
  writeV();
  __syncthreads();

  const int cswz = (fr & 7) << 4;  // read-side XOR for Ks
  const char* kbase = (const char*)Ks;

  for (int j = 0; j < T / 64; ++j) {
    // QK^T swapped: lane holds P[q=fr][k=n*16+fg*4+r]. ks-outer: sacc[0..3]
    // rotate -> consecutive MFMAs independent.
    f32x4 sacc[4] = {};
#pragma unroll
    for (int ks = 0; ks < 4; ++ks) {
#pragma unroll
      for (int n = 0; n < 4; ++n) {
        const bf16x8 kf = *(const bf16x8*)(kbase + (n * 16 + fr) * 256 +
                                           ((ks * 64 + fg * 16) ^ cswz));
        sacc[n] = MFMA16(kf, qf[ks], sacc[n]);
      }
    }
    __syncthreads();  // Ks consumed by all waves

    const bool more = (j + 1 < T / 64);
    if (more) {
      stageK((j + 1) * 64);  // DMA into Ks (dead) while exp+PV run
      loadV((j + 1) * 64);
    }

    // exp + in-register pack into PV A-fragments:
    // paf[ks2][jj] = P[q=fr][k = (2*ks2+(jj>>2))*16 + fg*4 + (jj&3)]
    bf16x8 paf[2];
    float lsum = 0.f;
#pragma unroll
    for (int ks2 = 0; ks2 < 2; ++ks2) {
#pragma unroll
      for (int jj = 0; jj < 8; ++jj) {
        const float p = exp2f(sacc[ks2 * 2 + (jj >> 2)][jj & 3]);
        lsum += p;
        paf[ks2][jj] = (bf16_t)p;
      }
    }
    l_i += lsum;

    // PV: Vs column order matches paf's k order by construction.
#pragma unroll
    for (int ks2 = 0; ks2 < 2; ++ks2) {
#pragma unroll
      for (int n = 0; n < 8; ++n) {
        const bf16x8 vf = *(const bf16x8*)(&Vs[n * 16 + fr][ks2 * 32 + fg * 8]);
        acc[n] = MFMA16(paf[ks2], vf, acc[n]);
      }
    }

    asm volatile("s_waitcnt vmcnt(0)" ::: "memory");  // K DMA + V regs landed
    __builtin_amdgcn_sched_barrier(0);
    __syncthreads();  // Vs consumed by all; Ks(j+1) visible
    if (more) {
      writeV();
      __syncthreads();  // Vs(j+1) ready
    }
  }

  // epilogue: l reduce across fg groups (lanes fr, fr+16, fr+32, fr+48 hold
  // disjoint k-subsets of q=fr), then fetch 1/l for this lane's output rows.
  float l = l_i;
  l += __shfl_xor(l, 16, 64);
  l += __shfl_xor(l, 32, 64);  // lanes with same fr now hold l_full(q=fr)
#pragma unroll
  for (int r = 0; r < 4; ++r) {
    const float inv = 1.0f / __shfl(l, fg * 4 + r, 64);
    const int t = qt * 64 + wave * 16 + fg * 4 + r;
    bf16_t* yrow = Y + (size_t)(b * T + t) * 2048 + h * 128;
#pragma unroll
    for (int n = 0; n < 8; ++n)
      yrow[n * 16 + fr] = (bf16_t)(acc[n][r] * inv);
  }
}

// ---------------------------------------------------------------------------
// Flash fallback (ws-lean): fused rope, exp-only softmax. (ks-outer QK^T)
// ---------------------------------------------------------------------------
__global__ __launch_bounds__(256) void flash_fused_v2(
    const bf16_t* __restrict__ qkv, const bf16_t* __restrict__ cosb,
    const bf16_t* __restrict__ sinb, bf16_t* __restrict__ Y) {
  constexpr int T = 2048;
  __shared__ bf16_t Ks[64][136];
  __shared__ bf16_t Vs[128][72];
  __shared__ bf16_t Ps[128][72];
  const int tid = threadIdx.x;
  const int lane = tid & 63;
  const int wave = tid >> 6;
  const int fr = lane & 15;
  const int fg = lane >> 4;
  const int qt = blockIdx.x;
  const int bh = blockIdx.y;
  const int b = bh >> 4, h = bh & 15;

  const bf16_t* qbase = qkv + (size_t)b * T * 6144 + h * 128;
  bf16x8 qf[2][4];
#pragma unroll
  for (int i = 0; i < 2; ++i) {
    const int trow = qt * 128 + wave * 32 + i * 16 + fr;
    const bf16_t* qrow = qbase + (size_t)trow * 6144;
#pragma unroll
    for (int ks = 0; ks < 4; ++ks) {
      const int d = ks * 32 + fg * 8;
      const float sgn = (d < 64) ? -1.f : 1.f;
      const bf16x8 qv = *(const bf16x8*)(qrow + d);
      const bf16x8 qp = *(const bf16x8*)(qrow + (d ^ 64));
      const bf16x8 cv = *(const bf16x8*)(cosb + trow * 128 + d);
      const bf16x8 sv = *(const bf16x8*)(sinb + trow * 128 + d);
      bf16x8 o;
#pragma unroll
      for (int jj = 0; jj < 8; ++jj)
        o[jj] = (bf16_t)((((float)qv[jj]) * ((float)cv[jj]) +
                          sgn * ((float)qp[jj]) * ((float)sv[jj])) *
                         0.08838834764831845f);
      qf[i][ks] = o;
    }
  }

  f32x4 acc[2][8] = {};
  float l_i[2][4] = {};

  const int kr = tid >> 4;
  const int kc = (tid & 15) * 8;
  const float sgnk = (kc < 64) ? -1.f : 1.f;
  const int tp = tid & 63;

  for (int j = 0; j < T / 64; ++j) {
    const int t0 = j * 64;
#pragma unroll
    for (int it = 0; it < 4; ++it) {
      const int row = it * 16 + kr;
      const int tg = t0 + row;
      const bf16_t* krow = qkv + ((size_t)(b * T + tg)) * 6144 + 2048 + h * 128;
      const bf16x8 kv = *(const bf16x8*)(krow + kc);
      const bf16x8 kp = *(const bf16x8*)(krow + (kc ^ 64));
      const bf16x8 cv = *(const bf16x8*)(cosb + tg * 128 + kc);
      const bf16x8 sv = *(const bf16x8*)(sinb + tg * 128 + kc);
      bf16x8 o;
#pragma unroll
      for (int jj = 0; jj < 8; ++jj)
        o[jj] = (bf16_t)(((float)kv[jj]) * ((float)cv[jj]) +
                         sgnk * ((float)kp[jj]) * ((float)sv[jj]));
      *(bf16x8*)(&Ks[row][kc]) = o;
    }
#pragma unroll
    for (int cc = 0; cc < 4; ++cc) {
      const int d8 = (cc * 4 + (tid >> 6)) * 8;
      const bf16x8 vv = *(const bf16x8*)(qkv + ((size_t)(b * T + t0 + tp)) * 6144 +
                                         4096 + h * 128 + d8);
#pragma unroll
      for (int jj = 0; jj < 8; ++jj) Vs[d8 + jj][tp] = vv[jj];
    }
    __syncthreads();

    f32x4 sacc[2][4] = {};
#pragma unroll
    for (int ks = 0; ks < 4; ++ks) {
#pragma unroll
      for (int n = 0; n < 4; ++n) {
        const bf16x8 kf = *(const bf16x8*)(&Ks[n * 16 + fr][ks * 32 + fg * 8]);
        sacc[0][n] = MFMA16(qf[0][ks], kf, sacc[0][n]);
        sacc[1][n] = MFMA16(qf[1][ks], kf, sacc[1][n]);
      }
    }

#pragma unroll
    for (int i = 0; i < 2; ++i) {
#pragma unroll
      for (int r = 0; r < 4; ++r) {
        const float p0 = __expf(sacc[i][0][r]);
        const float p1 = __expf(sacc[i][1][r]);
        const float p2 = __expf(sacc[i][2][r]);
        const float p3 = __expf(sacc[i][3][r]);
        l_i[i][r] += (p0 + p1) + (p2 + p3);
        const int prow = wave * 32 + i * 16 + fg * 4 + r;
        Ps[prow][0 + fr] = (bf16_t)p0;
        Ps[prow][16 + fr] = (bf16_t)p1;
        Ps[prow][32 + fr] = (bf16_t)p2;
        Ps[prow][48 + fr] = (bf16_t)p3;
      }
    }

#pragma unroll
    for (int ks = 0; ks < 2; ++ks) {
      const bf16x8 pf0 = *(const bf16x8*)(&Ps[wave * 32 + fr][ks * 32 + fg * 8]);
      const bf16x8 pf1 = *(const bf16x8*)(&Ps[wave * 32 + 16 + fr][ks * 32 + fg * 8]);
#pragma unroll
      for (int n = 0; n < 8; ++n) {
        const bf16x8 vf = *(const bf16x8*)(&Vs[n * 16 + fr][ks * 32 + fg * 8]);
        acc[0][n] = MFMA16(pf0, vf, acc[0][n]);
        acc[1][n] = MFMA16(pf1, vf, acc[1][n]);
      }
    }
    __syncthreads();
  }

#pragma unroll
  for (int i = 0; i < 2; ++i) {
#pragma unroll
    for (int r = 0; r < 4; ++r) {
      float l = l_i[i][r];
#pragma unroll
      for (int msk = 1; msk < 16; msk <<= 1) l += __shfl_xor(l, msk, 64);
      const float inv = 1.0f / l;
      const int t = qt * 128 + wave * 32 + i * 16 + fg * 4 + r;
      bf16_t* yrow = Y + (size_t)(b * T + t) * 2048 + h * 128;
#pragma unroll
      for (int n = 0; n < 8; ++n)
        yrow[n * 16 + fr] = (bf16_t)(acc[i][n][r] * inv);
    }
  }
}

// ---------------------------------------------------------------------------
extern "C" void kernel_launch(void* const* d_in, const int* in_sizes, int n_in,
                              void* d_out, int out_size, void* d_ws, size_t ws_size,
                              hipStream_t stream) {
  const float* x = (const float*)d_in[0];
  const float* cosi = (const float*)d_in[1];
  const float* sini = (const float*)d_in[2];
  const float* Wqkv = (const float*)d_in[3];
  const float* Wproj = (const float*)d_in[4];

  const size_t NEED_FAST = sizeof(bf16_t) *
      ((size_t)12582912 + 262144 + 262144 + 25165824 + 8388608 + 8388608);
  const size_t NEED_BASE = 256 + sizeof(bf16_t) *
      ((size_t)12582912 + 4194304 + 262144 + 262144 + 25165824);

  if (ws_size >= NEED_FAST) {
    bf16_t* base = (bf16_t*)d_ws;
    bf16_t* WqkvT = base;                    // dead after gemm1
    bf16_t* y = base;                        // alias
    bf16_t* cosb = base + 12582912;
    bf16_t* sinb = cosb + 262144;
    bf16_t* qkv = sinb + 262144;             // live through flash
    bf16_t* WprojT = qkv;                    // alias head, written after flash
    bf16_t* Kr = qkv + 25165824;
    bf16_t* xb = Kr;                         // alias: x-bf16, dead before rope_k
    bf16_t* Vt = Kr + 8388608;

    conv_vec_f32<<<128, 256, 0, stream>>>(cosi, cosb, 32768);
    conv_vec_f32<<<128, 256, 0, stream>>>(sini, sinb, 32768);
    conv_vec_f32<<<4096, 256, 0, stream>>>(x, xb, 1048576);  // x -> bf16
    conv_transpose_f32<<<dim3(96, 32), 256, 0, stream>>>(Wqkv, WqkvT, 2048, 6144);
    gemm8<false><<<384, 512, 0, stream>>>(xb, WqkvT, qkv, 4096, 6144, 2048, 24);
    rope_k<<<4096, 256, 0, stream>>>(qkv, cosb, sinb, Kr);  // overwrites xb (dead)
    transpose_v<<<dim3(32, 2, 32), 256, 0, stream>>>(qkv, Vt);
    flash_q64p<<<dim3(32, 32), 256, 0, stream>>>(qkv, cosb, sinb, Kr, Vt, y);
    conv_transpose_f32<<<dim3(32, 32), 256, 0, stream>>>(Wproj, WprojT, 2048, 2048);
    gemm_lds<true><<<dim3(32, 16), 256, 0, stream>>>(y, WprojT, d_out, 4096, 2048, 2048);
  } else if (ws_size >= NEED_BASE) {
    bf16_t* base = (bf16_t*)((char*)d_ws + 256);
    bf16_t* WqkvT = base;
    bf16_t* y = base;
    bf16_t* WprojT = base + 12582912;
    bf16_t* cosb = WprojT + 4194304;
    bf16_t* sinb = cosb + 262144;
    bf16_t* qkv = sinb + 262144;

    conv_vec_f32<<<128, 256, 0, stream>>>(cosi, cosb, 32768);
    conv_vec_f32<<<128, 256, 0, stream>>>(sini, sinb, 32768);
    conv_transpose_f32<<<dim3(96, 32), 256, 0, stream>>>(Wqkv, WqkvT, 2048, 6144);
    gemm_t<true, false><<<dim3(32, 48), 256, 0, stream>>>(x, WqkvT, qkv, 4096, 6144, 2048);
    flash_fused_v2<<<dim3(16, 32), 256, 0, stream>>>(qkv, cosb, sinb, y);
    conv_transpose_f32<<<dim3(32, 32), 256, 0, stream>>>(Wproj, WprojT, 2048, 2048);
    gemm_t<false, true><<<dim3(32, 16), 256, 0, stream>>>(y, WprojT, d_out, 4096, 2048, 2048);
  } else {
    fill_diag<<<(out_size + 255) / 256, 256, 0, stream>>>((uint32_t*)d_out, out_size);
  }
}

// Round 7
// 419.663 us; speedup vs baseline: 1.6522x; 1.0108x over previous
//
#include <hip/hip_runtime.h>
#include <cstdint>
#include <cstddef>

typedef __bf16 bf16_t;
typedef __bf16 bf16x8 __attribute__((ext_vector_type(8)));
typedef __bf16 bf16x4 __attribute__((ext_vector_type(4)));
typedef float f32x4 __attribute__((ext_vector_type(4)));

#define MFMA16(a, b, c) __builtin_amdgcn_mfma_f32_16x16x32_bf16(a, b, c, 0, 0, 0)

// async global->LDS, 16B per lane. LDS dest = wave-uniform base + lane*16.
__device__ __forceinline__ void gll16(const bf16_t* g, bf16_t* l) {
  __builtin_amdgcn_global_load_lds(
      (__attribute__((address_space(1))) uint32_t*)((uintptr_t)g),
      (__attribute__((address_space(3))) uint32_t*)((uint32_t)(uintptr_t)l),
      16, 0, 0);
}

// Diagnostic: absmax ~1000 => ws_size too small.
__global__ void fill_diag(uint32_t* out, int n_u32) {
  int i = blockIdx.x * 256 + threadIdx.x;
  if (i < n_u32) out[i] = 0x447A0000u;  // f32 1000.0
}

// ---------------------------------------------------------------------------
// f32 -> bf16 vector convert (x, cos/sin tables). One bf16x8 per thread.
// ---------------------------------------------------------------------------
__global__ void conv_vec_f32(const float* __restrict__ in, bf16_t* __restrict__ out,
                             int n8) {
  const int i = blockIdx.x * 256 + threadIdx.x;
  if (i >= n8) return;
  const float* p = in + (size_t)i * 8;
  const f32x4 a = *(const f32x4*)p;
  const f32x4 b = *(const f32x4*)(p + 4);
  bf16x8 o;
#pragma unroll
  for (int j = 0; j < 4; ++j) {
    o[j] = (bf16_t)a[j];
    o[4 + j] = (bf16_t)b[j];
  }
  ((bf16x8*)out)[i] = o;
}

// ---------------------------------------------------------------------------
// 64x64 tiled transpose+convert: in R x C f32 -> out C x R bf16.
// ---------------------------------------------------------------------------
__global__ __launch_bounds__(256) void conv_transpose_f32(
    const float* __restrict__ in, bf16_t* __restrict__ out, int R, int C) {
  __shared__ bf16_t tile[64][72];
  const int bc = blockIdx.x * 64;
  const int br = blockIdx.y * 64;
  const int t = threadIdx.x;
  const int r = t >> 3;
  const int c8 = (t & 7) * 8;
#pragma unroll
  for (int ii = 0; ii < 2; ++ii) {
    const int rr = r + ii * 32;
    const float* p = in + (size_t)(br + rr) * C + bc + c8;
    const f32x4 a = *(const f32x4*)p;
    const f32x4 b = *(const f32x4*)(p + 4);
    bf16x8 v;
#pragma unroll
    for (int j = 0; j < 4; ++j) {
      v[j] = (bf16_t)a[j];
      v[4 + j] = (bf16_t)b[j];
    }
    *(bf16x8*)(&tile[rr][c8]) = v;
  }
  __syncthreads();
#pragma unroll
  for (int ii = 0; ii < 2; ++ii) {
    const int rr = r + ii * 32;
    bf16x8 o;
#pragma unroll
    for (int jj = 0; jj < 8; ++jj) o[jj] = tile[c8 + jj][rr];
    *(bf16x8*)(out + (size_t)(bc + rr) * R + br + c8) = o;
  }
}

// ---------------------------------------------------------------------------
// gemm8n: 128x256-tile 2-phase-per-K-tile GEMM (round-7).
//   C[M,N] = A[M,K] @ Bt^T, BK=64, 512 thr, 8 waves (2M x 4N), per-wave 64x64.
//   Grid = (M/128)*(N/256): qkv 32x24=768 = 3 exact CU rounds; proj 32x8=256
//   = 1 exact round (fixes the 384-block 75%-fill quantization of the 256^2
//   tile). LDS 128KB: A = 3 slots x 16KB (cycle t%3), B = 5 half-slots x 16KB
//   (half h of tile t at slot (2t+h)%5). Slot-overwrite safety (paper-checked):
//   every stage lands >=1 barrier after its slot's last reader. Steady-state
//   vmcnt(2) at ph2 end (leaves only sA(t+2) in flight); tail drains vmcnt(0).
//   Staging uses rule-#21 involution (source chunk ^= row&7, read col-XOR).
// ---------------------------------------------------------------------------
template <bool C32>
__global__ __launch_bounds__(512, 2) void gemm8n(
    const bf16_t* __restrict__ A, const bf16_t* __restrict__ Bt,
    void* __restrict__ C, int M, int N, int K, int nbn) {
  __shared__ __align__(1024) bf16_t lds8[65536];  // A: 3x8192, B: 5x8192 (bf16)
  bf16_t* As = lds8;           // 3 slots * 8192 el
  bf16_t* Bs = lds8 + 24576;   // 5 slots * 8192 el

  const int tid = threadIdx.x;
  const int lane = tid & 63;
  const int wave = tid >> 6;
  const int wr = wave >> 2;  // 0..1 (M half: 64 rows)
  const int wc = wave & 3;   // 0..3 (N quarter: 64 cols)
  const int fr = lane & 15;
  const int fg = lane >> 4;

  // XCD-aware bijective swizzle (nwg % 8 == 0 by construction).
  const int nwg = gridDim.x;
  const int bid = blockIdx.x;
  const int swz = (bid & 7) * (nwg >> 3) + (bid >> 3);
  const int m0 = (swz / nbn) * 128;
  const int n0 = (swz % nbn) * 256;

  const int NT = K >> 6;

  const int srow = tid >> 3;  // 0..63
  const int sj = tid & 7;

  // stage one 128-row x 64-col half-tile (16KB) into slotBase.
  auto stage = [&](const bf16_t* __restrict__ G, int grow0, bf16_t* slotBase,
                   int kt) {
#pragma unroll
    for (int l = 0; l < 2; ++l) {
      const int r = l * 64 + srow;
      const int j = sj ^ (r & 7);  // inverse-swizzled source chunk
      gll16(G + (size_t)(grow0 + r) * K + kt * 64 + j * 8,
            slotBase + l * 4096 + tid * 8);
    }
  };

  const int cb0 = (fg * 16) ^ ((fr & 7) << 4);  // swizzled k-half-0 byte col

  auto lda = [&](bf16x8(&af)[4][2], int t) {
    const char* base = (const char*)(As + (t % 3) * 8192);
#pragma unroll
    for (int m = 0; m < 4; ++m) {
      const char* p = base + (wr * 64 + m * 16 + fr) * 128;
      af[m][0] = *(const bf16x8*)(p + cb0);
      af[m][1] = *(const bf16x8*)(p + (cb0 ^ 64));
    }
  };
  auto ldb2 = [&](bf16x8(&bf)[2][2], int t, int nlo) {
    const char* base = (const char*)(Bs + ((2 * t + (wc >> 1)) % 5) * 8192);
#pragma unroll
    for (int n = 0; n < 2; ++n) {
      const char* p = base + ((wc & 1) * 64 + (nlo + n) * 16 + fr) * 128;
      bf[n][0] = *(const bf16x8*)(p + cb0);
      bf[n][1] = *(const bf16x8*)(p + (cb0 ^ 64));
    }
  };

  f32x4 acc[4][4] = {};

  // Prologue: A(0)->s0, A(1)->s1, B(0,0)->b0, B(0,1)->b1, B(1,0)->b2.
  stage(A, m0, As, 0);
  stage(A, m0, As + 8192, 1);
  stage(Bt, n0, Bs, 0);
  stage(Bt, n0 + 128, Bs + 8192, 0);
  stage(Bt, n0, Bs + 2 * 8192, 1);
  asm volatile("s_waitcnt vmcnt(2)" ::: "memory");  // B(1,0) may stay in flight
  __builtin_amdgcn_s_barrier();

  bf16x8 af[4][2], bf01[2][2], bf23[2][2];

  for (int t = 0; t < NT; ++t) {
    // ---- ph1: af(t) + bf(t,n01); stage B(t+2,0), B(t+1,1); MFMA n01 ----
    lda(af, t);
    ldb2(bf01, t, 0);
    if (t + 2 < NT) stage(Bt, n0, Bs + ((2 * t + 4) % 5) * 8192, t + 2);
    if (t + 1 < NT) stage(Bt, n0 + 128, Bs + ((2 * t + 3) % 5) * 8192, t + 1);
    asm volatile("s_waitcnt lgkmcnt(8)" ::: "memory");
    __builtin_amdgcn_s_barrier();
    asm volatile("s_waitcnt lgkmcnt(0)" ::: "memory");
    __builtin_amdgcn_sched_barrier(0);
    __builtin_amdgcn_s_setprio(1);
#pragma unroll
    for (int k = 0; k < 2; ++k)
#pragma unroll
      for (int m = 0; m < 4; ++m)
#pragma unroll
        for (int n = 0; n < 2; ++n)
          acc[m][n] = MFMA16(af[m][k], bf01[n][k], acc[m][n]);
    __builtin_amdgcn_s_setprio(0);
    __builtin_amdgcn_s_barrier();
    // ---- ph2: bf(t,n23); stage A(t+2); MFMA n23; counted vmcnt ----
    ldb2(bf23, t, 2);
    if (t + 2 < NT) stage(A, m0, As + ((t + 2) % 3) * 8192, t + 2);
    __builtin_amdgcn_s_barrier();
    asm volatile("s_waitcnt lgkmcnt(0)" ::: "memory");
    __builtin_amdgcn_sched_barrier(0);
    __builtin_amdgcn_s_setprio(1);
#pragma unroll
    for (int k = 0; k < 2; ++k)
#pragma unroll
      for (int m = 0; m < 4; ++m)
#pragma unroll
        for (int n = 0; n < 2; ++n)
          acc[m][n + 2] = MFMA16(af[m][k], bf23[n][k], acc[m][n + 2]);
    __builtin_amdgcn_s_setprio(0);
    if (t + 3 < NT) {
      asm volatile("s_waitcnt vmcnt(2)" ::: "memory");
    } else {
      asm volatile("s_waitcnt vmcnt(0)" ::: "memory");  // tail: guards skipped
    }
    __builtin_amdgcn_s_barrier();
  }

#pragma unroll
  for (int m = 0; m < 4; ++m) {
#pragma unroll
    for (int n = 0; n < 4; ++n) {
#pragma unroll
      for (int r = 0; r < 4; ++r) {
        const int row = m0 + wr * 64 + m * 16 + fg * 4 + r;
        const int col = n0 + wc * 64 + n * 16 + fr;
        const size_t idx = (size_t)row * N + col;
        if (C32)
          ((float*)C)[idx] = acc[m][n][r];
        else
          ((bf16_t*)C)[idx] = (bf16_t)acc[m][n][r];
      }
    }
  }
  (void)M;
}

// ---------------------------------------------------------------------------
// Register-staged GEMM (fallback path only): A f32 option, C f32 option.
// ---------------------------------------------------------------------------
template <bool A32, bool C32>
__global__ __launch_bounds__(256) void gemm_t(
    const void* __restrict__ A, const bf16_t* __restrict__ Bt,
    void* __restrict__ C, int M, int N, int K) {
  __shared__ bf16_t As[128 * 32];
  __shared__ bf16_t Bs[128 * 32];
  const int tid = threadIdx.x;
  const int lane = tid & 63;
  const int wave = tid >> 6;
  const int m0 = blockIdx.x * 128;
  const int n0 = blockIdx.y * 128;
  const int wm = (wave & 1) * 64;
  const int wn = (wave >> 1) * 64;
  const int fr = lane & 15;
  const int fk = (lane >> 4) * 8;

  f32x4 acc[4][4] = {};

  const size_t ea0 = (size_t)(m0 + (tid >> 2)) * K + (tid & 3) * 8;
  const bf16_t* gb = Bt + (size_t)(n0 + (tid >> 2)) * K + (tid & 3) * 8;
  bf16_t* lA = As + tid * 8;
  bf16_t* lB = Bs + tid * 8;
  const size_t half = (size_t)64 * K;

  for (int k0 = 0; k0 < K; k0 += 32) {
    bf16x8 ra0, ra1;
    if (A32) {
      const float* pa = (const float*)A + ea0 + k0;
      const f32x4 x0 = *(const f32x4*)pa;
      const f32x4 x1 = *(const f32x4*)(pa + 4);
      const f32x4 x2 = *(const f32x4*)(pa + half);
      const f32x4 x3 = *(const f32x4*)(pa + half + 4);
#pragma unroll
      for (int j = 0; j < 4; ++j) {
        ra0[j] = (bf16_t)x0[j];
        ra0[4 + j] = (bf16_t)x1[j];
        ra1[j] = (bf16_t)x2[j];
        ra1[4 + j] = (bf16_t)x3[j];
      }
    } else {
      const bf16_t* pa = (const bf16_t*)A + ea0 + k0;
      ra0 = *(const bf16x8*)pa;
      ra1 = *(const bf16x8*)(pa + half);
    }
    const bf16x8 rb0 = *(const bf16x8*)gb;
    const bf16x8 rb1 = *(const bf16x8*)(gb + half);
    gb += 32;
    __syncthreads();
    *(bf16x8*)lA = ra0;
    *(bf16x8*)(lA + 2048) = ra1;
    *(bf16x8*)lB = rb0;
    *(bf16x8*)(lB + 2048) = rb1;
    __syncthreads();
    bf16x8 af[4], bfr[4];
#pragma unroll
    for (int i = 0; i < 4; ++i)
      af[i] = *(const bf16x8*)(As + (wm + i * 16 + fr) * 32 + fk);
#pragma unroll
    for (int j = 0; j < 4; ++j)
      bfr[j] = *(const bf16x8*)(Bs + (wn + j * 16 + fr) * 32 + fk);
#pragma unroll
    for (int i = 0; i < 4; ++i)
#pragma unroll
      for (int j = 0; j < 4; ++j)
        acc[i][j] = MFMA16(af[i], bfr[j], acc[i][j]);
  }

  const int fg = lane >> 4;
#pragma unroll
  for (int i = 0; i < 4; ++i) {
#pragma unroll
    for (int j = 0; j < 4; ++j) {
#pragma unroll
      for (int r = 0; r < 4; ++r) {
        const int row = m0 + wm + i * 16 + fg * 4 + r;
        const int col = n0 + wn + j * 16 + fr;
        const size_t idx = (size_t)row * N + col;
        if (C32)
          ((float*)C)[idx] = acc[i][j][r];
        else
          ((bf16_t*)C)[idx] = (bf16_t)acc[i][j][r];
      }
    }
  }
}

// ---------------------------------------------------------------------------
// K rope extract: qkv (B*T,6144) -> Kr (B,H,T,D) bf16 rope'd.
// ---------------------------------------------------------------------------
__global__ __launch_bounds__(256) void rope_k(
    const bf16_t* __restrict__ qkv, const bf16_t* __restrict__ cosb,
    const bf16_t* __restrict__ sinb, bf16_t* __restrict__ Kr) {
  const int row = blockIdx.x;  // b*2048 + t
  const int t = row & 2047;
  const int b = row >> 11;
  const int idx = threadIdx.x * 8;
  const int h = idx >> 7;
  const int d = idx & 127;
  const float sgn = (d < 64) ? -1.f : 1.f;
  const bf16_t* base = qkv + (size_t)row * 6144 + 2048;
  const bf16x8 kv = *(const bf16x8*)(base + idx);
  const bf16x8 kp = *(const bf16x8*)(base + (idx ^ 64));
  const bf16x8 cv = *(const bf16x8*)(cosb + t * 128 + d);
  const bf16x8 sv = *(const bf16x8*)(sinb + t * 128 + d);
  bf16x8 o;
#pragma unroll
  for (int jj = 0; jj < 8; ++jj)
    o[jj] = (bf16_t)(((float)kv[jj]) * ((float)cv[jj]) +
                     sgn * ((float)kp[jj]) * ((float)sv[jj]));
  *(bf16x8*)(Kr + ((size_t)(b * 16 + h) * 2048 + t) * 128 + d) = o;
}

// ---------------------------------------------------------------------------
// V extract + transpose: qkv cols 4096.. -> Vt (B,H,D,T).
// ---------------------------------------------------------------------------
__global__ __launch_bounds__(256) void transpose_v(
    const bf16_t* __restrict__ qkv, bf16_t* __restrict__ Vt) {
  __shared__ bf16_t tile[64][72];
  const int bh = blockIdx.z;
  const int b = bh >> 4, h = bh & 15;
  const int t0 = blockIdx.x * 64;
  const int d0 = blockIdx.y * 64;
  const int t = threadIdx.x;
  const int r = t >> 3;
  const int c8 = (t & 7) * 8;
#pragma unroll
  for (int ii = 0; ii < 2; ++ii) {
    const int rr = r + ii * 32;
    *(bf16x8*)(&tile[rr][c8]) =
        *(const bf16x8*)(qkv + (size_t)(b * 2048 + t0 + rr) * 6144 + 4096 + h * 128 + d0 + c8);
  }
  __syncthreads();
#pragma unroll
  for (int ii = 0; ii < 2; ++ii) {
    const int rr = r + ii * 32;
    bf16x8 o;
#pragma unroll
    for (int jj = 0; jj < 8; ++jj) o[jj] = tile[c8 + jj][rr];
    *(bf16x8*)(Vt + ((size_t)bh * 128 + d0 + rr) * 2048 + t0 + c8) = o;
  }
}

// ---------------------------------------------------------------------------
// Flash (round-6 structure, unchanged): QBLK=64, swapped QK^T via
// global_load_lds K staging with rule-#21 involution, in-register P,
// π-permuted Vs, T14 pipeline, ks-outer QK^T.
// ---------------------------------------------------------------------------
__global__ __launch_bounds__(256, 4) void flash_q64p(
    const bf16_t* __restrict__ qkv, const bf16_t* __restrict__ cosb,
    const bf16_t* __restrict__ sinb, const bf16_t* __restrict__ Kr,
    const bf16_t* __restrict__ Vt, bf16_t* __restrict__ Y) {
  constexpr int T = 2048;
  __shared__ __align__(1024) bf16_t Ks[64 * 128];  // swizzled linear tile
  __shared__ bf16_t Vs[128][72];
  const int tid = threadIdx.x;
  const int lane = tid & 63;
  const int fr = lane & 15;
  const int fg = lane >> 4;
  const int qt = blockIdx.x;  // 0..31, 64 q-rows each
  const int bh = blockIdx.y;
  const int b = bh >> 4, h = bh & 15;

  // Q rope'd on the fly; scale = rsqrt(128) * log2(e) folded in.
  const int wave = tid >> 6;
  const int trow = qt * 64 + wave * 16 + fr;
  const bf16_t* qrow = qkv + (size_t)(b * T + trow) * 6144 + h * 128;
  bf16x8 qf[4];
#pragma unroll
  for (int ks = 0; ks < 4; ++ks) {
    const int d = ks * 32 + fg * 8;
    const float sgn = (d < 64) ? -1.f : 1.f;
    const bf16x8 qv = *(const bf16x8*)(qrow + d);
    const bf16x8 qp = *(const bf16x8*)(qrow + (d ^ 64));
    const bf16x8 cv = *(const bf16x8*)(cosb + trow * 128 + d);
    const bf16x8 sv = *(const bf16x8*)(sinb + trow * 128 + d);
    bf16x8 o;
#pragma unroll
    for (int jj = 0; jj < 8; ++jj)
      o[jj] = (bf16_t)((((float)qv[jj]) * ((float)cv[jj]) +
                        sgn * ((float)qp[jj]) * ((float)sv[jj])) *
                       0.1275174825f);  // (1/sqrt(128)) * log2(e)
    qf[ks] = o;
  }

  f32x4 acc[8] = {};
  float l_i = 0.f;

  const int krow = tid >> 4;                    // 0..15
  const int sc = (tid & 15) ^ (krow & 7);       // pre-swizzled source chunk
  const int vrow = tid >> 3;        // 0..31 (d rows, +32*it)
  const int vu = tid & 7;           // t-chunk index (8 consecutive t)
  const int vc0 = ((vu >> 2) * 32) + ((vu & 1) * 16) + (((vu >> 1) & 1) * 4);
  const bf16_t* Kh = Kr + (size_t)bh * T * 128;
  const bf16_t* Vh = Vt + (size_t)bh * 128 * T;

  auto stageK = [&](int t0) {
#pragma unroll
    for (int it = 0; it < 4; ++it)
      gll16(Kh + (size_t)(t0 + it * 16 + krow) * 128 + sc * 8,
            Ks + it * 2048 + tid * 8);
  };
  bf16x8 vreg[4];
  auto loadV = [&](int t0) {
#pragma unroll
    for (int it = 0; it < 4; ++it)
      vreg[it] = *(const bf16x8*)(Vh + (size_t)(it * 32 + vrow) * T + t0 + vu * 8);
  };
  auto writeV = [&]() {
#pragma unroll
    for (int it = 0; it < 4; ++it) {
      const int row = it * 32 + vrow;
      const bf16x8 v = vreg[it];
      bf16x4 lo, hi;
#pragma unroll
      for (int jj = 0; jj < 4; ++jj) {
        lo[jj] = v[jj];
        hi[jj] = v[4 + jj];
      }
      *(bf16x4*)(&Vs[row][vc0]) = lo;      // t = base+0..3  (b2=0)
      *(bf16x4*)(&Vs[row][vc0 + 8]) = hi;  // t = base+4..7  (b2=1)
    }
  };

  // prologue: stage tile 0
  stageK(0);
  loadV(0);
  asm volatile("s_waitcnt vmcnt(0)" ::: "memory");
  __builtin_amdgcn_sched_barrier(0);
  writeV();
  __syncthreads();

  const int cswz = (fr & 7) << 4;  // read-side XOR for Ks
  const char* kbase = (const char*)Ks;

  for (int j = 0; j < T / 64; ++j) {
    // QK^T swapped: lane holds P[q=fr][k=n*16+fg*4+r]. ks-outer.
    f32x4 sacc[4] = {};
#pragma unroll
    for (int ks = 0; ks < 4; ++ks) {
#pragma unroll
      for (int n = 0; n < 4; ++n) {
        const bf16x8 kf = *(const bf16x8*)(kbase + (n * 16 + fr) * 256 +
                                           ((ks * 64 + fg * 16) ^ cswz));
        sacc[n] = MFMA16(kf, qf[ks], sacc[n]);
      }
    }
    __syncthreads();  // Ks consumed by all waves

    const bool more = (j + 1 < T / 64);
    if (more) {
      stageK((j + 1) * 64);  // DMA into Ks (dead) while exp+PV run
      loadV((j + 1) * 64);
    }

    // exp + in-register pack into PV A-fragments.
    bf16x8 paf[2];
    float lsum = 0.f;
#pragma unroll
    for (int ks2 = 0; ks2 < 2; ++ks2) {
#pragma unroll
      for (int jj = 0; jj < 8; ++jj) {
        const float p = exp2f(sacc[ks2 * 2 + (jj >> 2)][jj & 3]);
        lsum += p;
        paf[ks2][jj] = (bf16_t)p;
      }
    }
    l_i += lsum;

    // PV: Vs column order matches paf's k order by construction.
#pragma unroll
    for (int ks2 = 0; ks2 < 2; ++ks2) {
#pragma unroll
      for (int n = 0; n < 8; ++n) {
        const bf16x8 vf = *(const bf16x8*)(&Vs[n * 16 + fr][ks2 * 32 + fg * 8]);
        acc[n] = MFMA16(paf[ks2], vf, acc[n]);
      }
    }

    asm volatile("s_waitcnt vmcnt(0)" ::: "memory");  // K DMA + V regs landed
    __builtin_amdgcn_sched_barrier(0);
    __syncthreads();  // Vs consumed by all; Ks(j+1) visible
    if (more) {
      writeV();
      __syncthreads();  // Vs(j+1) ready
    }
  }

  // epilogue: l reduce across fg groups, then fetch 1/l per output row.
  float l = l_i;
  l += __shfl_xor(l, 16, 64);
  l += __shfl_xor(l, 32, 64);  // lanes with same fr now hold l_full(q=fr)
#pragma unroll
  for (int r = 0; r < 4; ++r) {
    const float inv = 1.0f / __shfl(l, fg * 4 + r, 64);
    const int t = qt * 64 + wave * 16 + fg * 4 + r;
    bf16_t* yrow = Y + (size_t)(b * T + t) * 2048 + h * 128;
#pragma unroll
    for (int n = 0; n < 8; ++n)
      yrow[n * 16 + fr] = (bf16_t)(acc[n][r] * inv);
  }
}

// ---------------------------------------------------------------------------
// Flash fallback (ws-lean): fused rope, exp-only softmax. (unchanged)
// ---------------------------------------------------------------------------
__global__ __launch_bounds__(256) void flash_fused_v2(
    const bf16_t* __restrict__ qkv, const bf16_t* __restrict__ cosb,
    const bf16_t* __restrict__ sinb, bf16_t* __restrict__ Y) {
  constexpr int T = 2048;
  __shared__ bf16_t Ks[64][136];
  __shared__ bf16_t Vs[128][72];
  __shared__ bf16_t Ps[128][72];
  const int tid = threadIdx.x;
  const int lane = tid & 63;
  const int wave = tid >> 6;
  const int fr = lane & 15;
  const int fg = lane >> 4;
  const int qt = blockIdx.x;
  const int bh = blockIdx.y;
  const int b = bh >> 4, h = bh & 15;

  const bf16_t* qbase = qkv + (size_t)b * T * 6144 + h * 128;
  bf16x8 qf[2][4];
#pragma unroll
  for (int i = 0; i < 2; ++i) {
    const int trow = qt * 128 + wave * 32 + i * 16 + fr;
    const bf16_t* qrow = qbase + (size_t)trow * 6144;
#pragma unroll
    for (int ks = 0; ks < 4; ++ks) {
      const int d = ks * 32 + fg * 8;
      const float sgn = (d < 64) ? -1.f : 1.f;
      const bf16x8 qv = *(const bf16x8*)(qrow + d);
      const bf16x8 qp = *(const bf16x8*)(qrow + (d ^ 64));
      const bf16x8 cv = *(const bf16x8*)(cosb + trow * 128 + d);
      const bf16x8 sv = *(const bf16x8*)(sinb + trow * 128 + d);
      bf16x8 o;
#pragma unroll
      for (int jj = 0; jj < 8; ++jj)
        o[jj] = (bf16_t)((((float)qv[jj]) * ((float)cv[jj]) +
                          sgn * ((float)qp[jj]) * ((float)sv[jj])) *
                         0.08838834764831845f);
      qf[i][ks] = o;
    }
  }

  f32x4 acc[2][8] = {};
  float l_i[2][4] = {};

  const int kr = tid >> 4;
  const int kc = (tid & 15) * 8;
  const float sgnk = (kc < 64) ? -1.f : 1.f;
  const int tp = tid & 63;

  for (int j = 0; j < T / 64; ++j) {
    const int t0 = j * 64;
#pragma unroll
    for (int it = 0; it < 4; ++it) {
      const int row = it * 16 + kr;
      const int tg = t0 + row;
      const bf16_t* krow = qkv + ((size_t)(b * T + tg)) * 6144 + 2048 + h * 128;
      const bf16x8 kv = *(const bf16x8*)(krow + kc);
      const bf16x8 kp = *(const bf16x8*)(krow + (kc ^ 64));
      const bf16x8 cv = *(const bf16x8*)(cosb + tg * 128 + kc);
      const bf16x8 sv = *(const bf16x8*)(sinb + tg * 128 + kc);
      bf16x8 o;
#pragma unroll
      for (int jj = 0; jj < 8; ++jj)
        o[jj] = (bf16_t)(((float)kv[jj]) * ((float)cv[jj]) +
                         sgnk * ((float)kp[jj]) * ((float)sv[jj]));
      *(bf16x8*)(&Ks[row][kc]) = o;
    }
#pragma unroll
    for (int cc = 0; cc < 4; ++cc) {
      const int d8 = (cc * 4 + (tid >> 6)) * 8;
      const bf16x8 vv = *(const bf16x8*)(qkv + ((size_t)(b * T + t0 + tp)) * 6144 +
                                         4096 + h * 128 + d8);
#pragma unroll
      for (int jj = 0; jj < 8; ++jj) Vs[d8 + jj][tp] = vv[jj];
    }
    __syncthreads();

    f32x4 sacc[2][4] = {};
#pragma unroll
    for (int ks = 0; ks < 4; ++ks) {
#pragma unroll
      for (int n = 0; n < 4; ++n) {
        const bf16x8 kf = *(const bf16x8*)(&Ks[n * 16 + fr][ks * 32 + fg * 8]);
        sacc[0][n] = MFMA16(qf[0][ks], kf, sacc[0][n]);
        sacc[1][n] = MFMA16(qf[1][ks], kf, sacc[1][n]);
      }
    }

#pragma unroll
    for (int i = 0; i < 2; ++i) {
#pragma unroll
      for (int r = 0; r < 4; ++r) {
        const float p0 = __expf(sacc[i][0][r]);
        const float p1 = __expf(sacc[i][1][r]);
        const float p2 = __expf(sacc[i][2][r]);
        const float p3 = __expf(sacc[i][3][r]);
        l_i[i][r] += (p0 + p1) + (p2 + p3);
        const int prow = wave * 32 + i * 16 + fg * 4 + r;
        Ps[prow][0 + fr] = (bf16_t)p0;
        Ps[prow][16 + fr] = (bf16_t)p1;
        Ps[prow][32 + fr] = (bf16_t)p2;
        Ps[prow][48 + fr] = (bf16_t)p3;
      }
    }

#pragma unroll
    for (int ks = 0; ks < 2; ++ks) {
      const bf16x8 pf0 = *(const bf16x8*)(&Ps[wave * 32 + fr][ks * 32 + fg * 8]);
      const bf16x8 pf1 = *(const bf16x8*)(&Ps[wave * 32 + 16 + fr][ks * 32 + fg * 8]);
#pragma unroll
      for (int n = 0; n < 8; ++n) {
        const bf16x8 vf = *(const bf16x8*)(&Vs[n * 16 + fr][ks * 32 + fg * 8]);
        acc[0][n] = MFMA16(pf0, vf, acc[0][n]);
        acc[1][n] = MFMA16(pf1, vf, acc[1][n]);
      }
    }
    __syncthreads();
  }

#pragma unroll
  for (int i = 0; i < 2; ++i) {
#pragma unroll
    for (int r = 0; r < 4; ++r) {
      float l = l_i[i][r];
#pragma unroll
      for (int msk = 1; msk < 16; msk <<= 1) l += __shfl_xor(l, msk, 64);
      const float inv = 1.0f / l;
      const int t = qt * 128 + wave * 32 + i * 16 + fg * 4 + r;
      bf16_t* yrow = Y + (size_t)(b * T + t) * 2048 + h * 128;
#pragma unroll
      for (int n = 0; n < 8; ++n)
        yrow[n * 16 + fr] = (bf16_t)(acc[i][n][r] * inv);
    }
  }
}

// ---------------------------------------------------------------------------
extern "C" void kernel_launch(void* const* d_in, const int* in_sizes, int n_in,
                              void* d_out, int out_size, void* d_ws, size_t ws_size,
                              hipStream_t stream) {
  const float* x = (const float*)d_in[0];
  const float* cosi = (const float*)d_in[1];
  const float* sini = (const float*)d_in[2];
  const float* Wqkv = (const float*)d_in[3];
  const float* Wproj = (const float*)d_in[4];

  const size_t NEED_FAST = sizeof(bf16_t) *
      ((size_t)12582912 + 262144 + 262144 + 25165824 + 8388608 + 8388608);
  const size_t NEED_BASE = 256 + sizeof(bf16_t) *
      ((size_t)12582912 + 4194304 + 262144 + 262144 + 25165824);

  if (ws_size >= NEED_FAST) {
    bf16_t* base = (bf16_t*)d_ws;
    bf16_t* WqkvT = base;                    // dead after gemm1
    bf16_t* y = base;                        // alias
    bf16_t* cosb = base + 12582912;
    bf16_t* sinb = cosb + 262144;
    bf16_t* qkv = sinb + 262144;             // live through flash
    bf16_t* WprojT = qkv;                    // alias head, written after flash
    bf16_t* Kr = qkv + 25165824;
    bf16_t* xb = Kr;                         // alias: x-bf16, dead before rope_k
    bf16_t* Vt = Kr + 8388608;

    conv_vec_f32<<<128, 256, 0, stream>>>(cosi, cosb, 32768);
    conv_vec_f32<<<128, 256, 0, stream>>>(sini, sinb, 32768);
    conv_vec_f32<<<4096, 256, 0, stream>>>(x, xb, 1048576);  // x -> bf16
    conv_transpose_f32<<<dim3(96, 32), 256, 0, stream>>>(Wqkv, WqkvT, 2048, 6144);
    gemm8n<false><<<768, 512, 0, stream>>>(xb, WqkvT, qkv, 4096, 6144, 2048, 24);
    rope_k<<<4096, 256, 0, stream>>>(qkv, cosb, sinb, Kr);  // overwrites xb (dead)
    transpose_v<<<dim3(32, 2, 32), 256, 0, stream>>>(qkv, Vt);
    flash_q64p<<<dim3(32, 32), 256, 0, stream>>>(qkv, cosb, sinb, Kr, Vt, y);
    conv_transpose_f32<<<dim3(32, 32), 256, 0, stream>>>(Wproj, WprojT, 2048, 2048);
    gemm8n<true><<<256, 512, 0, stream>>>(y, WprojT, d_out, 4096, 2048, 2048, 8);
  } else if (ws_size >= NEED_BASE) {
    bf16_t* base = (bf16_t*)((char*)d_ws + 256);
    bf16_t* WqkvT = base;
    bf16_t* y = base;
    bf16_t* WprojT = base + 12582912;
    bf16_t* cosb = WprojT + 4194304;
    bf16_t* sinb = cosb + 262144;
    bf16_t* qkv = sinb + 262144;

    conv_vec_f32<<<128, 256, 0, stream>>>(cosi, cosb, 32768);
    conv_vec_f32<<<128, 256, 0, stream>>>(sini, sinb, 32768);
    conv_transpose_f32<<<dim3(96, 32), 256, 0, stream>>>(Wqkv, WqkvT, 2048, 6144);
    gemm_t<true, false><<<dim3(32, 48), 256, 0, stream>>>(x, WqkvT, qkv, 4096, 6144, 2048);
    flash_fused_v2<<<dim3(16, 32), 256, 0, stream>>>(qkv, cosb, sinb, y);
    conv_transpose_f32<<<dim3(32, 32), 256, 0, stream>>>(Wproj, WprojT, 2048, 2048);
    gemm_t<false, true><<<dim3(32, 16), 256, 0, stream>>>(y, WprojT, d_out, 4096, 2048, 2048);
  } else {
    fill_diag<<<(out_size + 255) / 256, 256, 0, stream>>>((uint32_t*)d_out, out_size);
  }
}

// Round 8
// 413.389 us; speedup vs baseline: 1.6772x; 1.0152x over previous
//
#include <hip/hip_runtime.h>
#include <cstdint>
#include <cstddef>

typedef __bf16 bf16_t;
typedef __bf16 bf16x8 __attribute__((ext_vector_type(8)));
typedef __bf16 bf16x4 __attribute__((ext_vector_type(4)));
typedef float f32x4 __attribute__((ext_vector_type(4)));

#define MFMA16(a, b, c) __builtin_amdgcn_mfma_f32_16x16x32_bf16(a, b, c, 0, 0, 0)

// async global->LDS, 16B per lane. LDS dest = wave-uniform base + lane*16.
__device__ __forceinline__ void gll16(const bf16_t* g, bf16_t* l) {
  __builtin_amdgcn_global_load_lds(
      (__attribute__((address_space(1))) uint32_t*)((uintptr_t)g),
      (__attribute__((address_space(3))) uint32_t*)((uint32_t)(uintptr_t)l),
      16, 0, 0);
}

// Diagnostic: absmax ~1000 => ws_size too small.
__global__ void fill_diag(uint32_t* out, int n_u32) {
  int i = blockIdx.x * 256 + threadIdx.x;
  if (i < n_u32) out[i] = 0x447A0000u;  // f32 1000.0
}

// ---------------------------------------------------------------------------
// f32 -> bf16 vector convert (x, cos/sin tables). One bf16x8 per thread.
// ---------------------------------------------------------------------------
__global__ void conv_vec_f32(const float* __restrict__ in, bf16_t* __restrict__ out,
                             int n8) {
  const int i = blockIdx.x * 256 + threadIdx.x;
  if (i >= n8) return;
  const float* p = in + (size_t)i * 8;
  const f32x4 a = *(const f32x4*)p;
  const f32x4 b = *(const f32x4*)(p + 4);
  bf16x8 o;
#pragma unroll
  for (int j = 0; j < 4; ++j) {
    o[j] = (bf16_t)a[j];
    o[4 + j] = (bf16_t)b[j];
  }
  ((bf16x8*)out)[i] = o;
}

// ---------------------------------------------------------------------------
// 64x64 tiled transpose+convert: in R x C f32 -> out C x R bf16.
// ---------------------------------------------------------------------------
__global__ __launch_bounds__(256) void conv_transpose_f32(
    const float* __restrict__ in, bf16_t* __restrict__ out, int R, int C) {
  __shared__ bf16_t tile[64][72];
  const int bc = blockIdx.x * 64;
  const int br = blockIdx.y * 64;
  const int t = threadIdx.x;
  const int r = t >> 3;
  const int c8 = (t & 7) * 8;
#pragma unroll
  for (int ii = 0; ii < 2; ++ii) {
    const int rr = r + ii * 32;
    const float* p = in + (size_t)(br + rr) * C + bc + c8;
    const f32x4 a = *(const f32x4*)p;
    const f32x4 b = *(const f32x4*)(p + 4);
    bf16x8 v;
#pragma unroll
    for (int j = 0; j < 4; ++j) {
      v[j] = (bf16_t)a[j];
      v[4 + j] = (bf16_t)b[j];
    }
    *(bf16x8*)(&tile[rr][c8]) = v;
  }
  __syncthreads();
#pragma unroll
  for (int ii = 0; ii < 2; ++ii) {
    const int rr = r + ii * 32;
    bf16x8 o;
#pragma unroll
    for (int jj = 0; jj < 8; ++jj) o[jj] = tile[c8 + jj][rr];
    *(bf16x8*)(out + (size_t)(bc + rr) * R + br + c8) = o;
  }
}

// ---------------------------------------------------------------------------
// 256x256 8-phase GEMM (round-6 version, REVERTED for qkv: the 128x256 retile
// raised FETCH 176->307MB and lost its fill gain to HBM/L2 traffic).
// ---------------------------------------------------------------------------
#define MF8(MLO, AARR, BARR, NLO)                                              \
  do {                                                                         \
    _Pragma("unroll") for (int k_ = 0; k_ < 2; ++k_) {                         \
      _Pragma("unroll") for (int m_ = 0; m_ < 4; ++m_) {                       \
        _Pragma("unroll") for (int n_ = 0; n_ < 2; ++n_) {                     \
          acc[(MLO) + m_][(NLO) + n_] = MFMA16(AARR[m_][k_], BARR[n_][k_],     \
                                               acc[(MLO) + m_][(NLO) + n_]);   \
        }                                                                      \
      }                                                                        \
    }                                                                          \
  } while (0)

template <bool C32>
__global__ __launch_bounds__(512, 2) void gemm8(
    const bf16_t* __restrict__ A, const bf16_t* __restrict__ Bt,
    void* __restrict__ C, int M, int N, int K, int nbn) {
  __shared__ __align__(1024) bf16_t lds8[65536];  // A: [0,32768), B: [32768,65536)
  bf16_t* As = lds8;
  bf16_t* Bs = lds8 + 32768;

  const int tid = threadIdx.x;
  const int lane = tid & 63;
  const int wave = tid >> 6;
  const int wr = wave >> 2;  // 0..1 (M half)
  const int wc = wave & 3;   // 0..3 (N quarter)
  const int fr = lane & 15;
  const int fg = lane >> 4;

  // XCD-aware bijective swizzle (nwg % 8 == 0 by construction).
  const int nwg = gridDim.x;
  const int bid = blockIdx.x;
  const int swz = (bid & 7) * (nwg >> 3) + (bid >> 3);
  const int m0 = (swz / nbn) * 256;
  const int n0 = (swz % nbn) * 256;

  const int NT = K >> 6;  // BK=64 tiles

  // staging geometry: wave covers segs {2w, 2w+1}; seg = 8 rows of 128B.
  const int sseg0 = wave * 2;
  const int srow = lane >> 3;
  const int sj = lane & 7;

  auto stage = [&](const bf16_t* __restrict__ G, int row0, bf16_t* L, int kt,
                   int h) {
#pragma unroll
    for (int l = 0; l < 2; ++l) {
      const int seg = sseg0 + l;
      const int r = seg * 8 + srow;       // row in half-tile 0..127
      const int j = sj ^ (r & 7);         // inverse-swizzled source chunk
      const bf16_t* src = G + (size_t)(row0 + h * 128 + r) * K + kt * 64 + j * 8;
      gll16(src, L + ((2 * kt + h) & 3) * 8192 + seg * 512 + lane * 8);
    }
  };

  const int cb0 = (fg * 16) ^ ((fr & 7) << 4);  // kk=0 byte col (swizzled)

  auto lda = [&](bf16x8(&af)[4][2], int kt, int mlo) {
    const char* base = (const char*)(As + ((2 * kt + wr) & 3) * 8192);
#pragma unroll
    for (int m = 0; m < 4; ++m) {
      const char* p = base + ((mlo + m) * 16 + fr) * 128;
      af[m][0] = *(const bf16x8*)(p + cb0);
      af[m][1] = *(const bf16x8*)(p + (cb0 ^ 64));
    }
  };
  auto ldb = [&](bf16x8(&bf)[2][2], int kt, int nlo) {
    const char* base = (const char*)(Bs + ((2 * kt + (wc >> 1)) & 3) * 8192);
#pragma unroll
    for (int n = 0; n < 2; ++n) {
      const char* p = base + ((wc & 1) * 64 + (nlo + n) * 16 + fr) * 128;
      bf[n][0] = *(const bf16x8*)(p + cb0);
      bf[n][1] = *(const bf16x8*)(p + (cb0 ^ 64));
    }
  };

  f32x4 acc[8][4] = {};

  // Prologue: A(0), B(0), B(1); drain A(0)+B(0), keep B(1) in flight.
  stage(A, m0, As, 0, 0);
  stage(A, m0, As, 0, 1);
  stage(Bt, n0, Bs, 0, 0);
  stage(Bt, n0, Bs, 0, 1);
  stage(Bt, n0, Bs, 1, 0);
  stage(Bt, n0, Bs, 1, 1);
  asm volatile("s_waitcnt vmcnt(4)" ::: "memory");
  __builtin_amdgcn_s_barrier();

  bf16x8 af[4][2], bfA[2][2], bfB[2][2];

  for (int u = 0; u < NT; u += 2) {
    const bool st2 = (u + 2 < NT);
    const bool st3 = (u + 3 < NT);
    // ---------------- tile u ----------------
    lda(af, u, 0);
    ldb(bfA, u, 0);
    stage(A, m0, As, u + 1, 0);
    asm volatile("s_waitcnt lgkmcnt(8)" ::: "memory");
    __builtin_amdgcn_s_barrier();
    asm volatile("s_waitcnt lgkmcnt(0)" ::: "memory");
    __builtin_amdgcn_sched_barrier(0);
    __builtin_amdgcn_s_setprio(1);
    MF8(0, af, bfA, 0);
    __builtin_amdgcn_s_setprio(0);
    __builtin_amdgcn_s_barrier();
    ldb(bfB, u, 2);
    stage(A, m0, As, u + 1, 1);
    __builtin_amdgcn_s_barrier();
    asm volatile("s_waitcnt lgkmcnt(0)" ::: "memory");
    __builtin_amdgcn_sched_barrier(0);
    __builtin_amdgcn_s_setprio(1);
    MF8(0, af, bfB, 2);
    __builtin_amdgcn_s_setprio(0);
    __builtin_amdgcn_s_barrier();
    lda(af, u, 4);
    if (st2) stage(Bt, n0, Bs, u + 2, 0);
    __builtin_amdgcn_s_barrier();
    asm volatile("s_waitcnt lgkmcnt(0)" ::: "memory");
    __builtin_amdgcn_sched_barrier(0);
    __builtin_amdgcn_s_setprio(1);
    MF8(4, af, bfB, 2);
    __builtin_amdgcn_s_setprio(0);
    __builtin_amdgcn_s_barrier();
    if (st2) stage(Bt, n0, Bs, u + 2, 1);
    __builtin_amdgcn_s_barrier();
    __builtin_amdgcn_s_setprio(1);
    MF8(4, af, bfA, 0);
    __builtin_amdgcn_s_setprio(0);
    asm volatile("s_waitcnt vmcnt(4)" ::: "memory");
    __builtin_amdgcn_s_barrier();
    // ---------------- tile u+1 ----------------
    lda(af, u + 1, 0);
    ldb(bfA, u + 1, 0);
    if (st2) stage(A, m0, As, u + 2, 0);
    asm volatile("s_waitcnt lgkmcnt(8)" ::: "memory");
    __builtin_amdgcn_s_barrier();
    asm volatile("s_waitcnt lgkmcnt(0)" ::: "memory");
    __builtin_amdgcn_sched_barrier(0);
    __builtin_amdgcn_s_setprio(1);
    MF8(0, af, bfA, 0);
    __builtin_amdgcn_s_setprio(0);
    __builtin_amdgcn_s_barrier();
    ldb(bfB, u + 1, 2);
    if (st2) stage(A, m0, As, u + 2, 1);
    __builtin_amdgcn_s_barrier();
    asm volatile("s_waitcnt lgkmcnt(0)" ::: "memory");
    __builtin_amdgcn_sched_barrier(0);
    __builtin_amdgcn_s_setprio(1);
    MF8(0, af, bfB, 2);
    __builtin_amdgcn_s_setprio(0);
    __builtin_amdgcn_s_barrier();
    lda(af, u + 1, 4);
    if (st3) stage(Bt, n0, Bs, u + 3, 0);
    __builtin_amdgcn_s_barrier();
    asm volatile("s_waitcnt lgkmcnt(0)" ::: "memory");
    __builtin_amdgcn_sched_barrier(0);
    __builtin_amdgcn_s_setprio(1);
    MF8(4, af, bfB, 2);
    __builtin_amdgcn_s_setprio(0);
    __builtin_amdgcn_s_barrier();
    if (st3) stage(Bt, n0, Bs, u + 3, 1);
    __builtin_amdgcn_s_barrier();
    __builtin_amdgcn_s_setprio(1);
    MF8(4, af, bfA, 0);
    __builtin_amdgcn_s_setprio(0);
    asm volatile("s_waitcnt vmcnt(4)" ::: "memory");
    __builtin_amdgcn_s_barrier();
  }

#pragma unroll
  for (int m = 0; m < 8; ++m) {
#pragma unroll
    for (int n = 0; n < 4; ++n) {
#pragma unroll
      for (int r = 0; r < 4; ++r) {
        const int row = m0 + wr * 128 + m * 16 + fg * 4 + r;
        const int col = n0 + wc * 64 + n * 16 + fr;
        const size_t idx = (size_t)row * N + col;
        if (C32)
          ((float*)C)[idx] = acc[m][n][r];
        else
          ((bf16_t*)C)[idx] = (bf16_t)acc[m][n][r];
      }
    }
  }
  (void)M;
}

// ---------------------------------------------------------------------------
// gemm8n: 128x256-tile 2-phase GEMM — kept ONLY for the proj GEMM (grid 256
// = exactly 1 CU round; measured round-7 improvement vs gemm_lds).
// ---------------------------------------------------------------------------
template <bool C32>
__global__ __launch_bounds__(512, 2) void gemm8n(
    const bf16_t* __restrict__ A, const bf16_t* __restrict__ Bt,
    void* __restrict__ C, int M, int N, int K, int nbn) {
  __shared__ __align__(1024) bf16_t lds8[65536];  // A: 3x8192, B: 5x8192 (bf16)
  bf16_t* As = lds8;           // 3 slots * 8192 el
  bf16_t* Bs = lds8 + 24576;   // 5 slots * 8192 el

  const int tid = threadIdx.x;
  const int lane = tid & 63;
  const int wave = tid >> 6;
  const int wr = wave >> 2;
  const int wc = wave & 3;
  const int fr = lane & 15;
  const int fg = lane >> 4;

  const int nwg = gridDim.x;
  const int bid = blockIdx.x;
  const int swz = (bid & 7) * (nwg >> 3) + (bid >> 3);
  const int m0 = (swz / nbn) * 128;
  const int n0 = (swz % nbn) * 256;

  const int NT = K >> 6;

  const int srow = tid >> 3;  // 0..63
  const int sj = tid & 7;

  auto stage = [&](const bf16_t* __restrict__ G, int grow0, bf16_t* slotBase,
                   int kt) {
#pragma unroll
    for (int l = 0; l < 2; ++l) {
      const int r = l * 64 + srow;
      const int j = sj ^ (r & 7);
      gll16(G + (size_t)(grow0 + r) * K + kt * 64 + j * 8,
            slotBase + l * 4096 + tid * 8);
    }
  };

  const int cb0 = (fg * 16) ^ ((fr & 7) << 4);

  auto lda = [&](bf16x8(&af)[4][2], int t) {
    const char* base = (const char*)(As + (t % 3) * 8192);
#pragma unroll
    for (int m = 0; m < 4; ++m) {
      const char* p = base + (wr * 64 + m * 16 + fr) * 128;
      af[m][0] = *(const bf16x8*)(p + cb0);
      af[m][1] = *(const bf16x8*)(p + (cb0 ^ 64));
    }
  };
  auto ldb2 = [&](bf16x8(&bf)[2][2], int t, int nlo) {
    const char* base = (const char*)(Bs + ((2 * t + (wc >> 1)) % 5) * 8192);
#pragma unroll
    for (int n = 0; n < 2; ++n) {
      const char* p = base + ((wc & 1) * 64 + (nlo + n) * 16 + fr) * 128;
      bf[n][0] = *(const bf16x8*)(p + cb0);
      bf[n][1] = *(const bf16x8*)(p + (cb0 ^ 64));
    }
  };

  f32x4 acc[4][4] = {};

  stage(A, m0, As, 0);
  stage(A, m0, As + 8192, 1);
  stage(Bt, n0, Bs, 0);
  stage(Bt, n0 + 128, Bs + 8192, 0);
  stage(Bt, n0, Bs + 2 * 8192, 1);
  asm volatile("s_waitcnt vmcnt(2)" ::: "memory");
  __builtin_amdgcn_s_barrier();

  bf16x8 af[4][2], bf01[2][2], bf23[2][2];

  for (int t = 0; t < NT; ++t) {
    lda(af, t);
    ldb2(bf01, t, 0);
    if (t + 2 < NT) stage(Bt, n0, Bs + ((2 * t + 4) % 5) * 8192, t + 2);
    if (t + 1 < NT) stage(Bt, n0 + 128, Bs + ((2 * t + 3) % 5) * 8192, t + 1);
    asm volatile("s_waitcnt lgkmcnt(8)" ::: "memory");
    __builtin_amdgcn_s_barrier();
    asm volatile("s_waitcnt lgkmcnt(0)" ::: "memory");
    __builtin_amdgcn_sched_barrier(0);
    __builtin_amdgcn_s_setprio(1);
#pragma unroll
    for (int k = 0; k < 2; ++k)
#pragma unroll
      for (int m = 0; m < 4; ++m)
#pragma unroll
        for (int n = 0; n < 2; ++n)
          acc[m][n] = MFMA16(af[m][k], bf01[n][k], acc[m][n]);
    __builtin_amdgcn_s_setprio(0);
    __builtin_amdgcn_s_barrier();
    ldb2(bf23, t, 2);
    if (t + 2 < NT) stage(A, m0, As + ((t + 2) % 3) * 8192, t + 2);
    __builtin_amdgcn_s_barrier();
    asm volatile("s_waitcnt lgkmcnt(0)" ::: "memory");
    __builtin_amdgcn_sched_barrier(0);
    __builtin_amdgcn_s_setprio(1);
#pragma unroll
    for (int k = 0; k < 2; ++k)
#pragma unroll
      for (int m = 0; m < 4; ++m)
#pragma unroll
        for (int n = 0; n < 2; ++n)
          acc[m][n + 2] = MFMA16(af[m][k], bf23[n][k], acc[m][n + 2]);
    __builtin_amdgcn_s_setprio(0);
    if (t + 3 < NT) {
      asm volatile("s_waitcnt vmcnt(2)" ::: "memory");
    } else {
      asm volatile("s_waitcnt vmcnt(0)" ::: "memory");
    }
    __builtin_amdgcn_s_barrier();
  }

#pragma unroll
  for (int m = 0; m < 4; ++m) {
#pragma unroll
    for (int n = 0; n < 4; ++n) {
#pragma unroll
      for (int r = 0; r < 4; ++r) {
        const int row = m0 + wr * 64 + m * 16 + fg * 4 + r;
        const int col = n0 + wc * 64 + n * 16 + fr;
        const size_t idx = (size_t)row * N + col;
        if (C32)
          ((float*)C)[idx] = acc[m][n][r];
        else
          ((bf16_t*)C)[idx] = (bf16_t)acc[m][n][r];
      }
    }
  }
  (void)M;
}

// ---------------------------------------------------------------------------
// Register-staged GEMM (fallback path only): A f32 option, C f32 option.
// ---------------------------------------------------------------------------
template <bool A32, bool C32>
__global__ __launch_bounds__(256) void gemm_t(
    const void* __restrict__ A, const bf16_t* __restrict__ Bt,
    void* __restrict__ C, int M, int N, int K) {
  __shared__ bf16_t As[128 * 32];
  __shared__ bf16_t Bs[128 * 32];
  const int tid = threadIdx.x;
  const int lane = tid & 63;
  const int wave = tid >> 6;
  const int m0 = blockIdx.x * 128;
  const int n0 = blockIdx.y * 128;
  const int wm = (wave & 1) * 64;
  const int wn = (wave >> 1) * 64;
  const int fr = lane & 15;
  const int fk = (lane >> 4) * 8;

  f32x4 acc[4][4] = {};

  const size_t ea0 = (size_t)(m0 + (tid >> 2)) * K + (tid & 3) * 8;
  const bf16_t* gb = Bt + (size_t)(n0 + (tid >> 2)) * K + (tid & 3) * 8;
  bf16_t* lA = As + tid * 8;
  bf16_t* lB = Bs + tid * 8;
  const size_t half = (size_t)64 * K;

  for (int k0 = 0; k0 < K; k0 += 32) {
    bf16x8 ra0, ra1;
    if (A32) {
      const float* pa = (const float*)A + ea0 + k0;
      const f32x4 x0 = *(const f32x4*)pa;
      const f32x4 x1 = *(const f32x4*)(pa + 4);
      const f32x4 x2 = *(const f32x4*)(pa + half);
      const f32x4 x3 = *(const f32x4*)(pa + half + 4);
#pragma unroll
      for (int j = 0; j < 4; ++j) {
        ra0[j] = (bf16_t)x0[j];
        ra0[4 + j] = (bf16_t)x1[j];
        ra1[j] = (bf16_t)x2[j];
        ra1[4 + j] = (bf16_t)x3[j];
      }
    } else {
      const bf16_t* pa = (const bf16_t*)A + ea0 + k0;
      ra0 = *(const bf16x8*)pa;
      ra1 = *(const bf16x8*)(pa + half);
    }
    const bf16x8 rb0 = *(const bf16x8*)gb;
    const bf16x8 rb1 = *(const bf16x8*)(gb + half);
    gb += 32;
    __syncthreads();
    *(bf16x8*)lA = ra0;
    *(bf16x8*)(lA + 2048) = ra1;
    *(bf16x8*)lB = rb0;
    *(bf16x8*)(lB + 2048) = rb1;
    __syncthreads();
    bf16x8 af[4], bfr[4];
#pragma unroll
    for (int i = 0; i < 4; ++i)
      af[i] = *(const bf16x8*)(As + (wm + i * 16 + fr) * 32 + fk);
#pragma unroll
    for (int j = 0; j < 4; ++j)
      bfr[j] = *(const bf16x8*)(Bs + (wn + j * 16 + fr) * 32 + fk);
#pragma unroll
    for (int i = 0; i < 4; ++i)
#pragma unroll
      for (int j = 0; j < 4; ++j)
        acc[i][j] = MFMA16(af[i], bfr[j], acc[i][j]);
  }

  const int fg = lane >> 4;
#pragma unroll
  for (int i = 0; i < 4; ++i) {
#pragma unroll
    for (int j = 0; j < 4; ++j) {
#pragma unroll
      for (int r = 0; r < 4; ++r) {
        const int row = m0 + wm + i * 16 + fg * 4 + r;
        const int col = n0 + wn + j * 16 + fr;
        const size_t idx = (size_t)row * N + col;
        if (C32)
          ((float*)C)[idx] = acc[i][j][r];
        else
          ((bf16_t*)C)[idx] = (bf16_t)acc[i][j][r];
      }
    }
  }
}

// ---------------------------------------------------------------------------
// K rope extract: qkv (B*T,6144) -> Kr (B,H,T,D) bf16 rope'd.
// ---------------------------------------------------------------------------
__global__ __launch_bounds__(256) void rope_k(
    const bf16_t* __restrict__ qkv, const bf16_t* __restrict__ cosb,
    const bf16_t* __restrict__ sinb, bf16_t* __restrict__ Kr) {
  const int row = blockIdx.x;  // b*2048 + t
  const int t = row & 2047;
  const int b = row >> 11;
  const int idx = threadIdx.x * 8;
  const int h = idx >> 7;
  const int d = idx & 127;
  const float sgn = (d < 64) ? -1.f : 1.f;
  const bf16_t* base = qkv + (size_t)row * 6144 + 2048;
  const bf16x8 kv = *(const bf16x8*)(base + idx);
  const bf16x8 kp = *(const bf16x8*)(base + (idx ^ 64));
  const bf16x8 cv = *(const bf16x8*)(cosb + t * 128 + d);
  const bf16x8 sv = *(const bf16x8*)(sinb + t * 128 + d);
  bf16x8 o;
#pragma unroll
  for (int jj = 0; jj < 8; ++jj)
    o[jj] = (bf16_t)(((float)kv[jj]) * ((float)cv[jj]) +
                     sgn * ((float)kp[jj]) * ((float)sv[jj]));
  *(bf16x8*)(Kr + ((size_t)(b * 16 + h) * 2048 + t) * 128 + d) = o;
}

// ---------------------------------------------------------------------------
// V extract + transpose: qkv cols 4096.. -> Vt (B,H,D,T).
// ---------------------------------------------------------------------------
__global__ __launch_bounds__(256) void transpose_v(
    const bf16_t* __restrict__ qkv, bf16_t* __restrict__ Vt) {
  __shared__ bf16_t tile[64][72];
  const int bh = blockIdx.z;
  const int b = bh >> 4, h = bh & 15;
  const int t0 = blockIdx.x * 64;
  const int d0 = blockIdx.y * 64;
  const int t = threadIdx.x;
  const int r = t >> 3;
  const int c8 = (t & 7) * 8;
#pragma unroll
  for (int ii = 0; ii < 2; ++ii) {
    const int rr = r + ii * 32;
    *(bf16x8*)(&tile[rr][c8]) =
        *(const bf16x8*)(qkv + (size_t)(b * 2048 + t0 + rr) * 6144 + 4096 + h * 128 + d0 + c8);
  }
  __syncthreads();
#pragma unroll
  for (int ii = 0; ii < 2; ++ii) {
    const int rr = r + ii * 32;
    bf16x8 o;
#pragma unroll
    for (int jj = 0; jj < 8; ++jj) o[jj] = tile[c8 + jj][rr];
    *(bf16x8*)(Vt + ((size_t)bh * 128 + d0 + rr) * 2048 + t0 + c8) = o;
  }
}

// ---------------------------------------------------------------------------
// Flash round-8: QBLK=128 (q-per-wave=32) for 2x LDS-byte reuse — each kf/vf
// b128 read feeds TWO MFMAs (i=0,1). All round-5/6 machinery kept: K via
// global_load_lds + rule-#21 involution, π-permuted Vs, T14 prefetch
// pipeline, ks-outer MFMA ordering, in-register P, exp2 softmax.
// Grid (16,32)=512 blocks = 2/CU; kernel is LDS-throughput-bound so reduced
// TLP is acceptable (LDS-read volume halves: ~4GB -> ~2GB).
// ---------------------------------------------------------------------------
__global__ __launch_bounds__(256, 2) void flash_q128p(
    const bf16_t* __restrict__ qkv, const bf16_t* __restrict__ cosb,
    const bf16_t* __restrict__ sinb, const bf16_t* __restrict__ Kr,
    const bf16_t* __restrict__ Vt, bf16_t* __restrict__ Y) {
  constexpr int T = 2048;
  __shared__ __align__(1024) bf16_t Ks[64 * 128];  // swizzled linear tile
  __shared__ bf16_t Vs[128][72];
  const int tid = threadIdx.x;
  const int lane = tid & 63;
  const int fr = lane & 15;
  const int fg = lane >> 4;
  const int qt = blockIdx.x;  // 0..15, 128 q-rows each
  const int bh = blockIdx.y;
  const int b = bh >> 4, h = bh & 15;
  const int wave = tid >> 6;

  // Q rope'd on the fly; scale = rsqrt(128) * log2(e) folded in.
  const bf16_t* qbase = qkv + (size_t)b * T * 6144 + h * 128;
  bf16x8 qf[2][4];
#pragma unroll
  for (int i = 0; i < 2; ++i) {
    const int trow = qt * 128 + wave * 32 + i * 16 + fr;
    const bf16_t* qrow = qbase + (size_t)trow * 6144;
#pragma unroll
    for (int ks = 0; ks < 4; ++ks) {
      const int d = ks * 32 + fg * 8;
      const float sgn = (d < 64) ? -1.f : 1.f;
      const bf16x8 qv = *(const bf16x8*)(qrow + d);
      const bf16x8 qp = *(const bf16x8*)(qrow + (d ^ 64));
      const bf16x8 cv = *(const bf16x8*)(cosb + trow * 128 + d);
      const bf16x8 sv = *(const bf16x8*)(sinb + trow * 128 + d);
      bf16x8 o;
#pragma unroll
      for (int jj = 0; jj < 8; ++jj)
        o[jj] = (bf16_t)((((float)qv[jj]) * ((float)cv[jj]) +
                          sgn * ((float)qp[jj]) * ((float)sv[jj])) *
                         0.1275174825f);  // (1/sqrt(128)) * log2(e)
      qf[i][ks] = o;
    }
  }

  f32x4 acc[2][8] = {};
  float l_i[2] = {0.f, 0.f};

  const int krow = tid >> 4;                    // 0..15
  const int sc = (tid & 15) ^ (krow & 7);       // pre-swizzled source chunk
  const int vrow = tid >> 3;        // 0..31 (d rows, +32*it)
  const int vu = tid & 7;           // t-chunk index (8 consecutive t)
  const int vc0 = ((vu >> 2) * 32) + ((vu & 1) * 16) + (((vu >> 1) & 1) * 4);
  const bf16_t* Kh = Kr + (size_t)bh * T * 128;
  const bf16_t* Vh = Vt + (size_t)bh * 128 * T;

  auto stageK = [&](int t0) {
#pragma unroll
    for (int it = 0; it < 4; ++it)
      gll16(Kh + (size_t)(t0 + it * 16 + krow) * 128 + sc * 8,
            Ks + it * 2048 + tid * 8);
  };
  bf16x8 vreg[4];
  auto loadV = [&](int t0) {
#pragma unroll
    for (int it = 0; it < 4; ++it)
      vreg[it] = *(const bf16x8*)(Vh + (size_t)(it * 32 + vrow) * T + t0 + vu * 8);
  };
  auto writeV = [&]() {
#pragma unroll
    for (int it = 0; it < 4; ++it) {
      const int row = it * 32 + vrow;
      const bf16x8 v = vreg[it];
      bf16x4 lo, hi;
#pragma unroll
      for (int jj = 0; jj < 4; ++jj) {
        lo[jj] = v[jj];
        hi[jj] = v[4 + jj];
      }
      *(bf16x4*)(&Vs[row][vc0]) = lo;      // t = base+0..3  (b2=0)
      *(bf16x4*)(&Vs[row][vc0 + 8]) = hi;  // t = base+4..7  (b2=1)
    }
  };

  // prologue: stage tile 0
  stageK(0);
  loadV(0);
  asm volatile("s_waitcnt vmcnt(0)" ::: "memory");
  __builtin_amdgcn_sched_barrier(0);
  writeV();
  __syncthreads();

  const int cswz = (fr & 7) << 4;  // read-side XOR for Ks
  const char* kbase = (const char*)Ks;

  for (int j = 0; j < T / 64; ++j) {
    // QK^T swapped: lane holds P[q=fr][k=n*16+fg*4+r]; kf reused for i=0,1.
    f32x4 sacc[2][4] = {};
#pragma unroll
    for (int ks = 0; ks < 4; ++ks) {
#pragma unroll
      for (int n = 0; n < 4; ++n) {
        const bf16x8 kf = *(const bf16x8*)(kbase + (n * 16 + fr) * 256 +
                                           ((ks * 64 + fg * 16) ^ cswz));
        sacc[0][n] = MFMA16(kf, qf[0][ks], sacc[0][n]);
        sacc[1][n] = MFMA16(kf, qf[1][ks], sacc[1][n]);
      }
    }
    __syncthreads();  // Ks consumed by all waves

    const bool more = (j + 1 < T / 64);
    if (more) {
      stageK((j + 1) * 64);  // DMA into Ks (dead) while exp+PV run
      loadV((j + 1) * 64);
    }

    // exp + in-register pack into PV A-fragments.
    bf16x8 paf[2][2];
#pragma unroll
    for (int i = 0; i < 2; ++i) {
      float lsum = 0.f;
#pragma unroll
      for (int ks2 = 0; ks2 < 2; ++ks2) {
#pragma unroll
        for (int jj = 0; jj < 8; ++jj) {
          const float p = exp2f(sacc[i][ks2 * 2 + (jj >> 2)][jj & 3]);
          lsum += p;
          paf[i][ks2][jj] = (bf16_t)p;
        }
      }
      l_i[i] += lsum;
    }

    // PV: vf reused for i=0,1; Vs column order matches paf's k order.
#pragma unroll
    for (int ks2 = 0; ks2 < 2; ++ks2) {
#pragma unroll
      for (int n = 0; n < 8; ++n) {
        const bf16x8 vf = *(const bf16x8*)(&Vs[n * 16 + fr][ks2 * 32 + fg * 8]);
        acc[0][n] = MFMA16(paf[0][ks2], vf, acc[0][n]);
        acc[1][n] = MFMA16(paf[1][ks2], vf, acc[1][n]);
      }
    }

    asm volatile("s_waitcnt vmcnt(0)" ::: "memory");  // K DMA + V regs landed
    __builtin_amdgcn_sched_barrier(0);
    __syncthreads();  // Vs consumed by all; Ks(j+1) visible
    if (more) {
      writeV();
      __syncthreads();  // Vs(j+1) ready
    }
  }

  // epilogue: l reduce across fg groups, then fetch 1/l per output row.
#pragma unroll
  for (int i = 0; i < 2; ++i) {
    float l = l_i[i];
    l += __shfl_xor(l, 16, 64);
    l += __shfl_xor(l, 32, 64);  // lanes with same fr now hold l_full(q=fr)
#pragma unroll
    for (int r = 0; r < 4; ++r) {
      const float inv = 1.0f / __shfl(l, fg * 4 + r, 64);
      const int t = qt * 128 + wave * 32 + i * 16 + fg * 4 + r;
      bf16_t* yrow = Y + (size_t)(b * T + t) * 2048 + h * 128;
#pragma unroll
      for (int n = 0; n < 8; ++n)
        yrow[n * 16 + fr] = (bf16_t)(acc[i][n][r] * inv);
    }
  }
}

// ---------------------------------------------------------------------------
// Flash fallback (ws-lean): fused rope, exp-only softmax. (unchanged)
// ---------------------------------------------------------------------------
__global__ __launch_bounds__(256) void flash_fused_v2(
    const bf16_t* __restrict__ qkv, const bf16_t* __restrict__ cosb,
    const bf16_t* __restrict__ sinb, bf16_t* __restrict__ Y) {
  constexpr int T = 2048;
  __shared__ bf16_t Ks[64][136];
  __shared__ bf16_t Vs[128][72];
  __shared__ bf16_t Ps[128][72];
  const int tid = threadIdx.x;
  const int lane = tid & 63;
  const int wave = tid >> 6;
  const int fr = lane & 15;
  const int fg = lane >> 4;
  const int qt = blockIdx.x;
  const int bh = blockIdx.y;
  const int b = bh >> 4, h = bh & 15;

  const bf16_t* qbase = qkv + (size_t)b * T * 6144 + h * 128;
  bf16x8 qf[2][4];
#pragma unroll
  for (int i = 0; i < 2; ++i) {
    const int trow = qt * 128 + wave * 32 + i * 16 + fr;
    const bf16_t* qrow = qbase + (size_t)trow * 6144;
#pragma unroll
    for (int ks = 0; ks < 4; ++ks) {
      const int d = ks * 32 + fg * 8;
      const float sgn = (d < 64) ? -1.f : 1.f;
      const bf16x8 qv = *(const bf16x8*)(qrow + d);
      const bf16x8 qp = *(const bf16x8*)(qrow + (d ^ 64));
      const bf16x8 cv = *(const bf16x8*)(cosb + trow * 128 + d);
      const bf16x8 sv = *(const bf16x8*)(sinb + trow * 128 + d);
      bf16x8 o;
#pragma unroll
      for (int jj = 0; jj < 8; ++jj)
        o[jj] = (bf16_t)((((float)qv[jj]) * ((float)cv[jj]) +
                          sgn * ((float)qp[jj]) * ((float)sv[jj])) *
                         0.08838834764831845f);
      qf[i][ks] = o;
    }
  }

  f32x4 acc[2][8] = {};
  float l_i[2][4] = {};

  const int kr = tid >> 4;
  const int kc = (tid & 15) * 8;
  const float sgnk = (kc < 64) ? -1.f : 1.f;
  const int tp = tid & 63;

  for (int j = 0; j < T / 64; ++j) {
    const int t0 = j * 64;
#pragma unroll
    for (int it = 0; it < 4; ++it) {
      const int row = it * 16 + kr;
      const int tg = t0 + row;
      const bf16_t* krow = qkv + ((size_t)(b * T + tg)) * 6144 + 2048 + h * 128;
      const bf16x8 kv = *(const bf16x8*)(krow + kc);
      const bf16x8 kp = *(const bf16x8*)(krow + (kc ^ 64));
      const bf16x8 cv = *(const bf16x8*)(cosb + tg * 128 + kc);
      const bf16x8 sv = *(const bf16x8*)(sinb + tg * 128 + kc);
      bf16x8 o;
#pragma unroll
      for (int jj = 0; jj < 8; ++jj)
        o[jj] = (bf16_t)(((float)kv[jj]) * ((float)cv[jj]) +
                         sgnk * ((float)kp[jj]) * ((float)sv[jj]));
      *(bf16x8*)(&Ks[row][kc]) = o;
    }
#pragma unroll
    for (int cc = 0; cc < 4; ++cc) {
      const int d8 = (cc * 4 + (tid >> 6)) * 8;
      const bf16x8 vv = *(const bf16x8*)(qkv + ((size_t)(b * T + t0 + tp)) * 6144 +
                                         4096 + h * 128 + d8);
#pragma unroll
      for (int jj = 0; jj < 8; ++jj) Vs[d8 + jj][tp] = vv[jj];
    }
    __syncthreads();

    f32x4 sacc[2][4] = {};
#pragma unroll
    for (int ks = 0; ks < 4; ++ks) {
#pragma unroll
      for (int n = 0; n < 4; ++n) {
        const bf16x8 kf = *(const bf16x8*)(&Ks[n * 16 + fr][ks * 32 + fg * 8]);
        sacc[0][n] = MFMA16(qf[0][ks], kf, sacc[0][n]);
        sacc[1][n] = MFMA16(qf[1][ks], kf, sacc[1][n]);
      }
    }

#pragma unroll
    for (int i = 0; i < 2; ++i) {
#pragma unroll
      for (int r = 0; r < 4; ++r) {
        const float p0 = __expf(sacc[i][0][r]);
        const float p1 = __expf(sacc[i][1][r]);
        const float p2 = __expf(sacc[i][2][r]);
        const float p3 = __expf(sacc[i][3][r]);
        l_i[i][r] += (p0 + p1) + (p2 + p3);
        const int prow = wave * 32 + i * 16 + fg * 4 + r;
        Ps[prow][0 + fr] = (bf16_t)p0;
        Ps[prow][16 + fr] = (bf16_t)p1;
        Ps[prow][32 + fr] = (bf16_t)p2;
        Ps[prow][48 + fr] = (bf16_t)p3;
      }
    }

#pragma unroll
    for (int ks = 0; ks < 2; ++ks) {
      const bf16x8 pf0 = *(const bf16x8*)(&Ps[wave * 32 + fr][ks * 32 + fg * 8]);
      const bf16x8 pf1 = *(const bf16x8*)(&Ps[wave * 32 + 16 + fr][ks * 32 + fg * 8]);
#pragma unroll
      for (int n = 0; n < 8; ++n) {
        const bf16x8 vf = *(const bf16x8*)(&Vs[n * 16 + fr][ks * 32 + fg * 8]);
        acc[0][n] = MFMA16(pf0, vf, acc[0][n]);
        acc[1][n] = MFMA16(pf1, vf, acc[1][n]);
      }
    }
    __syncthreads();
  }

#pragma unroll
  for (int i = 0; i < 2; ++i) {
#pragma unroll
    for (int r = 0; r < 4; ++r) {
      float l = l_i[i][r];
#pragma unroll
      for (int msk = 1; msk < 16; msk <<= 1) l += __shfl_xor(l, msk, 64);
      const float inv = 1.0f / l;
      const int t = qt * 128 + wave * 32 + i * 16 + fg * 4 + r;
      bf16_t* yrow = Y + (size_t)(b * T + t) * 2048 + h * 128;
#pragma unroll
      for (int n = 0; n < 8; ++n)
        yrow[n * 16 + fr] = (bf16_t)(acc[i][n][r] * inv);
    }
  }
}

// ---------------------------------------------------------------------------
extern "C" void kernel_launch(void* const* d_in, const int* in_sizes, int n_in,
                              void* d_out, int out_size, void* d_ws, size_t ws_size,
                              hipStream_t stream) {
  const float* x = (const float*)d_in[0];
  const float* cosi = (const float*)d_in[1];
  const float* sini = (const float*)d_in[2];
  const float* Wqkv = (const float*)d_in[3];
  const float* Wproj = (const float*)d_in[4];

  const size_t NEED_FAST = sizeof(bf16_t) *
      ((size_t)12582912 + 262144 + 262144 + 25165824 + 8388608 + 8388608);
  const size_t NEED_BASE = 256 + sizeof(bf16_t) *
      ((size_t)12582912 + 4194304 + 262144 + 262144 + 25165824);

  if (ws_size >= NEED_FAST) {
    bf16_t* base = (bf16_t*)d_ws;
    bf16_t* WqkvT = base;                    // dead after gemm1
    bf16_t* y = base;                        // alias
    bf16_t* cosb = base + 12582912;
    bf16_t* sinb = cosb + 262144;
    bf16_t* qkv = sinb + 262144;             // live through flash
    bf16_t* WprojT = qkv;                    // alias head, written after flash
    bf16_t* Kr = qkv + 25165824;
    bf16_t* xb = Kr;                         // alias: x-bf16, dead before rope_k
    bf16_t* Vt = Kr + 8388608;

    conv_vec_f32<<<128, 256, 0, stream>>>(cosi, cosb, 32768);
    conv_vec_f32<<<128, 256, 0, stream>>>(sini, sinb, 32768);
    conv_vec_f32<<<4096, 256, 0, stream>>>(x, xb, 1048576);  // x -> bf16
    conv_transpose_f32<<<dim3(96, 32), 256, 0, stream>>>(Wqkv, WqkvT, 2048, 6144);
    gemm8<false><<<384, 512, 0, stream>>>(xb, WqkvT, qkv, 4096, 6144, 2048, 24);
    rope_k<<<4096, 256, 0, stream>>>(qkv, cosb, sinb, Kr);  // overwrites xb (dead)
    transpose_v<<<dim3(32, 2, 32), 256, 0, stream>>>(qkv, Vt);
    flash_q128p<<<dim3(16, 32), 256, 0, stream>>>(qkv, cosb, sinb, Kr, Vt, y);
    conv_transpose_f32<<<dim3(32, 32), 256, 0, stream>>>(Wproj, WprojT, 2048, 2048);
    gemm8n<true><<<256, 512, 0, stream>>>(y, WprojT, d_out, 4096, 2048, 2048, 8);
  } else if (ws_size >= NEED_BASE) {
    bf16_t* base = (bf16_t*)((char*)d_ws + 256);
    bf16_t* WqkvT = base;
    bf16_t* y = base;
    bf16_t* WprojT = base + 12582912;
    bf16_t* cosb = WprojT + 4194304;
    bf16_t* sinb = cosb + 262144;
    bf16_t* qkv = sinb + 262144;

    conv_vec_f32<<<128, 256, 0, stream>>>(cosi, cosb, 32768);
    conv_vec_f32<<<128, 256, 0, stream>>>(sini, sinb, 32768);
    conv_transpose_f32<<<dim3(96, 32), 256, 0, stream>>>(Wqkv, WqkvT, 2048, 6144);
    gemm_t<true, false><<<dim3(32, 48), 256, 0, stream>>>(x, WqkvT, qkv, 4096, 6144, 2048);
    flash_fused_v2<<<dim3(16, 32), 256, 0, stream>>>(qkv, cosb, sinb, y);
    conv_transpose_f32<<<dim3(32, 32), 256, 0, stream>>>(Wproj, WprojT, 2048, 2048);
    gemm_t<false, true><<<dim3(32, 16), 256, 0, stream>>>(y, WprojT, d_out, 4096, 2048, 2048);
  } else {
    fill_diag<<<(out_size + 255) / 256, 256, 0, stream>>>((uint32_t*)d_out, out_size);
  }
}

// Round 9
// 394.945 us; speedup vs baseline: 1.7556x; 1.0467x over previous
//
#include <hip/hip_runtime.h>
#include <cstdint>
#include <cstddef>

typedef __bf16 bf16_t;
typedef __bf16 bf16x8 __attribute__((ext_vector_type(8)));
typedef __bf16 bf16x4 __attribute__((ext_vector_type(4)));
typedef float f32x4 __attribute__((ext_vector_type(4)));

#define MFMA16(a, b, c) __builtin_amdgcn_mfma_f32_16x16x32_bf16(a, b, c, 0, 0, 0)

// async global->LDS, 16B per lane. LDS dest = wave-uniform base + lane*16.
__device__ __forceinline__ void gll16(const bf16_t* g, bf16_t* l) {
  __builtin_amdgcn_global_load_lds(
      (__attribute__((address_space(1))) uint32_t*)((uintptr_t)g),
      (__attribute__((address_space(3))) uint32_t*)((uint32_t)(uintptr_t)l),
      16, 0, 0);
}

// Diagnostic: absmax ~1000 => ws_size too small.
__global__ void fill_diag(uint32_t* out, int n_u32) {
  int i = blockIdx.x * 256 + threadIdx.x;
  if (i < n_u32) out[i] = 0x447A0000u;  // f32 1000.0
}

// ---------------------------------------------------------------------------
// f32 -> bf16 vector convert (x, cos/sin tables). One bf16x8 per thread.
// ---------------------------------------------------------------------------
__global__ void conv_vec_f32(const float* __restrict__ in, bf16_t* __restrict__ out,
                             int n8) {
  const int i = blockIdx.x * 256 + threadIdx.x;
  if (i >= n8) return;
  const float* p = in + (size_t)i * 8;
  const f32x4 a = *(const f32x4*)p;
  const f32x4 b = *(const f32x4*)(p + 4);
  bf16x8 o;
#pragma unroll
  for (int j = 0; j < 4; ++j) {
    o[j] = (bf16_t)a[j];
    o[4 + j] = (bf16_t)b[j];
  }
  ((bf16x8*)out)[i] = o;
}

// ---------------------------------------------------------------------------
// 64x64 tiled transpose+convert: in R x C f32 -> out C x R bf16.
// ---------------------------------------------------------------------------
__global__ __launch_bounds__(256) void conv_transpose_f32(
    const float* __restrict__ in, bf16_t* __restrict__ out, int R, int C) {
  __shared__ bf16_t tile[64][72];
  const int bc = blockIdx.x * 64;
  const int br = blockIdx.y * 64;
  const int t = threadIdx.x;
  const int r = t >> 3;
  const int c8 = (t & 7) * 8;
#pragma unroll
  for (int ii = 0; ii < 2; ++ii) {
    const int rr = r + ii * 32;
    const float* p = in + (size_t)(br + rr) * C + bc + c8;
    const f32x4 a = *(const f32x4*)p;
    const f32x4 b = *(const f32x4*)(p + 4);
    bf16x8 v;
#pragma unroll
    for (int j = 0; j < 4; ++j) {
      v[j] = (bf16_t)a[j];
      v[4 + j] = (bf16_t)b[j];
    }
    *(bf16x8*)(&tile[rr][c8]) = v;
  }
  __syncthreads();
#pragma unroll
  for (int ii = 0; ii < 2; ++ii) {
    const int rr = r + ii * 32;
    bf16x8 o;
#pragma unroll
    for (int jj = 0; jj < 8; ++jj) o[jj] = tile[c8 + jj][rr];
    *(bf16x8*)(out + (size_t)(bc + rr) * R + br + c8) = o;
  }
}

// ---------------------------------------------------------------------------
// gemm8k: 256x192-tile 2-phase GEMM (round-9, qkv shape).
//   Grid = (M/256)*(N/192): qkv 16x32 = 512 blocks = EXACTLY 2 CU rounds
//   (fixes gemm8's 384-block 75% fill) while keeping BM=256 (round-7 showed
//   shrinking M blows up B re-read traffic; shrinking N keeps intensity).
//   512 thr, 8 waves (2M x 4N), per-wave 128x48 (8 m-frags x 3 n-frags).
//   LDS 112KB: A = 4 half-slots x 16KB (128 rows x 64, slot (2t+h)&3, same
//   as proven gemm8); B = 6 third-slots x 8KB (64 rows x 64, slot (3t+g)%6).
//   Slot liveness (paper-checked): B(t) read only in ph1 -> B(t+2) staged in
//   ph2(t) (same slot, 1 barrier after last reader). A(t) last read ph2 ->
//   A(t+1,h0) in ph1(t) (distinct slot), A(t+1,h1) in ph2(t) (distinct slot).
//   vmcnt(3) at ph2 end leaves only B(t+2)'s 3 loads in flight; tail drains 0.
//   Staging uses rule-#21 involution (source chunk ^= row&7, read col-XOR).
// ---------------------------------------------------------------------------
template <bool C32>
__global__ __launch_bounds__(512, 2) void gemm8k(
    const bf16_t* __restrict__ A, const bf16_t* __restrict__ Bt,
    void* __restrict__ C, int M, int N, int K, int nbn) {
  __shared__ __align__(1024) bf16_t lds8[57344];  // A: 4x8192 el, B: 6x4096 el
  bf16_t* As = lds8;            // 4 half-slots
  bf16_t* Bs = lds8 + 32768;    // 6 third-slots

  const int tid = threadIdx.x;
  const int lane = tid & 63;
  const int wave = tid >> 6;
  const int wr = wave >> 2;  // 0..1 (M half: 128 rows)
  const int wc = wave & 3;   // 0..3 (N: 48 cols)
  const int fr = lane & 15;
  const int fg = lane >> 4;

  // XCD-aware bijective swizzle (nwg % 8 == 0 by construction).
  const int nwg = gridDim.x;
  const int bid = blockIdx.x;
  const int swz = (bid & 7) * (nwg >> 3) + (bid >> 3);
  const int m0 = (swz / nbn) * 256;
  const int n0 = (swz % nbn) * 192;

  const int NT = K >> 6;  // BK=64 tiles (K=2048 -> 32)

  // A staging (identical geometry to gemm8): wave covers segs {2w,2w+1}.
  const int sseg0 = wave * 2;
  const int srow = lane >> 3;
  const int sj = lane & 7;
  auto stageA = [&](int kt, int h) {
#pragma unroll
    for (int l = 0; l < 2; ++l) {
      const int seg = sseg0 + l;
      const int r = seg * 8 + srow;      // row in half 0..127
      const int j = sj ^ (r & 7);        // inverse-swizzled source chunk
      gll16(A + (size_t)(m0 + h * 128 + r) * K + kt * 64 + j * 8,
            As + ((2 * kt + h) & 3) * 8192 + seg * 512 + lane * 8);
    }
  };
  // B staging: one 64-row third (8KB) = 1 gll16/thread.
  const int srow3 = tid >> 3;           // 0..63
  const int sj3 = tid & 7;
  auto stageB = [&](int kt, int g) {
    const int j = sj3 ^ (srow3 & 7);
    gll16(Bt + (size_t)(n0 + g * 64 + srow3) * K + kt * 64 + j * 8,
          Bs + ((3 * kt + g) % 6) * 4096 + tid * 8);
  };

  const int cb0 = (fg * 16) ^ ((fr & 7) << 4);  // swizzled k-half-0 byte col

  auto lda = [&](bf16x8(&af)[4][2], int t, int mlo) {
    const char* base = (const char*)(As + ((2 * t + wr) & 3) * 8192);
#pragma unroll
    for (int m = 0; m < 4; ++m) {
      const char* p = base + ((mlo + m) * 16 + fr) * 128;
      af[m][0] = *(const bf16x8*)(p + cb0);
      af[m][1] = *(const bf16x8*)(p + (cb0 ^ 64));
    }
  };
  auto ldb = [&](bf16x8(&bf)[3][2], int t) {
#pragma unroll
    for (int n = 0; n < 3; ++n) {
      const int c = wc * 48 + n * 16;   // col in 192-tile
      const int g = c >> 6;
      const int r = c & 63;
      const char* p = (const char*)(Bs + ((3 * t + g) % 6) * 4096) +
                      (r + fr) * 128;
      bf[n][0] = *(const bf16x8*)(p + cb0);
      bf[n][1] = *(const bf16x8*)(p + (cb0 ^ 64));
    }
  };

  f32x4 acc[8][3] = {};

  // Prologue: A(0) both halves, B(0) 3 thirds, B(1) 3 thirds.
  stageA(0, 0);
  stageA(0, 1);
  stageB(0, 0);
  stageB(0, 1);
  stageB(0, 2);
  stageB(1, 0);
  stageB(1, 1);
  stageB(1, 2);
  asm volatile("s_waitcnt vmcnt(3)" ::: "memory");  // A(0)+B(0) landed
  __builtin_amdgcn_s_barrier();

  bf16x8 af[4][2], bf[3][2];

  for (int t = 0; t < NT; ++t) {
    // ---- ph1: af m0-3 (8) + bf all (6); stage A(t+1,h0); MFMA m0-3 ----
    lda(af, t, 0);
    ldb(bf, t);
    if (t + 1 < NT) stageA(t + 1, 0);
    asm volatile("s_waitcnt lgkmcnt(8)" ::: "memory");
    __builtin_amdgcn_s_barrier();
    asm volatile("s_waitcnt lgkmcnt(0)" ::: "memory");
    __builtin_amdgcn_sched_barrier(0);
    __builtin_amdgcn_s_setprio(1);
#pragma unroll
    for (int k = 0; k < 2; ++k)
#pragma unroll
      for (int m = 0; m < 4; ++m)
#pragma unroll
        for (int n = 0; n < 3; ++n)
          acc[m][n] = MFMA16(af[m][k], bf[n][k], acc[m][n]);
    __builtin_amdgcn_s_setprio(0);
    __builtin_amdgcn_s_barrier();
    // ---- ph2: af m4-7 (8); stage A(t+1,h1), B(t+2,g0..2); MFMA m4-7 ----
    lda(af, t, 4);
    if (t + 1 < NT) stageA(t + 1, 1);
    if (t + 2 < NT) {
      stageB(t + 2, 0);
      stageB(t + 2, 1);
      stageB(t + 2, 2);
    }
    __builtin_amdgcn_s_barrier();
    asm volatile("s_waitcnt lgkmcnt(0)" ::: "memory");
    __builtin_amdgcn_sched_barrier(0);
    __builtin_amdgcn_s_setprio(1);
#pragma unroll
    for (int k = 0; k < 2; ++k)
#pragma unroll
      for (int m = 0; m < 4; ++m)
#pragma unroll
        for (int n = 0; n < 3; ++n)
          acc[m + 4][n] = MFMA16(af[m][k], bf[n][k], acc[m + 4][n]);
    __builtin_amdgcn_s_setprio(0);
    if (t + 2 < NT) {
      asm volatile("s_waitcnt vmcnt(3)" ::: "memory");  // keep B(t+2) in flight
    } else {
      asm volatile("s_waitcnt vmcnt(0)" ::: "memory");  // tail drain
    }
    __builtin_amdgcn_s_barrier();
  }

#pragma unroll
  for (int m = 0; m < 8; ++m) {
#pragma unroll
    for (int n = 0; n < 3; ++n) {
#pragma unroll
      for (int r = 0; r < 4; ++r) {
        const int row = m0 + wr * 128 + m * 16 + fg * 4 + r;
        const int col = n0 + wc * 48 + n * 16 + fr;
        const size_t idx = (size_t)row * N + col;
        if (C32)
          ((float*)C)[idx] = acc[m][n][r];
        else
          ((bf16_t*)C)[idx] = (bf16_t)acc[m][n][r];
      }
    }
  }
  (void)M;
}

// ---------------------------------------------------------------------------
// gemm8n: 128x256-tile 2-phase GEMM — kept for the proj GEMM (grid 256
// = exactly 1 CU round; N=2048 not divisible by 192).
// ---------------------------------------------------------------------------
template <bool C32>
__global__ __launch_bounds__(512, 2) void gemm8n(
    const bf16_t* __restrict__ A, const bf16_t* __restrict__ Bt,
    void* __restrict__ C, int M, int N, int K, int nbn) {
  __shared__ __align__(1024) bf16_t lds8[65536];  // A: 3x8192, B: 5x8192 (bf16)
  bf16_t* As = lds8;           // 3 slots * 8192 el
  bf16_t* Bs = lds8 + 24576;   // 5 slots * 8192 el

  const int tid = threadIdx.x;
  const int lane = tid & 63;
  const int wave = tid >> 6;
  const int wr = wave >> 2;
  const int wc = wave & 3;
  const int fr = lane & 15;
  const int fg = lane >> 4;

  const int nwg = gridDim.x;
  const int bid = blockIdx.x;
  const int swz = (bid & 7) * (nwg >> 3) + (bid >> 3);
  const int m0 = (swz / nbn) * 128;
  const int n0 = (swz % nbn) * 256;

  const int NT = K >> 6;

  const int srow = tid >> 3;  // 0..63
  const int sj = tid & 7;

  auto stage = [&](const bf16_t* __restrict__ G, int grow0, bf16_t* slotBase,
                   int kt) {
#pragma unroll
    for (int l = 0; l < 2; ++l) {
      const int r = l * 64 + srow;
      const int j = sj ^ (r & 7);
      gll16(G + (size_t)(grow0 + r) * K + kt * 64 + j * 8,
            slotBase + l * 4096 + tid * 8);
    }
  };

  const int cb0 = (fg * 16) ^ ((fr & 7) << 4);

  auto lda = [&](bf16x8(&af)[4][2], int t) {
    const char* base = (const char*)(As + (t % 3) * 8192);
#pragma unroll
    for (int m = 0; m < 4; ++m) {
      const char* p = base + (wr * 64 + m * 16 + fr) * 128;
      af[m][0] = *(const bf16x8*)(p + cb0);
      af[m][1] = *(const bf16x8*)(p + (cb0 ^ 64));
    }
  };
  auto ldb2 = [&](bf16x8(&bf)[2][2], int t, int nlo) {
    const char* base = (const char*)(Bs + ((2 * t + (wc >> 1)) % 5) * 8192);
#pragma unroll
    for (int n = 0; n < 2; ++n) {
      const char* p = base + ((wc & 1) * 64 + (nlo + n) * 16 + fr) * 128;
      bf[n][0] = *(const bf16x8*)(p + cb0);
      bf[n][1] = *(const bf16x8*)(p + (cb0 ^ 64));
    }
  };

  f32x4 acc[4][4] = {};

  stage(A, m0, As, 0);
  stage(A, m0, As + 8192, 1);
  stage(Bt, n0, Bs, 0);
  stage(Bt, n0 + 128, Bs + 8192, 0);
  stage(Bt, n0, Bs + 2 * 8192, 1);
  asm volatile("s_waitcnt vmcnt(2)" ::: "memory");
  __builtin_amdgcn_s_barrier();

  bf16x8 af[4][2], bf01[2][2], bf23[2][2];

  for (int t = 0; t < NT; ++t) {
    lda(af, t);
    ldb2(bf01, t, 0);
    if (t + 2 < NT) stage(Bt, n0, Bs + ((2 * t + 4) % 5) * 8192, t + 2);
    if (t + 1 < NT) stage(Bt, n0 + 128, Bs + ((2 * t + 3) % 5) * 8192, t + 1);
    asm volatile("s_waitcnt lgkmcnt(8)" ::: "memory");
    __builtin_amdgcn_s_barrier();
    asm volatile("s_waitcnt lgkmcnt(0)" ::: "memory");
    __builtin_amdgcn_sched_barrier(0);
    __builtin_amdgcn_s_setprio(1);
#pragma unroll
    for (int k = 0; k < 2; ++k)
#pragma unroll
      for (int m = 0; m < 4; ++m)
#pragma unroll
        for (int n = 0; n < 2; ++n)
          acc[m][n] = MFMA16(af[m][k], bf01[n][k], acc[m][n]);
    __builtin_amdgcn_s_setprio(0);
    __builtin_amdgcn_s_barrier();
    ldb2(bf23, t, 2);
    if (t + 2 < NT) stage(A, m0, As + ((t + 2) % 3) * 8192, t + 2);
    __builtin_amdgcn_s_barrier();
    asm volatile("s_waitcnt lgkmcnt(0)" ::: "memory");
    __builtin_amdgcn_sched_barrier(0);
    __builtin_amdgcn_s_setprio(1);
#pragma unroll
    for (int k = 0; k < 2; ++k)
#pragma unroll
      for (int m = 0; m < 4; ++m)
#pragma unroll
        for (int n = 0; n < 2; ++n)
          acc[m][n + 2] = MFMA16(af[m][k], bf23[n][k], acc[m][n + 2]);
    __builtin_amdgcn_s_setprio(0);
    if (t + 3 < NT) {
      asm volatile("s_waitcnt vmcnt(2)" ::: "memory");
    } else {
      asm volatile("s_waitcnt vmcnt(0)" ::: "memory");
    }
    __builtin_amdgcn_s_barrier();
  }

#pragma unroll
  for (int m = 0; m < 4; ++m) {
#pragma unroll
    for (int n = 0; n < 4; ++n) {
#pragma unroll
      for (int r = 0; r < 4; ++r) {
        const int row = m0 + wr * 64 + m * 16 + fg * 4 + r;
        const int col = n0 + wc * 64 + n * 16 + fr;
        const size_t idx = (size_t)row * N + col;
        if (C32)
          ((float*)C)[idx] = acc[m][n][r];
        else
          ((bf16_t*)C)[idx] = (bf16_t)acc[m][n][r];
      }
    }
  }
  (void)M;
}

// ---------------------------------------------------------------------------
// Register-staged GEMM (fallback path only): A f32 option, C f32 option.
// ---------------------------------------------------------------------------
template <bool A32, bool C32>
__global__ __launch_bounds__(256) void gemm_t(
    const void* __restrict__ A, const bf16_t* __restrict__ Bt,
    void* __restrict__ C, int M, int N, int K) {
  __shared__ bf16_t As[128 * 32];
  __shared__ bf16_t Bs[128 * 32];
  const int tid = threadIdx.x;
  const int lane = tid & 63;
  const int wave = tid >> 6;
  const int m0 = blockIdx.x * 128;
  const int n0 = blockIdx.y * 128;
  const int wm = (wave & 1) * 64;
  const int wn = (wave >> 1) * 64;
  const int fr = lane & 15;
  const int fk = (lane >> 4) * 8;

  f32x4 acc[4][4] = {};

  const size_t ea0 = (size_t)(m0 + (tid >> 2)) * K + (tid & 3) * 8;
  const bf16_t* gb = Bt + (size_t)(n0 + (tid >> 2)) * K + (tid & 3) * 8;
  bf16_t* lA = As + tid * 8;
  bf16_t* lB = Bs + tid * 8;
  const size_t half = (size_t)64 * K;

  for (int k0 = 0; k0 < K; k0 += 32) {
    bf16x8 ra0, ra1;
    if (A32) {
      const float* pa = (const float*)A + ea0 + k0;
      const f32x4 x0 = *(const f32x4*)pa;
      const f32x4 x1 = *(const f32x4*)(pa + 4);
      const f32x4 x2 = *(const f32x4*)(pa + half);
      const f32x4 x3 = *(const f32x4*)(pa + half + 4);
#pragma unroll
      for (int j = 0; j < 4; ++j) {
        ra0[j] = (bf16_t)x0[j];
        ra0[4 + j] = (bf16_t)x1[j];
        ra1[j] = (bf16_t)x2[j];
        ra1[4 + j] = (bf16_t)x3[j];
      }
    } else {
      const bf16_t* pa = (const bf16_t*)A + ea0 + k0;
      ra0 = *(const bf16x8*)pa;
      ra1 = *(const bf16x8*)(pa + half);
    }
    const bf16x8 rb0 = *(const bf16x8*)gb;
    const bf16x8 rb1 = *(const bf16x8*)(gb + half);
    gb += 32;
    __syncthreads();
    *(bf16x8*)lA = ra0;
    *(bf16x8*)(lA + 2048) = ra1;
    *(bf16x8*)lB = rb0;
    *(bf16x8*)(lB + 2048) = rb1;
    __syncthreads();
    bf16x8 af[4], bfr[4];
#pragma unroll
    for (int i = 0; i < 4; ++i)
      af[i] = *(const bf16x8*)(As + (wm + i * 16 + fr) * 32 + fk);
#pragma unroll
    for (int j = 0; j < 4; ++j)
      bfr[j] = *(const bf16x8*)(Bs + (wn + j * 16 + fr) * 32 + fk);
#pragma unroll
    for (int i = 0; i < 4; ++i)
#pragma unroll
      for (int j = 0; j < 4; ++j)
        acc[i][j] = MFMA16(af[i], bfr[j], acc[i][j]);
  }

  const int fg = lane >> 4;
#pragma unroll
  for (int i = 0; i < 4; ++i) {
#pragma unroll
    for (int j = 0; j < 4; ++j) {
#pragma unroll
      for (int r = 0; r < 4; ++r) {
        const int row = m0 + wm + i * 16 + fg * 4 + r;
        const int col = n0 + wn + j * 16 + fr;
        const size_t idx = (size_t)row * N + col;
        if (C32)
          ((float*)C)[idx] = acc[i][j][r];
        else
          ((bf16_t*)C)[idx] = (bf16_t)acc[i][j][r];
      }
    }
  }
}

// ---------------------------------------------------------------------------
// K rope extract: qkv (B*T,6144) -> Kr (B,H,T,D) bf16 rope'd.
// ---------------------------------------------------------------------------
__global__ __launch_bounds__(256) void rope_k(
    const bf16_t* __restrict__ qkv, const bf16_t* __restrict__ cosb,
    const bf16_t* __restrict__ sinb, bf16_t* __restrict__ Kr) {
  const int row = blockIdx.x;  // b*2048 + t
  const int t = row & 2047;
  const int b = row >> 11;
  const int idx = threadIdx.x * 8;
  const int h = idx >> 7;
  const int d = idx & 127;
  const float sgn = (d < 64) ? -1.f : 1.f;
  const bf16_t* base = qkv + (size_t)row * 6144 + 2048;
  const bf16x8 kv = *(const bf16x8*)(base + idx);
  const bf16x8 kp = *(const bf16x8*)(base + (idx ^ 64));
  const bf16x8 cv = *(const bf16x8*)(cosb + t * 128 + d);
  const bf16x8 sv = *(const bf16x8*)(sinb + t * 128 + d);
  bf16x8 o;
#pragma unroll
  for (int jj = 0; jj < 8; ++jj)
    o[jj] = (bf16_t)(((float)kv[jj]) * ((float)cv[jj]) +
                     sgn * ((float)kp[jj]) * ((float)sv[jj]));
  *(bf16x8*)(Kr + ((size_t)(b * 16 + h) * 2048 + t) * 128 + d) = o;
}

// ---------------------------------------------------------------------------
// V extract + transpose: qkv cols 4096.. -> Vt (B,H,D,T).
// ---------------------------------------------------------------------------
__global__ __launch_bounds__(256) void transpose_v(
    const bf16_t* __restrict__ qkv, bf16_t* __restrict__ Vt) {
  __shared__ bf16_t tile[64][72];
  const int bh = blockIdx.z;
  const int b = bh >> 4, h = bh & 15;
  const int t0 = blockIdx.x * 64;
  const int d0 = blockIdx.y * 64;
  const int t = threadIdx.x;
  const int r = t >> 3;
  const int c8 = (t & 7) * 8;
#pragma unroll
  for (int ii = 0; ii < 2; ++ii) {
    const int rr = r + ii * 32;
    *(bf16x8*)(&tile[rr][c8]) =
        *(const bf16x8*)(qkv + (size_t)(b * 2048 + t0 + rr) * 6144 + 4096 + h * 128 + d0 + c8);
  }
  __syncthreads();
#pragma unroll
  for (int ii = 0; ii < 2; ++ii) {
    const int rr = r + ii * 32;
    bf16x8 o;
#pragma unroll
    for (int jj = 0; jj < 8; ++jj) o[jj] = tile[c8 + jj][rr];
    *(bf16x8*)(Vt + ((size_t)bh * 128 + d0 + rr) * 2048 + t0 + c8) = o;
  }
}

// ---------------------------------------------------------------------------
// Flash (round-8 structure, unchanged): QBLK=128 (q-per-wave=32), swapped
// QK^T via global_load_lds K staging with rule-#21 involution, in-register P,
// π-permuted Vs, T14 prefetch pipeline, ks-outer MFMA, exp2 softmax.
// ---------------------------------------------------------------------------
__global__ __launch_bounds__(256, 2) void flash_q128p(
    const bf16_t* __restrict__ qkv, const bf16_t* __restrict__ cosb,
    const bf16_t* __restrict__ sinb, const bf16_t* __restrict__ Kr,
    const bf16_t* __restrict__ Vt, bf16_t* __restrict__ Y) {
  constexpr int T = 2048;
  __shared__ __align__(1024) bf16_t Ks[64 * 128];  // swizzled linear tile
  __shared__ bf16_t Vs[128][72];
  const int tid = threadIdx.x;
  const int lane = tid & 63;
  const int fr = lane & 15;
  const int fg = lane >> 4;
  const int qt = blockIdx.x;  // 0..15, 128 q-rows each
  const int bh = blockIdx.y;
  const int b = bh >> 4, h = bh & 15;
  const int wave = tid >> 6;

  // Q rope'd on the fly; scale = rsqrt(128) * log2(e) folded in.
  const bf16_t* qbase = qkv + (size_t)b * T * 6144 + h * 128;
  bf16x8 qf[2][4];
#pragma unroll
  for (int i = 0; i < 2; ++i) {
    const int trow = qt * 128 + wave * 32 + i * 16 + fr;
    const bf16_t* qrow = qbase + (size_t)trow * 6144;
#pragma unroll
    for (int ks = 0; ks < 4; ++ks) {
      const int d = ks * 32 + fg * 8;
      const float sgn = (d < 64) ? -1.f : 1.f;
      const bf16x8 qv = *(const bf16x8*)(qrow + d);
      const bf16x8 qp = *(const bf16x8*)(qrow + (d ^ 64));
      const bf16x8 cv = *(const bf16x8*)(cosb + trow * 128 + d);
      const bf16x8 sv = *(const bf16x8*)(sinb + trow * 128 + d);
      bf16x8 o;
#pragma unroll
      for (int jj = 0; jj < 8; ++jj)
        o[jj] = (bf16_t)((((float)qv[jj]) * ((float)cv[jj]) +
                          sgn * ((float)qp[jj]) * ((float)sv[jj])) *
                         0.1275174825f);  // (1/sqrt(128)) * log2(e)
      qf[i][ks] = o;
    }
  }

  f32x4 acc[2][8] = {};
  float l_i[2] = {0.f, 0.f};

  const int krow = tid >> 4;                    // 0..15
  const int sc = (tid & 15) ^ (krow & 7);       // pre-swizzled source chunk
  const int vrow = tid >> 3;        // 0..31 (d rows, +32*it)
  const int vu = tid & 7;           // t-chunk index (8 consecutive t)
  const int vc0 = ((vu >> 2) * 32) + ((vu & 1) * 16) + (((vu >> 1) & 1) * 4);
  const bf16_t* Kh = Kr + (size_t)bh * T * 128;
  const bf16_t* Vh = Vt + (size_t)bh * 128 * T;

  auto stageK = [&](int t0) {
#pragma unroll
    for (int it = 0; it < 4; ++it)
      gll16(Kh + (size_t)(t0 + it * 16 + krow) * 128 + sc * 8,
            Ks + it * 2048 + tid * 8);
  };
  bf16x8 vreg[4];
  auto loadV = [&](int t0) {
#pragma unroll
    for (int it = 0; it < 4; ++it)
      vreg[it] = *(const bf16x8*)(Vh + (size_t)(it * 32 + vrow) * T + t0 + vu * 8);
  };
  auto writeV = [&]() {
#pragma unroll
    for (int it = 0; it < 4; ++it) {
      const int row = it * 32 + vrow;
      const bf16x8 v = vreg[it];
      bf16x4 lo, hi;
#pragma unroll
      for (int jj = 0; jj < 4; ++jj) {
        lo[jj] = v[jj];
        hi[jj] = v[4 + jj];
      }
      *(bf16x4*)(&Vs[row][vc0]) = lo;      // t = base+0..3  (b2=0)
      *(bf16x4*)(&Vs[row][vc0 + 8]) = hi;  // t = base+4..7  (b2=1)
    }
  };

  // prologue: stage tile 0
  stageK(0);
  loadV(0);
  asm volatile("s_waitcnt vmcnt(0)" ::: "memory");
  __builtin_amdgcn_sched_barrier(0);
  writeV();
  __syncthreads();

  const int cswz = (fr & 7) << 4;  // read-side XOR for Ks
  const char* kbase = (const char*)Ks;

  for (int j = 0; j < T / 64; ++j) {
    // QK^T swapped: lane holds P[q=fr][k=n*16+fg*4+r]; kf reused for i=0,1.
    f32x4 sacc[2][4] = {};
#pragma unroll
    for (int ks = 0; ks < 4; ++ks) {
#pragma unroll
      for (int n = 0; n < 4; ++n) {
        const bf16x8 kf = *(const bf16x8*)(kbase + (n * 16 + fr) * 256 +
                                           ((ks * 64 + fg * 16) ^ cswz));
        sacc[0][n] = MFMA16(kf, qf[0][ks], sacc[0][n]);
        sacc[1][n] = MFMA16(kf, qf[1][ks], sacc[1][n]);
      }
    }
    __syncthreads();  // Ks consumed by all waves

    const bool more = (j + 1 < T / 64);
    if (more) {
      stageK((j + 1) * 64);  // DMA into Ks (dead) while exp+PV run
      loadV((j + 1) * 64);
    }

    // exp + in-register pack into PV A-fragments.
    bf16x8 paf[2][2];
#pragma unroll
    for (int i = 0; i < 2; ++i) {
      float lsum = 0.f;
#pragma unroll
      for (int ks2 = 0; ks2 < 2; ++ks2) {
#pragma unroll
        for (int jj = 0; jj < 8; ++jj) {
          const float p = exp2f(sacc[i][ks2 * 2 + (jj >> 2)][jj & 3]);
          lsum += p;
          paf[i][ks2][jj] = (bf16_t)p;
        }
      }
      l_i[i] += lsum;
    }

    // PV: vf reused for i=0,1; Vs column order matches paf's k order.
#pragma unroll
    for (int ks2 = 0; ks2 < 2; ++ks2) {
#pragma unroll
      for (int n = 0; n < 8; ++n) {
        const bf16x8 vf = *(const bf16x8*)(&Vs[n * 16 + fr][ks2 * 32 + fg * 8]);
        acc[0][n] = MFMA16(paf[0][ks2], vf, acc[0][n]);
        acc[1][n] = MFMA16(paf[1][ks2], vf, acc[1][n]);
      }
    }

    asm volatile("s_waitcnt vmcnt(0)" ::: "memory");  // K DMA + V regs landed
    __builtin_amdgcn_sched_barrier(0);
    __syncthreads();  // Vs consumed by all; Ks(j+1) visible
    if (more) {
      writeV();
      __syncthreads();  // Vs(j+1) ready
    }
  }

  // epilogue: l reduce across fg groups, then fetch 1/l per output row.
#pragma unroll
  for (int i = 0; i < 2; ++i) {
    float l = l_i[i];
    l += __shfl_xor(l, 16, 64);
    l += __shfl_xor(l, 32, 64);  // lanes with same fr now hold l_full(q=fr)
#pragma unroll
    for (int r = 0; r < 4; ++r) {
      const float inv = 1.0f / __shfl(l, fg * 4 + r, 64);
      const int t = qt * 128 + wave * 32 + i * 16 + fg * 4 + r;
      bf16_t* yrow = Y + (size_t)(b * T + t) * 2048 + h * 128;
#pragma unroll
      for (int n = 0; n < 8; ++n)
        yrow[n * 16 + fr] = (bf16_t)(acc[i][n][r] * inv);
    }
  }
}

// ---------------------------------------------------------------------------
// Flash fallback (ws-lean): fused rope, exp-only softmax. (unchanged)
// ---------------------------------------------------------------------------
__global__ __launch_bounds__(256) void flash_fused_v2(
    const bf16_t* __restrict__ qkv, const bf16_t* __restrict__ cosb,
    const bf16_t* __restrict__ sinb, bf16_t* __restrict__ Y) {
  constexpr int T = 2048;
  __shared__ bf16_t Ks[64][136];
  __shared__ bf16_t Vs[128][72];
  __shared__ bf16_t Ps[128][72];
  const int tid = threadIdx.x;
  const int lane = tid & 63;
  const int wave = tid >> 6;
  const int fr = lane & 15;
  const int fg = lane >> 4;
  const int qt = blockIdx.x;
  const int bh = blockIdx.y;
  const int b = bh >> 4, h = bh & 15;

  const bf16_t* qbase = qkv + (size_t)b * T * 6144 + h * 128;
  bf16x8 qf[2][4];
#pragma unroll
  for (int i = 0; i < 2; ++i) {
    const int trow = qt * 128 + wave * 32 + i * 16 + fr;
    const bf16_t* qrow = qbase + (size_t)trow * 6144;
#pragma unroll
    for (int ks = 0; ks < 4; ++ks) {
      const int d = ks * 32 + fg * 8;
      const float sgn = (d < 64) ? -1.f : 1.f;
      const bf16x8 qv = *(const bf16x8*)(qrow + d);
      const bf16x8 qp = *(const bf16x8*)(qrow + (d ^ 64));
      const bf16x8 cv = *(const bf16x8*)(cosb + trow * 128 + d);
      const bf16x8 sv = *(const bf16x8*)(sinb + trow * 128 + d);
      bf16x8 o;
#pragma unroll
      for (int jj = 0; jj < 8; ++jj)
        o[jj] = (bf16_t)((((float)qv[jj]) * ((float)cv[jj]) +
                          sgn * ((float)qp[jj]) * ((float)sv[jj])) *
                         0.08838834764831845f);
      qf[i][ks] = o;
    }
  }

  f32x4 acc[2][8] = {};
  float l_i[2][4] = {};

  const int kr = tid >> 4;
  const int kc = (tid & 15) * 8;
  const float sgnk = (kc < 64) ? -1.f : 1.f;
  const int tp = tid & 63;

  for (int j = 0; j < T / 64; ++j) {
    const int t0 = j * 64;
#pragma unroll
    for (int it = 0; it < 4; ++it) {
      const int row = it * 16 + kr;
      const int tg = t0 + row;
      const bf16_t* krow = qkv + ((size_t)(b * T + tg)) * 6144 + 2048 + h * 128;
      const bf16x8 kv = *(const bf16x8*)(krow + kc);
      const bf16x8 kp = *(const bf16x8*)(krow + (kc ^ 64));
      const bf16x8 cv = *(const bf16x8*)(cosb + tg * 128 + kc);
      const bf16x8 sv = *(const bf16x8*)(sinb + tg * 128 + kc);
      bf16x8 o;
#pragma unroll
      for (int jj = 0; jj < 8; ++jj)
        o[jj] = (bf16_t)(((float)kv[jj]) * ((float)cv[jj]) +
                         sgnk * ((float)kp[jj]) * ((float)sv[jj]));
      *(bf16x8*)(&Ks[row][kc]) = o;
    }
#pragma unroll
    for (int cc = 0; cc < 4; ++cc) {
      const int d8 = (cc * 4 + (tid >> 6)) * 8;
      const bf16x8 vv = *(const bf16x8*)(qkv + ((size_t)(b * T + t0 + tp)) * 6144 +
                                         4096 + h * 128 + d8);
#pragma unroll
      for (int jj = 0; jj < 8; ++jj) Vs[d8 + jj][tp] = vv[jj];
    }
    __syncthreads();

    f32x4 sacc[2][4] = {};
#pragma unroll
    for (int ks = 0; ks < 4; ++ks) {
#pragma unroll
      for (int n = 0; n < 4; ++n) {
        const bf16x8 kf = *(const bf16x8*)(&Ks[n * 16 + fr][ks * 32 + fg * 8]);
        sacc[0][n] = MFMA16(qf[0][ks], kf, sacc[0][n]);
        sacc[1][n] = MFMA16(qf[1][ks], kf, sacc[1][n]);
      }
    }

#pragma unroll
    for (int i = 0; i < 2; ++i) {
#pragma unroll
      for (int r = 0; r < 4; ++r) {
        const float p0 = __expf(sacc[i][0][r]);
        const float p1 = __expf(sacc[i][1][r]);
        const float p2 = __expf(sacc[i][2][r]);
        const float p3 = __expf(sacc[i][3][r]);
        l_i[i][r] += (p0 + p1) + (p2 + p3);
        const int prow = wave * 32 + i * 16 + fg * 4 + r;
        Ps[prow][0 + fr] = (bf16_t)p0;
        Ps[prow][16 + fr] = (bf16_t)p1;
        Ps[prow][32 + fr] = (bf16_t)p2;
        Ps[prow][48 + fr] = (bf16_t)p3;
      }
    }

#pragma unroll
    for (int ks = 0; ks < 2; ++ks) {
      const bf16x8 pf0 = *(const bf16x8*)(&Ps[wave * 32 + fr][ks * 32 + fg * 8]);
      const bf16x8 pf1 = *(const bf16x8*)(&Ps[wave * 32 + 16 + fr][ks * 32 + fg * 8]);
#pragma unroll
      for (int n = 0; n < 8; ++n) {
        const bf16x8 vf = *(const bf16x8*)(&Vs[n * 16 + fr][ks * 32 + fg * 8]);
        acc[0][n] = MFMA16(pf0, vf, acc[0][n]);
        acc[1][n] = MFMA16(pf1, vf, acc[1][n]);
      }
    }
    __syncthreads();
  }

#pragma unroll
  for (int i = 0; i < 2; ++i) {
#pragma unroll
    for (int r = 0; r < 4; ++r) {
      float l = l_i[i][r];
#pragma unroll
      for (int msk = 1; msk < 16; msk <<= 1) l += __shfl_xor(l, msk, 64);
      const float inv = 1.0f / l;
      const int t = qt * 128 + wave * 32 + i * 16 + fg * 4 + r;
      bf16_t* yrow = Y + (size_t)(b * T + t) * 2048 + h * 128;
#pragma unroll
      for (int n = 0; n < 8; ++n)
        yrow[n * 16 + fr] = (bf16_t)(acc[i][n][r] * inv);
    }
  }
}

// ---------------------------------------------------------------------------
extern "C" void kernel_launch(void* const* d_in, const int* in_sizes, int n_in,
                              void* d_out, int out_size, void* d_ws, size_t ws_size,
                              hipStream_t stream) {
  const float* x = (const float*)d_in[0];
  const float* cosi = (const float*)d_in[1];
  const float* sini = (const float*)d_in[2];
  const float* Wqkv = (const float*)d_in[3];
  const float* Wproj = (const float*)d_in[4];

  const size_t NEED_FAST = sizeof(bf16_t) *
      ((size_t)12582912 + 262144 + 262144 + 25165824 + 8388608 + 8388608);
  const size_t NEED_BASE = 256 + sizeof(bf16_t) *
      ((size_t)12582912 + 4194304 + 262144 + 262144 + 25165824);

  if (ws_size >= NEED_FAST) {
    bf16_t* base = (bf16_t*)d_ws;
    bf16_t* WqkvT = base;                    // dead after gemm1
    bf16_t* y = base;                        // alias
    bf16_t* cosb = base + 12582912;
    bf16_t* sinb = cosb + 262144;
    bf16_t* qkv = sinb + 262144;             // live through flash
    bf16_t* WprojT = qkv;                    // alias head, written after flash
    bf16_t* Kr = qkv + 25165824;
    bf16_t* xb = Kr;                         // alias: x-bf16, dead before rope_k
    bf16_t* Vt = Kr + 8388608;

    conv_vec_f32<<<128, 256, 0, stream>>>(cosi, cosb, 32768);
    conv_vec_f32<<<128, 256, 0, stream>>>(sini, sinb, 32768);
    conv_vec_f32<<<4096, 256, 0, stream>>>(x, xb, 1048576);  // x -> bf16
    conv_transpose_f32<<<dim3(96, 32), 256, 0, stream>>>(Wqkv, WqkvT, 2048, 6144);
    gemm8k<false><<<512, 512, 0, stream>>>(xb, WqkvT, qkv, 4096, 6144, 2048, 32);
    rope_k<<<4096, 256, 0, stream>>>(qkv, cosb, sinb, Kr);  // overwrites xb (dead)
    transpose_v<<<dim3(32, 2, 32), 256, 0, stream>>>(qkv, Vt);
    flash_q128p<<<dim3(16, 32), 256, 0, stream>>>(qkv, cosb, sinb, Kr, Vt, y);
    conv_transpose_f32<<<dim3(32, 32), 256, 0, stream>>>(Wproj, WprojT, 2048, 2048);
    gemm8n<true><<<256, 512, 0, stream>>>(y, WprojT, d_out, 4096, 2048, 2048, 8);
  } else if (ws_size >= NEED_BASE) {
    bf16_t* base = (bf16_t*)((char*)d_ws + 256);
    bf16_t* WqkvT = base;
    bf16_t* y = base;
    bf16_t* WprojT = base + 12582912;
    bf16_t* cosb = WprojT + 4194304;
    bf16_t* sinb = cosb + 262144;
    bf16_t* qkv = sinb + 262144;

    conv_vec_f32<<<128, 256, 0, stream>>>(cosi, cosb, 32768);
    conv_vec_f32<<<128, 256, 0, stream>>>(sini, sinb, 32768);
    conv_transpose_f32<<<dim3(96, 32), 256, 0, stream>>>(Wqkv, WqkvT, 2048, 6144);
    gemm_t<true, false><<<dim3(32, 48), 256, 0, stream>>>(x, WqkvT, qkv, 4096, 6144, 2048);
    flash_fused_v2<<<dim3(16, 32), 256, 0, stream>>>(qkv, cosb, sinb, y);
    conv_transpose_f32<<<dim3(32, 32), 256, 0, stream>>>(Wproj, WprojT, 2048, 2048);
    gemm_t<false, true><<<dim3(32, 16), 256, 0, stream>>>(y, WprojT, d_out, 4096, 2048, 2048);
  } else {
    fill_diag<<<(out_size + 255) / 256, 256, 0, stream>>>((uint32_t*)d_out, out_size);
  }
}

// Round 10
// 393.185 us; speedup vs baseline: 1.7634x; 1.0045x over previous
//
#include <hip/hip_runtime.h>
#include <cstdint>
#include <cstddef>

typedef __bf16 bf16_t;
typedef __bf16 bf16x8 __attribute__((ext_vector_type(8)));
typedef __bf16 bf16x4 __attribute__((ext_vector_type(4)));
typedef float f32x4 __attribute__((ext_vector_type(4)));

#define MFMA16(a, b, c) __builtin_amdgcn_mfma_f32_16x16x32_bf16(a, b, c, 0, 0, 0)

// async global->LDS, 16B per lane. LDS dest = wave-uniform base + lane*16.
__device__ __forceinline__ void gll16(const bf16_t* g, bf16_t* l) {
  __builtin_amdgcn_global_load_lds(
      (__attribute__((address_space(1))) uint32_t*)((uintptr_t)g),
      (__attribute__((address_space(3))) uint32_t*)((uint32_t)(uintptr_t)l),
      16, 0, 0);
}

// Diagnostic: absmax ~1000 => ws_size too small.
__global__ void fill_diag(uint32_t* out, int n_u32) {
  int i = blockIdx.x * 256 + threadIdx.x;
  if (i < n_u32) out[i] = 0x447A0000u;  // f32 1000.0
}

// ---------------------------------------------------------------------------
// f32 -> bf16 vector convert (x, cos/sin tables). One bf16x8 per thread.
// ---------------------------------------------------------------------------
__global__ void conv_vec_f32(const float* __restrict__ in, bf16_t* __restrict__ out,
                             int n8) {
  const int i = blockIdx.x * 256 + threadIdx.x;
  if (i >= n8) return;
  const float* p = in + (size_t)i * 8;
  const f32x4 a = *(const f32x4*)p;
  const f32x4 b = *(const f32x4*)(p + 4);
  bf16x8 o;
#pragma unroll
  for (int j = 0; j < 4; ++j) {
    o[j] = (bf16_t)a[j];
    o[4 + j] = (bf16_t)b[j];
  }
  ((bf16x8*)out)[i] = o;
}

// ---------------------------------------------------------------------------
// 64x64 tiled transpose+convert: in R x C f32 -> out C x R bf16.
// ---------------------------------------------------------------------------
__global__ __launch_bounds__(256) void conv_transpose_f32(
    const float* __restrict__ in, bf16_t* __restrict__ out, int R, int C) {
  __shared__ bf16_t tile[64][72];
  const int bc = blockIdx.x * 64;
  const int br = blockIdx.y * 64;
  const int t = threadIdx.x;
  const int r = t >> 3;
  const int c8 = (t & 7) * 8;
#pragma unroll
  for (int ii = 0; ii < 2; ++ii) {
    const int rr = r + ii * 32;
    const float* p = in + (size_t)(br + rr) * C + bc + c8;
    const f32x4 a = *(const f32x4*)p;
    const f32x4 b = *(const f32x4*)(p + 4);
    bf16x8 v;
#pragma unroll
    for (int j = 0; j < 4; ++j) {
      v[j] = (bf16_t)a[j];
      v[4 + j] = (bf16_t)b[j];
    }
    *(bf16x8*)(&tile[rr][c8]) = v;
  }
  __syncthreads();
#pragma unroll
  for (int ii = 0; ii < 2; ++ii) {
    const int rr = r + ii * 32;
    bf16x8 o;
#pragma unroll
    for (int jj = 0; jj < 8; ++jj) o[jj] = tile[c8 + jj][rr];
    *(bf16x8*)(out + (size_t)(bc + rr) * R + br + c8) = o;
  }
}

// ---------------------------------------------------------------------------
// gemm8k: 256x192-tile 2-phase GEMM (qkv shape; best measured variant).
// ---------------------------------------------------------------------------
template <bool C32>
__global__ __launch_bounds__(512, 2) void gemm8k(
    const bf16_t* __restrict__ A, const bf16_t* __restrict__ Bt,
    void* __restrict__ C, int M, int N, int K, int nbn) {
  __shared__ __align__(1024) bf16_t lds8[57344];  // A: 4x8192 el, B: 6x4096 el
  bf16_t* As = lds8;            // 4 half-slots
  bf16_t* Bs = lds8 + 32768;    // 6 third-slots

  const int tid = threadIdx.x;
  const int lane = tid & 63;
  const int wave = tid >> 6;
  const int wr = wave >> 2;  // 0..1 (M half: 128 rows)
  const int wc = wave & 3;   // 0..3 (N: 48 cols)
  const int fr = lane & 15;
  const int fg = lane >> 4;

  // XCD-aware bijective swizzle (nwg % 8 == 0 by construction).
  const int nwg = gridDim.x;
  const int bid = blockIdx.x;
  const int swz = (bid & 7) * (nwg >> 3) + (bid >> 3);
  const int m0 = (swz / nbn) * 256;
  const int n0 = (swz % nbn) * 192;

  const int NT = K >> 6;  // BK=64 tiles (K=2048 -> 32)

  // A staging: wave covers segs {2w,2w+1}.
  const int sseg0 = wave * 2;
  const int srow = lane >> 3;
  const int sj = lane & 7;
  auto stageA = [&](int kt, int h) {
#pragma unroll
    for (int l = 0; l < 2; ++l) {
      const int seg = sseg0 + l;
      const int r = seg * 8 + srow;      // row in half 0..127
      const int j = sj ^ (r & 7);        // inverse-swizzled source chunk
      gll16(A + (size_t)(m0 + h * 128 + r) * K + kt * 64 + j * 8,
            As + ((2 * kt + h) & 3) * 8192 + seg * 512 + lane * 8);
    }
  };
  // B staging: one 64-row third (8KB) = 1 gll16/thread.
  const int srow3 = tid >> 3;           // 0..63
  const int sj3 = tid & 7;
  auto stageB = [&](int kt, int g) {
    const int j = sj3 ^ (srow3 & 7);
    gll16(Bt + (size_t)(n0 + g * 64 + srow3) * K + kt * 64 + j * 8,
          Bs + ((3 * kt + g) % 6) * 4096 + tid * 8);
  };

  const int cb0 = (fg * 16) ^ ((fr & 7) << 4);  // swizzled k-half-0 byte col

  auto lda = [&](bf16x8(&af)[4][2], int t, int mlo) {
    const char* base = (const char*)(As + ((2 * t + wr) & 3) * 8192);
#pragma unroll
    for (int m = 0; m < 4; ++m) {
      const char* p = base + ((mlo + m) * 16 + fr) * 128;
      af[m][0] = *(const bf16x8*)(p + cb0);
      af[m][1] = *(const bf16x8*)(p + (cb0 ^ 64));
    }
  };
  auto ldb = [&](bf16x8(&bf)[3][2], int t) {
#pragma unroll
    for (int n = 0; n < 3; ++n) {
      const int c = wc * 48 + n * 16;   // col in 192-tile
      const int g = c >> 6;
      const int r = c & 63;
      const char* p = (const char*)(Bs + ((3 * t + g) % 6) * 4096) +
                      (r + fr) * 128;
      bf[n][0] = *(const bf16x8*)(p + cb0);
      bf[n][1] = *(const bf16x8*)(p + (cb0 ^ 64));
    }
  };

  f32x4 acc[8][3] = {};

  // Prologue: A(0) both halves, B(0) 3 thirds, B(1) 3 thirds.
  stageA(0, 0);
  stageA(0, 1);
  stageB(0, 0);
  stageB(0, 1);
  stageB(0, 2);
  stageB(1, 0);
  stageB(1, 1);
  stageB(1, 2);
  asm volatile("s_waitcnt vmcnt(3)" ::: "memory");  // A(0)+B(0) landed
  __builtin_amdgcn_s_barrier();

  bf16x8 af[4][2], bf[3][2];

  for (int t = 0; t < NT; ++t) {
    // ---- ph1: af m0-3 (8) + bf all (6); stage A(t+1,h0); MFMA m0-3 ----
    lda(af, t, 0);
    ldb(bf, t);
    if (t + 1 < NT) stageA(t + 1, 0);
    asm volatile("s_waitcnt lgkmcnt(8)" ::: "memory");
    __builtin_amdgcn_s_barrier();
    asm volatile("s_waitcnt lgkmcnt(0)" ::: "memory");
    __builtin_amdgcn_sched_barrier(0);
    __builtin_amdgcn_s_setprio(1);
#pragma unroll
    for (int k = 0; k < 2; ++k)
#pragma unroll
      for (int m = 0; m < 4; ++m)
#pragma unroll
        for (int n = 0; n < 3; ++n)
          acc[m][n] = MFMA16(af[m][k], bf[n][k], acc[m][n]);
    __builtin_amdgcn_s_setprio(0);
    __builtin_amdgcn_s_barrier();
    // ---- ph2: af m4-7 (8); stage A(t+1,h1), B(t+2,g0..2); MFMA m4-7 ----
    lda(af, t, 4);
    if (t + 1 < NT) stageA(t + 1, 1);
    if (t + 2 < NT) {
      stageB(t + 2, 0);
      stageB(t + 2, 1);
      stageB(t + 2, 2);
    }
    __builtin_amdgcn_s_barrier();
    asm volatile("s_waitcnt lgkmcnt(0)" ::: "memory");
    __builtin_amdgcn_sched_barrier(0);
    __builtin_amdgcn_s_setprio(1);
#pragma unroll
    for (int k = 0; k < 2; ++k)
#pragma unroll
      for (int m = 0; m < 4; ++m)
#pragma unroll
        for (int n = 0; n < 3; ++n)
          acc[m + 4][n] = MFMA16(af[m][k], bf[n][k], acc[m + 4][n]);
    __builtin_amdgcn_s_setprio(0);
    if (t + 2 < NT) {
      asm volatile("s_waitcnt vmcnt(3)" ::: "memory");  // keep B(t+2) in flight
    } else {
      asm volatile("s_waitcnt vmcnt(0)" ::: "memory");  // tail drain
    }
    __builtin_amdgcn_s_barrier();
  }

#pragma unroll
  for (int m = 0; m < 8; ++m) {
#pragma unroll
    for (int n = 0; n < 3; ++n) {
#pragma unroll
      for (int r = 0; r < 4; ++r) {
        const int row = m0 + wr * 128 + m * 16 + fg * 4 + r;
        const int col = n0 + wc * 48 + n * 16 + fr;
        const size_t idx = (size_t)row * N + col;
        if (C32)
          ((float*)C)[idx] = acc[m][n][r];
        else
          ((bf16_t*)C)[idx] = (bf16_t)acc[m][n][r];
      }
    }
  }
  (void)M;
}

// ---------------------------------------------------------------------------
// gemm8n: 128x256-tile 2-phase GEMM — kept for the proj GEMM (grid 256
// = exactly 1 CU round; N=2048 not divisible by 192).
// ---------------------------------------------------------------------------
template <bool C32>
__global__ __launch_bounds__(512, 2) void gemm8n(
    const bf16_t* __restrict__ A, const bf16_t* __restrict__ Bt,
    void* __restrict__ C, int M, int N, int K, int nbn) {
  __shared__ __align__(1024) bf16_t lds8[65536];  // A: 3x8192, B: 5x8192 (bf16)
  bf16_t* As = lds8;           // 3 slots * 8192 el
  bf16_t* Bs = lds8 + 24576;   // 5 slots * 8192 el

  const int tid = threadIdx.x;
  const int lane = tid & 63;
  const int wave = tid >> 6;
  const int wr = wave >> 2;
  const int wc = wave & 3;
  const int fr = lane & 15;
  const int fg = lane >> 4;

  const int nwg = gridDim.x;
  const int bid = blockIdx.x;
  const int swz = (bid & 7) * (nwg >> 3) + (bid >> 3);
  const int m0 = (swz / nbn) * 128;
  const int n0 = (swz % nbn) * 256;

  const int NT = K >> 6;

  const int srow = tid >> 3;  // 0..63
  const int sj = tid & 7;

  auto stage = [&](const bf16_t* __restrict__ G, int grow0, bf16_t* slotBase,
                   int kt) {
#pragma unroll
    for (int l = 0; l < 2; ++l) {
      const int r = l * 64 + srow;
      const int j = sj ^ (r & 7);
      gll16(G + (size_t)(grow0 + r) * K + kt * 64 + j * 8,
            slotBase + l * 4096 + tid * 8);
    }
  };

  const int cb0 = (fg * 16) ^ ((fr & 7) << 4);

  auto lda = [&](bf16x8(&af)[4][2], int t) {
    const char* base = (const char*)(As + (t % 3) * 8192);
#pragma unroll
    for (int m = 0; m < 4; ++m) {
      const char* p = base + (wr * 64 + m * 16 + fr) * 128;
      af[m][0] = *(const bf16x8*)(p + cb0);
      af[m][1] = *(const bf16x8*)(p + (cb0 ^ 64));
    }
  };
  auto ldb2 = [&](bf16x8(&bf)[2][2], int t, int nlo) {
    const char* base = (const char*)(Bs + ((2 * t + (wc >> 1)) % 5) * 8192);
#pragma unroll
    for (int n = 0; n < 2; ++n) {
      const char* p = base + ((wc & 1) * 64 + (nlo + n) * 16 + fr) * 128;
      bf[n][0] = *(const bf16x8*)(p + cb0);
      bf[n][1] = *(const bf16x8*)(p + (cb0 ^ 64));
    }
  };

  f32x4 acc[4][4] = {};

  stage(A, m0, As, 0);
  stage(A, m0, As + 8192, 1);
  stage(Bt, n0, Bs, 0);
  stage(Bt, n0 + 128, Bs + 8192, 0);
  stage(Bt, n0, Bs + 2 * 8192, 1);
  asm volatile("s_waitcnt vmcnt(2)" ::: "memory");
  __builtin_amdgcn_s_barrier();

  bf16x8 af[4][2], bf01[2][2], bf23[2][2];

  for (int t = 0; t < NT; ++t) {
    lda(af, t);
    ldb2(bf01, t, 0);
    if (t + 2 < NT) stage(Bt, n0, Bs + ((2 * t + 4) % 5) * 8192, t + 2);
    if (t + 1 < NT) stage(Bt, n0 + 128, Bs + ((2 * t + 3) % 5) * 8192, t + 1);
    asm volatile("s_waitcnt lgkmcnt(8)" ::: "memory");
    __builtin_amdgcn_s_barrier();
    asm volatile("s_waitcnt lgkmcnt(0)" ::: "memory");
    __builtin_amdgcn_sched_barrier(0);
    __builtin_amdgcn_s_setprio(1);
#pragma unroll
    for (int k = 0; k < 2; ++k)
#pragma unroll
      for (int m = 0; m < 4; ++m)
#pragma unroll
        for (int n = 0; n < 2; ++n)
          acc[m][n] = MFMA16(af[m][k], bf01[n][k], acc[m][n]);
    __builtin_amdgcn_s_setprio(0);
    __builtin_amdgcn_s_barrier();
    ldb2(bf23, t, 2);
    if (t + 2 < NT) stage(A, m0, As + ((t + 2) % 3) * 8192, t + 2);
    __builtin_amdgcn_s_barrier();
    asm volatile("s_waitcnt lgkmcnt(0)" ::: "memory");
    __builtin_amdgcn_sched_barrier(0);
    __builtin_amdgcn_s_setprio(1);
#pragma unroll
    for (int k = 0; k < 2; ++k)
#pragma unroll
      for (int m = 0; m < 4; ++m)
#pragma unroll
        for (int n = 0; n < 2; ++n)
          acc[m][n + 2] = MFMA16(af[m][k], bf23[n][k], acc[m][n + 2]);
    __builtin_amdgcn_s_setprio(0);
    if (t + 3 < NT) {
      asm volatile("s_waitcnt vmcnt(2)" ::: "memory");
    } else {
      asm volatile("s_waitcnt vmcnt(0)" ::: "memory");
    }
    __builtin_amdgcn_s_barrier();
  }

#pragma unroll
  for (int m = 0; m < 4; ++m) {
#pragma unroll
    for (int n = 0; n < 4; ++n) {
#pragma unroll
      for (int r = 0; r < 4; ++r) {
        const int row = m0 + wr * 64 + m * 16 + fg * 4 + r;
        const int col = n0 + wc * 64 + n * 16 + fr;
        const size_t idx = (size_t)row * N + col;
        if (C32)
          ((float*)C)[idx] = acc[m][n][r];
        else
          ((bf16_t*)C)[idx] = (bf16_t)acc[m][n][r];
      }
    }
  }
  (void)M;
}

// ---------------------------------------------------------------------------
// Register-staged GEMM (fallback path only): A f32 option, C f32 option.
// ---------------------------------------------------------------------------
template <bool A32, bool C32>
__global__ __launch_bounds__(256) void gemm_t(
    const void* __restrict__ A, const bf16_t* __restrict__ Bt,
    void* __restrict__ C, int M, int N, int K) {
  __shared__ bf16_t As[128 * 32];
  __shared__ bf16_t Bs[128 * 32];
  const int tid = threadIdx.x;
  const int lane = tid & 63;
  const int wave = tid >> 6;
  const int m0 = blockIdx.x * 128;
  const int n0 = blockIdx.y * 128;
  const int wm = (wave & 1) * 64;
  const int wn = (wave >> 1) * 64;
  const int fr = lane & 15;
  const int fk = (lane >> 4) * 8;

  f32x4 acc[4][4] = {};

  const size_t ea0 = (size_t)(m0 + (tid >> 2)) * K + (tid & 3) * 8;
  const bf16_t* gb = Bt + (size_t)(n0 + (tid >> 2)) * K + (tid & 3) * 8;
  bf16_t* lA = As + tid * 8;
  bf16_t* lB = Bs + tid * 8;
  const size_t half = (size_t)64 * K;

  for (int k0 = 0; k0 < K; k0 += 32) {
    bf16x8 ra0, ra1;
    if (A32) {
      const float* pa = (const float*)A + ea0 + k0;
      const f32x4 x0 = *(const f32x4*)pa;
      const f32x4 x1 = *(const f32x4*)(pa + 4);
      const f32x4 x2 = *(const f32x4*)(pa + half);
      const f32x4 x3 = *(const f32x4*)(pa + half + 4);
#pragma unroll
      for (int j = 0; j < 4; ++j) {
        ra0[j] = (bf16_t)x0[j];
        ra0[4 + j] = (bf16_t)x1[j];
        ra1[j] = (bf16_t)x2[j];
        ra1[4 + j] = (bf16_t)x3[j];
      }
    } else {
      const bf16_t* pa = (const bf16_t*)A + ea0 + k0;
      ra0 = *(const bf16x8*)pa;
      ra1 = *(const bf16x8*)(pa + half);
    }
    const bf16x8 rb0 = *(const bf16x8*)gb;
    const bf16x8 rb1 = *(const bf16x8*)(gb + half);
    gb += 32;
    __syncthreads();
    *(bf16x8*)lA = ra0;
    *(bf16x8*)(lA + 2048) = ra1;
    *(bf16x8*)lB = rb0;
    *(bf16x8*)(lB + 2048) = rb1;
    __syncthreads();
    bf16x8 af[4], bfr[4];
#pragma unroll
    for (int i = 0; i < 4; ++i)
      af[i] = *(const bf16x8*)(As + (wm + i * 16 + fr) * 32 + fk);
#pragma unroll
    for (int j = 0; j < 4; ++j)
      bfr[j] = *(const bf16x8*)(Bs + (wn + j * 16 + fr) * 32 + fk);
#pragma unroll
    for (int i = 0; i < 4; ++i)
#pragma unroll
      for (int j = 0; j < 4; ++j)
        acc[i][j] = MFMA16(af[i], bfr[j], acc[i][j]);
  }

  const int fg = lane >> 4;
#pragma unroll
  for (int i = 0; i < 4; ++i) {
#pragma unroll
    for (int j = 0; j < 4; ++j) {
#pragma unroll
      for (int r = 0; r < 4; ++r) {
        const int row = m0 + wm + i * 16 + fg * 4 + r;
        const int col = n0 + wn + j * 16 + fr;
        const size_t idx = (size_t)row * N + col;
        if (C32)
          ((float*)C)[idx] = acc[i][j][r];
        else
          ((bf16_t*)C)[idx] = (bf16_t)acc[i][j][r];
      }
    }
  }
}

// ---------------------------------------------------------------------------
// K rope extract: qkv (B*T,6144) -> Kr (B,H,T,D) bf16 rope'd.
// ---------------------------------------------------------------------------
__global__ __launch_bounds__(256) void rope_k(
    const bf16_t* __restrict__ qkv, const bf16_t* __restrict__ cosb,
    const bf16_t* __restrict__ sinb, bf16_t* __restrict__ Kr) {
  const int row = blockIdx.x;  // b*2048 + t
  const int t = row & 2047;
  const int b = row >> 11;
  const int idx = threadIdx.x * 8;
  const int h = idx >> 7;
  const int d = idx & 127;
  const float sgn = (d < 64) ? -1.f : 1.f;
  const bf16_t* base = qkv + (size_t)row * 6144 + 2048;
  const bf16x8 kv = *(const bf16x8*)(base + idx);
  const bf16x8 kp = *(const bf16x8*)(base + (idx ^ 64));
  const bf16x8 cv = *(const bf16x8*)(cosb + t * 128 + d);
  const bf16x8 sv = *(const bf16x8*)(sinb + t * 128 + d);
  bf16x8 o;
#pragma unroll
  for (int jj = 0; jj < 8; ++jj)
    o[jj] = (bf16_t)(((float)kv[jj]) * ((float)cv[jj]) +
                     sgn * ((float)kp[jj]) * ((float)sv[jj]));
  *(bf16x8*)(Kr + ((size_t)(b * 16 + h) * 2048 + t) * 128 + d) = o;
}

// ---------------------------------------------------------------------------
// V extract + transpose: qkv cols 4096.. -> Vt (B,H,D,T).
// ---------------------------------------------------------------------------
__global__ __launch_bounds__(256) void transpose_v(
    const bf16_t* __restrict__ qkv, bf16_t* __restrict__ Vt) {
  __shared__ bf16_t tile[64][72];
  const int bh = blockIdx.z;
  const int b = bh >> 4, h = bh & 15;
  const int t0 = blockIdx.x * 64;
  const int d0 = blockIdx.y * 64;
  const int t = threadIdx.x;
  const int r = t >> 3;
  const int c8 = (t & 7) * 8;
#pragma unroll
  for (int ii = 0; ii < 2; ++ii) {
    const int rr = r + ii * 32;
    *(bf16x8*)(&tile[rr][c8]) =
        *(const bf16x8*)(qkv + (size_t)(b * 2048 + t0 + rr) * 6144 + 4096 + h * 128 + d0 + c8);
  }
  __syncthreads();
#pragma unroll
  for (int ii = 0; ii < 2; ++ii) {
    const int rr = r + ii * 32;
    bf16x8 o;
#pragma unroll
    for (int jj = 0; jj < 8; ++jj) o[jj] = tile[c8 + jj][rr];
    *(bf16x8*)(Vt + ((size_t)bh * 128 + d0 + rr) * 2048 + t0 + c8) = o;
  }
}

// ---------------------------------------------------------------------------
// Flash round-10: DOUBLE-BUFFERED pipeline (Ks[2], Vs[2], 69.6KB LDS).
// K(j+1) DMA + V(j+1) reg-loads issued BEFORE QK^T so latency hides under
// the whole iteration; slots make the in-flight buffer disjoint from the
// read buffer, collapsing 3 barriers/iter to 1 (vmcnt(0)+writeV+barrier at
// iteration end). All round-8 machinery kept: QBLK=128 (q-per-wave=32),
// swapped QK^T, rule-#21 K swizzle, π-permuted Vs, in-register P, exp2.
// ---------------------------------------------------------------------------
__global__ __launch_bounds__(256, 2) void flash_q128d(
    const bf16_t* __restrict__ qkv, const bf16_t* __restrict__ cosb,
    const bf16_t* __restrict__ sinb, const bf16_t* __restrict__ Kr,
    const bf16_t* __restrict__ Vt, bf16_t* __restrict__ Y) {
  constexpr int T = 2048;
  __shared__ __align__(1024) bf16_t Ks[2 * 64 * 128];  // 2 swizzled slots
  __shared__ bf16_t Vs[2][128][72];                    // 2 π-permuted slots
  const int tid = threadIdx.x;
  const int lane = tid & 63;
  const int fr = lane & 15;
  const int fg = lane >> 4;
  const int qt = blockIdx.x;  // 0..15, 128 q-rows each
  const int bh = blockIdx.y;
  const int b = bh >> 4, h = bh & 15;
  const int wave = tid >> 6;

  // Q rope'd on the fly; scale = rsqrt(128) * log2(e) folded in.
  const bf16_t* qbase = qkv + (size_t)b * T * 6144 + h * 128;
  bf16x8 qf[2][4];
#pragma unroll
  for (int i = 0; i < 2; ++i) {
    const int trow = qt * 128 + wave * 32 + i * 16 + fr;
    const bf16_t* qrow = qbase + (size_t)trow * 6144;
#pragma unroll
    for (int ks = 0; ks < 4; ++ks) {
      const int d = ks * 32 + fg * 8;
      const float sgn = (d < 64) ? -1.f : 1.f;
      const bf16x8 qv = *(const bf16x8*)(qrow + d);
      const bf16x8 qp = *(const bf16x8*)(qrow + (d ^ 64));
      const bf16x8 cv = *(const bf16x8*)(cosb + trow * 128 + d);
      const bf16x8 sv = *(const bf16x8*)(sinb + trow * 128 + d);
      bf16x8 o;
#pragma unroll
      for (int jj = 0; jj < 8; ++jj)
        o[jj] = (bf16_t)((((float)qv[jj]) * ((float)cv[jj]) +
                          sgn * ((float)qp[jj]) * ((float)sv[jj])) *
                         0.1275174825f);  // (1/sqrt(128)) * log2(e)
      qf[i][ks] = o;
    }
  }

  f32x4 acc[2][8] = {};
  float l_i[2] = {0.f, 0.f};

  const int krow = tid >> 4;                    // 0..15
  const int sc = (tid & 15) ^ (krow & 7);       // pre-swizzled source chunk
  const int vrow = tid >> 3;        // 0..31 (d rows, +32*it)
  const int vu = tid & 7;           // t-chunk index (8 consecutive t)
  const int vc0 = ((vu >> 2) * 32) + ((vu & 1) * 16) + (((vu >> 1) & 1) * 4);
  const bf16_t* Kh = Kr + (size_t)bh * T * 128;
  const bf16_t* Vh = Vt + (size_t)bh * 128 * T;

  auto stageK = [&](int t0, int s) {
#pragma unroll
    for (int it = 0; it < 4; ++it)
      gll16(Kh + (size_t)(t0 + it * 16 + krow) * 128 + sc * 8,
            Ks + s * 8192 + it * 2048 + tid * 8);
  };
  bf16x8 vreg[4];
  auto loadV = [&](int t0) {
#pragma unroll
    for (int it = 0; it < 4; ++it)
      vreg[it] = *(const bf16x8*)(Vh + (size_t)(it * 32 + vrow) * T + t0 + vu * 8);
  };
  auto writeV = [&](int s) {
#pragma unroll
    for (int it = 0; it < 4; ++it) {
      const int row = it * 32 + vrow;
      const bf16x8 v = vreg[it];
      bf16x4 lo, hi;
#pragma unroll
      for (int jj = 0; jj < 4; ++jj) {
        lo[jj] = v[jj];
        hi[jj] = v[4 + jj];
      }
      *(bf16x4*)(&Vs[s][row][vc0]) = lo;      // t = base+0..3  (b2=0)
      *(bf16x4*)(&Vs[s][row][vc0 + 8]) = hi;  // t = base+4..7  (b2=1)
    }
  };

  // prologue: stage tile 0 into slot 0
  stageK(0, 0);
  loadV(0);
  asm volatile("s_waitcnt vmcnt(0)" ::: "memory");
  __builtin_amdgcn_sched_barrier(0);
  writeV(0);
  __syncthreads();

  const int cswz = (fr & 7) << 4;  // read-side XOR for Ks
  const char* kbase0 = (const char*)Ks;

  for (int j = 0; j < T / 64; ++j) {
    const int cur = j & 1;
    const int nxt = cur ^ 1;
    const bool more = (j + 1 < T / 64);
    // issue next tile's K DMA (into slot nxt) + V reg loads EARLY: latency
    // hides under this whole iteration's QK^T + exp + PV.
    if (more) {
      stageK((j + 1) * 64, nxt);
      loadV((j + 1) * 64);
    }

    // QK^T swapped: lane holds P[q=fr][k=n*16+fg*4+r]; kf reused for i=0,1.
    const char* kbase = kbase0 + cur * 16384;
    f32x4 sacc[2][4] = {};
#pragma unroll
    for (int ks = 0; ks < 4; ++ks) {
#pragma unroll
      for (int n = 0; n < 4; ++n) {
        const bf16x8 kf = *(const bf16x8*)(kbase + (n * 16 + fr) * 256 +
                                           ((ks * 64 + fg * 16) ^ cswz));
        sacc[0][n] = MFMA16(kf, qf[0][ks], sacc[0][n]);
        sacc[1][n] = MFMA16(kf, qf[1][ks], sacc[1][n]);
      }
    }

    // exp + in-register pack into PV A-fragments.
    bf16x8 paf[2][2];
#pragma unroll
    for (int i = 0; i < 2; ++i) {
      float lsum = 0.f;
#pragma unroll
      for (int ks2 = 0; ks2 < 2; ++ks2) {
#pragma unroll
        for (int jj = 0; jj < 8; ++jj) {
          const float p = exp2f(sacc[i][ks2 * 2 + (jj >> 2)][jj & 3]);
          lsum += p;
          paf[i][ks2][jj] = (bf16_t)p;
        }
      }
      l_i[i] += lsum;
    }

    // PV: vf reused for i=0,1; Vs column order matches paf's k order.
#pragma unroll
    for (int ks2 = 0; ks2 < 2; ++ks2) {
#pragma unroll
      for (int n = 0; n < 8; ++n) {
        const bf16x8 vf =
            *(const bf16x8*)(&Vs[cur][n * 16 + fr][ks2 * 32 + fg * 8]);
        acc[0][n] = MFMA16(paf[0][ks2], vf, acc[0][n]);
        acc[1][n] = MFMA16(paf[1][ks2], vf, acc[1][n]);
      }
    }

    if (more) {
      asm volatile("s_waitcnt vmcnt(0)" ::: "memory");  // K DMA + V regs landed
      __builtin_amdgcn_sched_barrier(0);
      writeV(nxt);  // distinct slot: no reader until after the barrier
    }
    __syncthreads();  // all waves done with cur; nxt fully populated
  }

  // epilogue: l reduce across fg groups, then fetch 1/l per output row.
#pragma unroll
  for (int i = 0; i < 2; ++i) {
    float l = l_i[i];
    l += __shfl_xor(l, 16, 64);
    l += __shfl_xor(l, 32, 64);  // lanes with same fr now hold l_full(q=fr)
#pragma unroll
    for (int r = 0; r < 4; ++r) {
      const float inv = 1.0f / __shfl(l, fg * 4 + r, 64);
      const int t = qt * 128 + wave * 32 + i * 16 + fg * 4 + r;
      bf16_t* yrow = Y + (size_t)(b * T + t) * 2048 + h * 128;
#pragma unroll
      for (int n = 0; n < 8; ++n)
        yrow[n * 16 + fr] = (bf16_t)(acc[i][n][r] * inv);
    }
  }
}

// ---------------------------------------------------------------------------
// Flash fallback (ws-lean): fused rope, exp-only softmax. (unchanged)
// ---------------------------------------------------------------------------
__global__ __launch_bounds__(256) void flash_fused_v2(
    const bf16_t* __restrict__ qkv, const bf16_t* __restrict__ cosb,
    const bf16_t* __restrict__ sinb, bf16_t* __restrict__ Y) {
  constexpr int T = 2048;
  __shared__ bf16_t Ks[64][136];
  __shared__ bf16_t Vs[128][72];
  __shared__ bf16_t Ps[128][72];
  const int tid = threadIdx.x;
  const int lane = tid & 63;
  const int wave = tid >> 6;
  const int fr = lane & 15;
  const int fg = lane >> 4;
  const int qt = blockIdx.x;
  const int bh = blockIdx.y;
  const int b = bh >> 4, h = bh & 15;

  const bf16_t* qbase = qkv + (size_t)b * T * 6144 + h * 128;
  bf16x8 qf[2][4];
#pragma unroll
  for (int i = 0; i < 2; ++i) {
    const int trow = qt * 128 + wave * 32 + i * 16 + fr;
    const bf16_t* qrow = qbase + (size_t)trow * 6144;
#pragma unroll
    for (int ks = 0; ks < 4; ++ks) {
      const int d = ks * 32 + fg * 8;
      const float sgn = (d < 64) ? -1.f : 1.f;
      const bf16x8 qv = *(const bf16x8*)(qrow + d);
      const bf16x8 qp = *(const bf16x8*)(qrow + (d ^ 64));
      const bf16x8 cv = *(const bf16x8*)(cosb + trow * 128 + d);
      const bf16x8 sv = *(const bf16x8*)(sinb + trow * 128 + d);
      bf16x8 o;
#pragma unroll
      for (int jj = 0; jj < 8; ++jj)
        o[jj] = (bf16_t)((((float)qv[jj]) * ((float)cv[jj]) +
                          sgn * ((float)qp[jj]) * ((float)sv[jj])) *
                         0.08838834764831845f);
      qf[i][ks] = o;
    }
  }

  f32x4 acc[2][8] = {};
  float l_i[2][4] = {};

  const int kr = tid >> 4;
  const int kc = (tid & 15) * 8;
  const float sgnk = (kc < 64) ? -1.f : 1.f;
  const int tp = tid & 63;

  for (int j = 0; j < T / 64; ++j) {
    const int t0 = j * 64;
#pragma unroll
    for (int it = 0; it < 4; ++it) {
      const int row = it * 16 + kr;
      const int tg = t0 + row;
      const bf16_t* krow = qkv + ((size_t)(b * T + tg)) * 6144 + 2048 + h * 128;
      const bf16x8 kv = *(const bf16x8*)(krow + kc);
      const bf16x8 kp = *(const bf16x8*)(krow + (kc ^ 64));
      const bf16x8 cv = *(const bf16x8*)(cosb + tg * 128 + kc);
      const bf16x8 sv = *(const bf16x8*)(sinb + tg * 128 + kc);
      bf16x8 o;
#pragma unroll
      for (int jj = 0; jj < 8; ++jj)
        o[jj] = (bf16_t)(((float)kv[jj]) * ((float)cv[jj]) +
                         sgnk * ((float)kp[jj]) * ((float)sv[jj]));
      *(bf16x8*)(&Ks[row][kc]) = o;
    }
#pragma unroll
    for (int cc = 0; cc < 4; ++cc) {
      const int d8 = (cc * 4 + (tid >> 6)) * 8;
      const bf16x8 vv = *(const bf16x8*)(qkv + ((size_t)(b * T + t0 + tp)) * 6144 +
                                         4096 + h * 128 + d8);
#pragma unroll
      for (int jj = 0; jj < 8; ++jj) Vs[d8 + jj][tp] = vv[jj];
    }
    __syncthreads();

    f32x4 sacc[2][4] = {};
#pragma unroll
    for (int ks = 0; ks < 4; ++ks) {
#pragma unroll
      for (int n = 0; n < 4; ++n) {
        const bf16x8 kf = *(const bf16x8*)(&Ks[n * 16 + fr][ks * 32 + fg * 8]);
        sacc[0][n] = MFMA16(qf[0][ks], kf, sacc[0][n]);
        sacc[1][n] = MFMA16(qf[1][ks], kf, sacc[1][n]);
      }
    }

#pragma unroll
    for (int i = 0; i < 2; ++i) {
#pragma unroll
      for (int r = 0; r < 4; ++r) {
        const float p0 = __expf(sacc[i][0][r]);
        const float p1 = __expf(sacc[i][1][r]);
        const float p2 = __expf(sacc[i][2][r]);
        const float p3 = __expf(sacc[i][3][r]);
        l_i[i][r] += (p0 + p1) + (p2 + p3);
        const int prow = wave * 32 + i * 16 + fg * 4 + r;
        Ps[prow][0 + fr] = (bf16_t)p0;
        Ps[prow][16 + fr] = (bf16_t)p1;
        Ps[prow][32 + fr] = (bf16_t)p2;
        Ps[prow][48 + fr] = (bf16_t)p3;
      }
    }

#pragma unroll
    for (int ks = 0; ks < 2; ++ks) {
      const bf16x8 pf0 = *(const bf16x8*)(&Ps[wave * 32 + fr][ks * 32 + fg * 8]);
      const bf16x8 pf1 = *(const bf16x8*)(&Ps[wave * 32 + 16 + fr][ks * 32 + fg * 8]);
#pragma unroll
      for (int n = 0; n < 8; ++n) {
        const bf16x8 vf = *(const bf16x8*)(&Vs[n * 16 + fr][ks * 32 + fg * 8]);
        acc[0][n] = MFMA16(pf0, vf, acc[0][n]);
        acc[1][n] = MFMA16(pf1, vf, acc[1][n]);
      }
    }
    __syncthreads();
  }

#pragma unroll
  for (int i = 0; i < 2; ++i) {
#pragma unroll
    for (int r = 0; r < 4; ++r) {
      float l = l_i[i][r];
#pragma unroll
      for (int msk = 1; msk < 16; msk <<= 1) l += __shfl_xor(l, msk, 64);
      const float inv = 1.0f / l;
      const int t = qt * 128 + wave * 32 + i * 16 + fg * 4 + r;
      bf16_t* yrow = Y + (size_t)(b * T + t) * 2048 + h * 128;
#pragma unroll
      for (int n = 0; n < 8; ++n)
        yrow[n * 16 + fr] = (bf16_t)(acc[i][n][r] * inv);
    }
  }
}

// ---------------------------------------------------------------------------
extern "C" void kernel_launch(void* const* d_in, const int* in_sizes, int n_in,
                              void* d_out, int out_size, void* d_ws, size_t ws_size,
                              hipStream_t stream) {
  const float* x = (const float*)d_in[0];
  const float* cosi = (const float*)d_in[1];
  const float* sini = (const float*)d_in[2];
  const float* Wqkv = (const float*)d_in[3];
  const float* Wproj = (const float*)d_in[4];

  const size_t NEED_FAST = sizeof(bf16_t) *
      ((size_t)12582912 + 262144 + 262144 + 25165824 + 8388608 + 8388608);
  const size_t NEED_BASE = 256 + sizeof(bf16_t) *
      ((size_t)12582912 + 4194304 + 262144 + 262144 + 25165824);

  if (ws_size >= NEED_FAST) {
    bf16_t* base = (bf16_t*)d_ws;
    bf16_t* WqkvT = base;                    // dead after gemm1
    bf16_t* y = base;                        // alias
    bf16_t* cosb = base + 12582912;
    bf16_t* sinb = cosb + 262144;
    bf16_t* qkv = sinb + 262144;             // live through flash
    bf16_t* WprojT = qkv;                    // alias head, written after flash
    bf16_t* Kr = qkv + 25165824;
    bf16_t* xb = Kr;                         // alias: x-bf16, dead before rope_k
    bf16_t* Vt = Kr + 8388608;

    conv_vec_f32<<<128, 256, 0, stream>>>(cosi, cosb, 32768);
    conv_vec_f32<<<128, 256, 0, stream>>>(sini, sinb, 32768);
    conv_vec_f32<<<4096, 256, 0, stream>>>(x, xb, 1048576);  // x -> bf16
    conv_transpose_f32<<<dim3(96, 32), 256, 0, stream>>>(Wqkv, WqkvT, 2048, 6144);
    gemm8k<false><<<512, 512, 0, stream>>>(xb, WqkvT, qkv, 4096, 6144, 2048, 32);
    rope_k<<<4096, 256, 0, stream>>>(qkv, cosb, sinb, Kr);  // overwrites xb (dead)
    transpose_v<<<dim3(32, 2, 32), 256, 0, stream>>>(qkv, Vt);
    flash_q128d<<<dim3(16, 32), 256, 0, stream>>>(qkv, cosb, sinb, Kr, Vt, y);
    conv_transpose_f32<<<dim3(32, 32), 256, 0, stream>>>(Wproj, WprojT, 2048, 2048);
    gemm8n<true><<<256, 512, 0, stream>>>(y, WprojT, d_out, 4096, 2048, 2048, 8);
  } else if (ws_size >= NEED_BASE) {
    bf16_t* base = (bf16_t*)((char*)d_ws + 256);
    bf16_t* WqkvT = base;
    bf16_t* y = base;
    bf16_t* WprojT = base + 12582912;
    bf16_t* cosb = WprojT + 4194304;
    bf16_t* sinb = cosb + 262144;
    bf16_t* qkv = sinb + 262144;

    conv_vec_f32<<<128, 256, 0, stream>>>(cosi, cosb, 32768);
    conv_vec_f32<<<128, 256, 0, stream>>>(sini, sinb, 32768);
    conv_transpose_f32<<<dim3(96, 32), 256, 0, stream>>>(Wqkv, WqkvT, 2048, 6144);
    gemm_t<true, false><<<dim3(32, 48), 256, 0, stream>>>(x, WqkvT, qkv, 4096, 6144, 2048);
    flash_fused_v2<<<dim3(16, 32), 256, 0, stream>>>(qkv, cosb, sinb, y);
    conv_transpose_f32<<<dim3(32, 32), 256, 0, stream>>>(Wproj, WprojT, 2048, 2048);
    gemm_t<false, true><<<dim3(32, 16), 256, 0, stream>>>(y, WprojT, d_out, 4096, 2048, 2048);
  } else {
    fill_diag<<<(out_size + 255) / 256, 256, 0, stream>>>((uint32_t*)d_out, out_size);
  }
}

// Round 11
// 384.374 us; speedup vs baseline: 1.8038x; 1.0229x over previous
//
#include <hip/hip_runtime.h>
#include <cstdint>
#include <cstddef>

typedef __bf16 bf16_t;
typedef __bf16 bf16x8 __attribute__((ext_vector_type(8)));
typedef __bf16 bf16x4 __attribute__((ext_vector_type(4)));
typedef float f32x4 __attribute__((ext_vector_type(4)));

#define MFMA16(a, b, c) __builtin_amdgcn_mfma_f32_16x16x32_bf16(a, b, c, 0, 0, 0)

// async global->LDS, 16B per lane. LDS dest = wave-uniform base + lane*16.
__device__ __forceinline__ void gll16(const bf16_t* g, bf16_t* l) {
  __builtin_amdgcn_global_load_lds(
      (__attribute__((address_space(1))) uint32_t*)((uintptr_t)g),
      (__attribute__((address_space(3))) uint32_t*)((uint32_t)(uintptr_t)l),
      16, 0, 0);
}

// Diagnostic: absmax ~1000 => ws_size too small.
__global__ void fill_diag(uint32_t* out, int n_u32) {
  int i = blockIdx.x * 256 + threadIdx.x;
  if (i < n_u32) out[i] = 0x447A0000u;  // f32 1000.0
}

// ---------------------------------------------------------------------------
// f32 -> bf16 vector convert (x, cos/sin tables). One bf16x8 per thread.
// ---------------------------------------------------------------------------
__global__ void conv_vec_f32(const float* __restrict__ in, bf16_t* __restrict__ out,
                             int n8) {
  const int i = blockIdx.x * 256 + threadIdx.x;
  if (i >= n8) return;
  const float* p = in + (size_t)i * 8;
  const f32x4 a = *(const f32x4*)p;
  const f32x4 b = *(const f32x4*)(p + 4);
  bf16x8 o;
#pragma unroll
  for (int j = 0; j < 4; ++j) {
    o[j] = (bf16_t)a[j];
    o[4 + j] = (bf16_t)b[j];
  }
  ((bf16x8*)out)[i] = o;
}

// ---------------------------------------------------------------------------
// 64x64 tiled transpose+convert: in R x C f32 -> out C x R bf16.
// ---------------------------------------------------------------------------
__global__ __launch_bounds__(256) void conv_transpose_f32(
    const float* __restrict__ in, bf16_t* __restrict__ out, int R, int C) {
  __shared__ bf16_t tile[64][72];
  const int bc = blockIdx.x * 64;
  const int br = blockIdx.y * 64;
  const int t = threadIdx.x;
  const int r = t >> 3;
  const int c8 = (t & 7) * 8;
#pragma unroll
  for (int ii = 0; ii < 2; ++ii) {
    const int rr = r + ii * 32;
    const float* p = in + (size_t)(br + rr) * C + bc + c8;
    const f32x4 a = *(const f32x4*)p;
    const f32x4 b = *(const f32x4*)(p + 4);
    bf16x8 v;
#pragma unroll
    for (int j = 0; j < 4; ++j) {
      v[j] = (bf16_t)a[j];
      v[4 + j] = (bf16_t)b[j];
    }
    *(bf16x8*)(&tile[rr][c8]) = v;
  }
  __syncthreads();
#pragma unroll
  for (int ii = 0; ii < 2; ++ii) {
    const int rr = r + ii * 32;
    bf16x8 o;
#pragma unroll
    for (int jj = 0; jj < 8; ++jj) o[jj] = tile[c8 + jj][rr];
    *(bf16x8*)(out + (size_t)(bc + rr) * R + br + c8) = o;
  }
}

// ---------------------------------------------------------------------------
// gemm8: 256x256-tile 8-phase GEMM (measured in-block ~1110 TF). N arg is the
// C leading dimension; nbn sets how many 256-col tiles this launch covers.
// Round-11: used for the N in [0,4096) slab of qkv (grid 256 = 1 exact round).
// ---------------------------------------------------------------------------
#define MF8(MLO, AARR, BARR, NLO)                                              \
  do {                                                                         \
    _Pragma("unroll") for (int k_ = 0; k_ < 2; ++k_) {                         \
      _Pragma("unroll") for (int m_ = 0; m_ < 4; ++m_) {                       \
        _Pragma("unroll") for (int n_ = 0; n_ < 2; ++n_) {                     \
          acc[(MLO) + m_][(NLO) + n_] = MFMA16(AARR[m_][k_], BARR[n_][k_],     \
                                               acc[(MLO) + m_][(NLO) + n_]);   \
        }                                                                      \
      }                                                                        \
    }                                                                          \
  } while (0)

template <bool C32>
__global__ __launch_bounds__(512, 2) void gemm8(
    const bf16_t* __restrict__ A, const bf16_t* __restrict__ Bt,
    void* __restrict__ C, int M, int N, int K, int nbn) {
  __shared__ __align__(1024) bf16_t lds8[65536];  // A: [0,32768), B: [32768,65536)
  bf16_t* As = lds8;
  bf16_t* Bs = lds8 + 32768;

  const int tid = threadIdx.x;
  const int lane = tid & 63;
  const int wave = tid >> 6;
  const int wr = wave >> 2;  // 0..1 (M half)
  const int wc = wave & 3;   // 0..3 (N quarter)
  const int fr = lane & 15;
  const int fg = lane >> 4;

  // XCD-aware bijective swizzle (nwg % 8 == 0 by construction).
  const int nwg = gridDim.x;
  const int bid = blockIdx.x;
  const int swz = (bid & 7) * (nwg >> 3) + (bid >> 3);
  const int m0 = (swz / nbn) * 256;
  const int n0 = (swz % nbn) * 256;

  const int NT = K >> 6;  // BK=64 tiles

  // staging geometry: wave covers segs {2w, 2w+1}; seg = 8 rows of 128B.
  const int sseg0 = wave * 2;
  const int srow = lane >> 3;
  const int sj = lane & 7;

  auto stage = [&](const bf16_t* __restrict__ G, int row0, bf16_t* L, int kt,
                   int h) {
#pragma unroll
    for (int l = 0; l < 2; ++l) {
      const int seg = sseg0 + l;
      const int r = seg * 8 + srow;       // row in half-tile 0..127
      const int j = sj ^ (r & 7);         // inverse-swizzled source chunk
      const bf16_t* src = G + (size_t)(row0 + h * 128 + r) * K + kt * 64 + j * 8;
      gll16(src, L + ((2 * kt + h) & 3) * 8192 + seg * 512 + lane * 8);
    }
  };

  const int cb0 = (fg * 16) ^ ((fr & 7) << 4);  // kk=0 byte col (swizzled)

  auto lda = [&](bf16x8(&af)[4][2], int kt, int mlo) {
    const char* base = (const char*)(As + ((2 * kt + wr) & 3) * 8192);
#pragma unroll
    for (int m = 0; m < 4; ++m) {
      const char* p = base + ((mlo + m) * 16 + fr) * 128;
      af[m][0] = *(const bf16x8*)(p + cb0);
      af[m][1] = *(const bf16x8*)(p + (cb0 ^ 64));
    }
  };
  auto ldb = [&](bf16x8(&bf)[2][2], int kt, int nlo) {
    const char* base = (const char*)(Bs + ((2 * kt + (wc >> 1)) & 3) * 8192);
#pragma unroll
    for (int n = 0; n < 2; ++n) {
      const char* p = base + ((wc & 1) * 64 + (nlo + n) * 16 + fr) * 128;
      bf[n][0] = *(const bf16x8*)(p + cb0);
      bf[n][1] = *(const bf16x8*)(p + (cb0 ^ 64));
    }
  };

  f32x4 acc[8][4] = {};

  // Prologue: A(0), B(0), B(1); drain A(0)+B(0), keep B(1) in flight.
  stage(A, m0, As, 0, 0);
  stage(A, m0, As, 0, 1);
  stage(Bt, n0, Bs, 0, 0);
  stage(Bt, n0, Bs, 0, 1);
  stage(Bt, n0, Bs, 1, 0);
  stage(Bt, n0, Bs, 1, 1);
  asm volatile("s_waitcnt vmcnt(4)" ::: "memory");
  __builtin_amdgcn_s_barrier();

  bf16x8 af[4][2], bfA[2][2], bfB[2][2];

  for (int u = 0; u < NT; u += 2) {
    const bool st2 = (u + 2 < NT);
    const bool st3 = (u + 3 < NT);
    // ---------------- tile u ----------------
    lda(af, u, 0);
    ldb(bfA, u, 0);
    stage(A, m0, As, u + 1, 0);
    asm volatile("s_waitcnt lgkmcnt(8)" ::: "memory");
    __builtin_amdgcn_s_barrier();
    asm volatile("s_waitcnt lgkmcnt(0)" ::: "memory");
    __builtin_amdgcn_sched_barrier(0);
    __builtin_amdgcn_s_setprio(1);
    MF8(0, af, bfA, 0);
    __builtin_amdgcn_s_setprio(0);
    __builtin_amdgcn_s_barrier();
    ldb(bfB, u, 2);
    stage(A, m0, As, u + 1, 1);
    __builtin_amdgcn_s_barrier();
    asm volatile("s_waitcnt lgkmcnt(0)" ::: "memory");
    __builtin_amdgcn_sched_barrier(0);
    __builtin_amdgcn_s_setprio(1);
    MF8(0, af, bfB, 2);
    __builtin_amdgcn_s_setprio(0);
    __builtin_amdgcn_s_barrier();
    lda(af, u, 4);
    if (st2) stage(Bt, n0, Bs, u + 2, 0);
    __builtin_amdgcn_s_barrier();
    asm volatile("s_waitcnt lgkmcnt(0)" ::: "memory");
    __builtin_amdgcn_sched_barrier(0);
    __builtin_amdgcn_s_setprio(1);
    MF8(4, af, bfB, 2);
    __builtin_amdgcn_s_setprio(0);
    __builtin_amdgcn_s_barrier();
    if (st2) stage(Bt, n0, Bs, u + 2, 1);
    __builtin_amdgcn_s_barrier();
    __builtin_amdgcn_s_setprio(1);
    MF8(4, af, bfA, 0);
    __builtin_amdgcn_s_setprio(0);
    asm volatile("s_waitcnt vmcnt(4)" ::: "memory");
    __builtin_amdgcn_s_barrier();
    // ---------------- tile u+1 ----------------
    lda(af, u + 1, 0);
    ldb(bfA, u + 1, 0);
    if (st2) stage(A, m0, As, u + 2, 0);
    asm volatile("s_waitcnt lgkmcnt(8)" ::: "memory");
    __builtin_amdgcn_s_barrier();
    asm volatile("s_waitcnt lgkmcnt(0)" ::: "memory");
    __builtin_amdgcn_sched_barrier(0);
    __builtin_amdgcn_s_setprio(1);
    MF8(0, af, bfA, 0);
    __builtin_amdgcn_s_setprio(0);
    __builtin_amdgcn_s_barrier();
    ldb(bfB, u + 1, 2);
    if (st2) stage(A, m0, As, u + 2, 1);
    __builtin_amdgcn_s_barrier();
    asm volatile("s_waitcnt lgkmcnt(0)" ::: "memory");
    __builtin_amdgcn_sched_barrier(0);
    __builtin_amdgcn_s_setprio(1);
    MF8(0, af, bfB, 2);
    __builtin_amdgcn_s_setprio(0);
    __builtin_amdgcn_s_barrier();
    lda(af, u + 1, 4);
    if (st3) stage(Bt, n0, Bs, u + 3, 0);
    __builtin_amdgcn_s_barrier();
    asm volatile("s_waitcnt lgkmcnt(0)" ::: "memory");
    __builtin_amdgcn_sched_barrier(0);
    __builtin_amdgcn_s_setprio(1);
    MF8(4, af, bfB, 2);
    __builtin_amdgcn_s_setprio(0);
    __builtin_amdgcn_s_barrier();
    if (st3) stage(Bt, n0, Bs, u + 3, 1);
    __builtin_amdgcn_s_barrier();
    __builtin_amdgcn_s_setprio(1);
    MF8(4, af, bfA, 0);
    __builtin_amdgcn_s_setprio(0);
    asm volatile("s_waitcnt vmcnt(4)" ::: "memory");
    __builtin_amdgcn_s_barrier();
  }

#pragma unroll
  for (int m = 0; m < 8; ++m) {
#pragma unroll
    for (int n = 0; n < 4; ++n) {
#pragma unroll
      for (int r = 0; r < 4; ++r) {
        const int row = m0 + wr * 128 + m * 16 + fg * 4 + r;
        const int col = n0 + wc * 64 + n * 16 + fr;
        const size_t idx = (size_t)row * N + col;
        if (C32)
          ((float*)C)[idx] = acc[m][n][r];
        else
          ((bf16_t*)C)[idx] = (bf16_t)acc[m][n][r];
      }
    }
  }
  (void)M;
}

// ---------------------------------------------------------------------------
// gemm8n: 128x256-tile 2-phase GEMM. N arg is the C leading dimension; the
// launch covers nbn 256-col tiles starting at the (pre-offset) Bt/C pointers.
// Used for: qkv N in [4096,6144) slab (grid 256 = 1 exact round) and proj.
// ---------------------------------------------------------------------------
template <bool C32>
__global__ __launch_bounds__(512, 2) void gemm8n(
    const bf16_t* __restrict__ A, const bf16_t* __restrict__ Bt,
    void* __restrict__ C, int M, int N, int K, int nbn) {
  __shared__ __align__(1024) bf16_t lds8[65536];  // A: 3x8192, B: 5x8192 (bf16)
  bf16_t* As = lds8;           // 3 slots * 8192 el
  bf16_t* Bs = lds8 + 24576;   // 5 slots * 8192 el

  const int tid = threadIdx.x;
  const int lane = tid & 63;
  const int wave = tid >> 6;
  const int wr = wave >> 2;
  const int wc = wave & 3;
  const int fr = lane & 15;
  const int fg = lane >> 4;

  const int nwg = gridDim.x;
  const int bid = blockIdx.x;
  const int swz = (bid & 7) * (nwg >> 3) + (bid >> 3);
  const int m0 = (swz / nbn) * 128;
  const int n0 = (swz % nbn) * 256;

  const int NT = K >> 6;

  const int srow = tid >> 3;  // 0..63
  const int sj = tid & 7;

  auto stage = [&](const bf16_t* __restrict__ G, int grow0, bf16_t* slotBase,
                   int kt) {
#pragma unroll
    for (int l = 0; l < 2; ++l) {
      const int r = l * 64 + srow;
      const int j = sj ^ (r & 7);
      gll16(G + (size_t)(grow0 + r) * K + kt * 64 + j * 8,
            slotBase + l * 4096 + tid * 8);
    }
  };

  const int cb0 = (fg * 16) ^ ((fr & 7) << 4);

  auto lda = [&](bf16x8(&af)[4][2], int t) {
    const char* base = (const char*)(As + (t % 3) * 8192);
#pragma unroll
    for (int m = 0; m < 4; ++m) {
      const char* p = base + (wr * 64 + m * 16 + fr) * 128;
      af[m][0] = *(const bf16x8*)(p + cb0);
      af[m][1] = *(const bf16x8*)(p + (cb0 ^ 64));
    }
  };
  auto ldb2 = [&](bf16x8(&bf)[2][2], int t, int nlo) {
    const char* base = (const char*)(Bs + ((2 * t + (wc >> 1)) % 5) * 8192);
#pragma unroll
    for (int n = 0; n < 2; ++n) {
      const char* p = base + ((wc & 1) * 64 + (nlo + n) * 16 + fr) * 128;
      bf[n][0] = *(const bf16x8*)(p + cb0);
      bf[n][1] = *(const bf16x8*)(p + (cb0 ^ 64));
    }
  };

  f32x4 acc[4][4] = {};

  stage(A, m0, As, 0);
  stage(A, m0, As + 8192, 1);
  stage(Bt, n0, Bs, 0);
  stage(Bt, n0 + 128, Bs + 8192, 0);
  stage(Bt, n0, Bs + 2 * 8192, 1);
  asm volatile("s_waitcnt vmcnt(2)" ::: "memory");
  __builtin_amdgcn_s_barrier();

  bf16x8 af[4][2], bf01[2][2], bf23[2][2];

  for (int t = 0; t < NT; ++t) {
    lda(af, t);
    ldb2(bf01, t, 0);
    if (t + 2 < NT) stage(Bt, n0, Bs + ((2 * t + 4) % 5) * 8192, t + 2);
    if (t + 1 < NT) stage(Bt, n0 + 128, Bs + ((2 * t + 3) % 5) * 8192, t + 1);
    asm volatile("s_waitcnt lgkmcnt(8)" ::: "memory");
    __builtin_amdgcn_s_barrier();
    asm volatile("s_waitcnt lgkmcnt(0)" ::: "memory");
    __builtin_amdgcn_sched_barrier(0);
    __builtin_amdgcn_s_setprio(1);
#pragma unroll
    for (int k = 0; k < 2; ++k)
#pragma unroll
      for (int m = 0; m < 4; ++m)
#pragma unroll
        for (int n = 0; n < 2; ++n)
          acc[m][n] = MFMA16(af[m][k], bf01[n][k], acc[m][n]);
    __builtin_amdgcn_s_setprio(0);
    __builtin_amdgcn_s_barrier();
    ldb2(bf23, t, 2);
    if (t + 2 < NT) stage(A, m0, As + ((t + 2) % 3) * 8192, t + 2);
    __builtin_amdgcn_s_barrier();
    asm volatile("s_waitcnt lgkmcnt(0)" ::: "memory");
    __builtin_amdgcn_sched_barrier(0);
    __builtin_amdgcn_s_setprio(1);
#pragma unroll
    for (int k = 0; k < 2; ++k)
#pragma unroll
      for (int m = 0; m < 4; ++m)
#pragma unroll
        for (int n = 0; n < 2; ++n)
          acc[m][n + 2] = MFMA16(af[m][k], bf23[n][k], acc[m][n + 2]);
    __builtin_amdgcn_s_setprio(0);
    if (t + 3 < NT) {
      asm volatile("s_waitcnt vmcnt(2)" ::: "memory");
    } else {
      asm volatile("s_waitcnt vmcnt(0)" ::: "memory");
    }
    __builtin_amdgcn_s_barrier();
  }

#pragma unroll
  for (int m = 0; m < 4; ++m) {
#pragma unroll
    for (int n = 0; n < 4; ++n) {
#pragma unroll
      for (int r = 0; r < 4; ++r) {
        const int row = m0 + wr * 64 + m * 16 + fg * 4 + r;
        const int col = n0 + wc * 64 + n * 16 + fr;
        const size_t idx = (size_t)row * N + col;
        if (C32)
          ((float*)C)[idx] = acc[m][n][r];
        else
          ((bf16_t*)C)[idx] = (bf16_t)acc[m][n][r];
      }
    }
  }
  (void)M;
}

// ---------------------------------------------------------------------------
// Register-staged GEMM (fallback path only): A f32 option, C f32 option.
// ---------------------------------------------------------------------------
template <bool A32, bool C32>
__global__ __launch_bounds__(256) void gemm_t(
    const void* __restrict__ A, const bf16_t* __restrict__ Bt,
    void* __restrict__ C, int M, int N, int K) {
  __shared__ bf16_t As[128 * 32];
  __shared__ bf16_t Bs[128 * 32];
  const int tid = threadIdx.x;
  const int lane = tid & 63;
  const int wave = tid >> 6;
  const int m0 = blockIdx.x * 128;
  const int n0 = blockIdx.y * 128;
  const int wm = (wave & 1) * 64;
  const int wn = (wave >> 1) * 64;
  const int fr = lane & 15;
  const int fk = (lane >> 4) * 8;

  f32x4 acc[4][4] = {};

  const size_t ea0 = (size_t)(m0 + (tid >> 2)) * K + (tid & 3) * 8;
  const bf16_t* gb = Bt + (size_t)(n0 + (tid >> 2)) * K + (tid & 3) * 8;
  bf16_t* lA = As + tid * 8;
  bf16_t* lB = Bs + tid * 8;
  const size_t half = (size_t)64 * K;

  for (int k0 = 0; k0 < K; k0 += 32) {
    bf16x8 ra0, ra1;
    if (A32) {
      const float* pa = (const float*)A + ea0 + k0;
      const f32x4 x0 = *(const f32x4*)pa;
      const f32x4 x1 = *(const f32x4*)(pa + 4);
      const f32x4 x2 = *(const f32x4*)(pa + half);
      const f32x4 x3 = *(const f32x4*)(pa + half + 4);
#pragma unroll
      for (int j = 0; j < 4; ++j) {
        ra0[j] = (bf16_t)x0[j];
        ra0[4 + j] = (bf16_t)x1[j];
        ra1[j] = (bf16_t)x2[j];
        ra1[4 + j] = (bf16_t)x3[j];
      }
    } else {
      const bf16_t* pa = (const bf16_t*)A + ea0 + k0;
      ra0 = *(const bf16x8*)pa;
      ra1 = *(const bf16x8*)(pa + half);
    }
    const bf16x8 rb0 = *(const bf16x8*)gb;
    const bf16x8 rb1 = *(const bf16x8*)(gb + half);
    gb += 32;
    __syncthreads();
    *(bf16x8*)lA = ra0;
    *(bf16x8*)(lA + 2048) = ra1;
    *(bf16x8*)lB = rb0;
    *(bf16x8*)(lB + 2048) = rb1;
    __syncthreads();
    bf16x8 af[4], bfr[4];
#pragma unroll
    for (int i = 0; i < 4; ++i)
      af[i] = *(const bf16x8*)(As + (wm + i * 16 + fr) * 32 + fk);
#pragma unroll
    for (int j = 0; j < 4; ++j)
      bfr[j] = *(const bf16x8*)(Bs + (wn + j * 16 + fr) * 32 + fk);
#pragma unroll
    for (int i = 0; i < 4; ++i)
#pragma unroll
      for (int j = 0; j < 4; ++j)
        acc[i][j] = MFMA16(af[i], bfr[j], acc[i][j]);
  }

  const int fg = lane >> 4;
#pragma unroll
  for (int i = 0; i < 4; ++i) {
#pragma unroll
    for (int j = 0; j < 4; ++j) {
#pragma unroll
      for (int r = 0; r < 4; ++r) {
        const int row = m0 + wm + i * 16 + fg * 4 + r;
        const int col = n0 + wn + j * 16 + fr;
        const size_t idx = (size_t)row * N + col;
        if (C32)
          ((float*)C)[idx] = acc[i][j][r];
        else
          ((bf16_t*)C)[idx] = (bf16_t)acc[i][j][r];
      }
    }
  }
}

// ---------------------------------------------------------------------------
// K rope extract: qkv (B*T,6144) -> Kr (B,H,T,D) bf16 rope'd.
// ---------------------------------------------------------------------------
__global__ __launch_bounds__(256) void rope_k(
    const bf16_t* __restrict__ qkv, const bf16_t* __restrict__ cosb,
    const bf16_t* __restrict__ sinb, bf16_t* __restrict__ Kr) {
  const int row = blockIdx.x;  // b*2048 + t
  const int t = row & 2047;
  const int b = row >> 11;
  const int idx = threadIdx.x * 8;
  const int h = idx >> 7;
  const int d = idx & 127;
  const float sgn = (d < 64) ? -1.f : 1.f;
  const bf16_t* base = qkv + (size_t)row * 6144 + 2048;
  const bf16x8 kv = *(const bf16x8*)(base + idx);
  const bf16x8 kp = *(const bf16x8*)(base + (idx ^ 64));
  const bf16x8 cv = *(const bf16x8*)(cosb + t * 128 + d);
  const bf16x8 sv = *(const bf16x8*)(sinb + t * 128 + d);
  bf16x8 o;
#pragma unroll
  for (int jj = 0; jj < 8; ++jj)
    o[jj] = (bf16_t)(((float)kv[jj]) * ((float)cv[jj]) +
                     sgn * ((float)kp[jj]) * ((float)sv[jj]));
  *(bf16x8*)(Kr + ((size_t)(b * 16 + h) * 2048 + t) * 128 + d) = o;
}

// ---------------------------------------------------------------------------
// V extract + transpose: qkv cols 4096.. -> Vt (B,H,D,T).
// ---------------------------------------------------------------------------
__global__ __launch_bounds__(256) void transpose_v(
    const bf16_t* __restrict__ qkv, bf16_t* __restrict__ Vt) {
  __shared__ bf16_t tile[64][72];
  const int bh = blockIdx.z;
  const int b = bh >> 4, h = bh & 15;
  const int t0 = blockIdx.x * 64;
  const int d0 = blockIdx.y * 64;
  const int t = threadIdx.x;
  const int r = t >> 3;
  const int c8 = (t & 7) * 8;
#pragma unroll
  for (int ii = 0; ii < 2; ++ii) {
    const int rr = r + ii * 32;
    *(bf16x8*)(&tile[rr][c8]) =
        *(const bf16x8*)(qkv + (size_t)(b * 2048 + t0 + rr) * 6144 + 4096 + h * 128 + d0 + c8);
  }
  __syncthreads();
#pragma unroll
  for (int ii = 0; ii < 2; ++ii) {
    const int rr = r + ii * 32;
    bf16x8 o;
#pragma unroll
    for (int jj = 0; jj < 8; ++jj) o[jj] = tile[c8 + jj][rr];
    *(bf16x8*)(Vt + ((size_t)bh * 128 + d0 + rr) * 2048 + t0 + c8) = o;
  }
}

// ---------------------------------------------------------------------------
// Flash (round-10 structure, kept): double-buffered Ks[2]/Vs[2], QBLK=128
// (q-per-wave=32), swapped QK^T, rule-#21 K swizzle, π-permuted Vs,
// in-register P, exp2 softmax, 1 barrier/iter.
// ---------------------------------------------------------------------------
__global__ __launch_bounds__(256, 2) void flash_q128d(
    const bf16_t* __restrict__ qkv, const bf16_t* __restrict__ cosb,
    const bf16_t* __restrict__ sinb, const bf16_t* __restrict__ Kr,
    const bf16_t* __restrict__ Vt, bf16_t* __restrict__ Y) {
  constexpr int T = 2048;
  __shared__ __align__(1024) bf16_t Ks[2 * 64 * 128];  // 2 swizzled slots
  __shared__ bf16_t Vs[2][128][72];                    // 2 π-permuted slots
  const int tid = threadIdx.x;
  const int lane = tid & 63;
  const int fr = lane & 15;
  const int fg = lane >> 4;
  const int qt = blockIdx.x;  // 0..15, 128 q-rows each
  const int bh = blockIdx.y;
  const int b = bh >> 4, h = bh & 15;
  const int wave = tid >> 6;

  // Q rope'd on the fly; scale = rsqrt(128) * log2(e) folded in.
  const bf16_t* qbase = qkv + (size_t)b * T * 6144 + h * 128;
  bf16x8 qf[2][4];
#pragma unroll
  for (int i = 0; i < 2; ++i) {
    const int trow = qt * 128 + wave * 32 + i * 16 + fr;
    const bf16_t* qrow = qbase + (size_t)trow * 6144;
#pragma unroll
    for (int ks = 0; ks < 4; ++ks) {
      const int d = ks * 32 + fg * 8;
      const float sgn = (d < 64) ? -1.f : 1.f;
      const bf16x8 qv = *(const bf16x8*)(qrow + d);
      const bf16x8 qp = *(const bf16x8*)(qrow + (d ^ 64));
      const bf16x8 cv = *(const bf16x8*)(cosb + trow * 128 + d);
      const bf16x8 sv = *(const bf16x8*)(sinb + trow * 128 + d);
      bf16x8 o;
#pragma unroll
      for (int jj = 0; jj < 8; ++jj)
        o[jj] = (bf16_t)((((float)qv[jj]) * ((float)cv[jj]) +
                          sgn * ((float)qp[jj]) * ((float)sv[jj])) *
                         0.1275174825f);  // (1/sqrt(128)) * log2(e)
      qf[i][ks] = o;
    }
  }

  f32x4 acc[2][8] = {};
  float l_i[2] = {0.f, 0.f};

  const int krow = tid >> 4;                    // 0..15
  const int sc = (tid & 15) ^ (krow & 7);       // pre-swizzled source chunk
  const int vrow = tid >> 3;        // 0..31 (d rows, +32*it)
  const int vu = tid & 7;           // t-chunk index (8 consecutive t)
  const int vc0 = ((vu >> 2) * 32) + ((vu & 1) * 16) + (((vu >> 1) & 1) * 4);
  const bf16_t* Kh = Kr + (size_t)bh * T * 128;
  const bf16_t* Vh = Vt + (size_t)bh * 128 * T;

  auto stageK = [&](int t0, int s) {
#pragma unroll
    for (int it = 0; it < 4; ++it)
      gll16(Kh + (size_t)(t0 + it * 16 + krow) * 128 + sc * 8,
            Ks + s * 8192 + it * 2048 + tid * 8);
  };
  bf16x8 vreg[4];
  auto loadV = [&](int t0) {
#pragma unroll
    for (int it = 0; it < 4; ++it)
      vreg[it] = *(const bf16x8*)(Vh + (size_t)(it * 32 + vrow) * T + t0 + vu * 8);
  };
  auto writeV = [&](int s) {
#pragma unroll
    for (int it = 0; it < 4; ++it) {
      const int row = it * 32 + vrow;
      const bf16x8 v = vreg[it];
      bf16x4 lo, hi;
#pragma unroll
      for (int jj = 0; jj < 4; ++jj) {
        lo[jj] = v[jj];
        hi[jj] = v[4 + jj];
      }
      *(bf16x4*)(&Vs[s][row][vc0]) = lo;      // t = base+0..3  (b2=0)
      *(bf16x4*)(&Vs[s][row][vc0 + 8]) = hi;  // t = base+4..7  (b2=1)
    }
  };

  // prologue: stage tile 0 into slot 0
  stageK(0, 0);
  loadV(0);
  asm volatile("s_waitcnt vmcnt(0)" ::: "memory");
  __builtin_amdgcn_sched_barrier(0);
  writeV(0);
  __syncthreads();

  const int cswz = (fr & 7) << 4;  // read-side XOR for Ks
  const char* kbase0 = (const char*)Ks;

  for (int j = 0; j < T / 64; ++j) {
    const int cur = j & 1;
    const int nxt = cur ^ 1;
    const bool more = (j + 1 < T / 64);
    // issue next tile's K DMA (into slot nxt) + V reg loads EARLY: latency
    // hides under this whole iteration's QK^T + exp + PV.
    if (more) {
      stageK((j + 1) * 64, nxt);
      loadV((j + 1) * 64);
    }

    // QK^T swapped: lane holds P[q=fr][k=n*16+fg*4+r]; kf reused for i=0,1.
    const char* kbase = kbase0 + cur * 16384;
    f32x4 sacc[2][4] = {};
#pragma unroll
    for (int ks = 0; ks < 4; ++ks) {
#pragma unroll
      for (int n = 0; n < 4; ++n) {
        const bf16x8 kf = *(const bf16x8*)(kbase + (n * 16 + fr) * 256 +
                                           ((ks * 64 + fg * 16) ^ cswz));
        sacc[0][n] = MFMA16(kf, qf[0][ks], sacc[0][n]);
        sacc[1][n] = MFMA16(kf, qf[1][ks], sacc[1][n]);
      }
    }

    // exp + in-register pack into PV A-fragments.
    bf16x8 paf[2][2];
#pragma unroll
    for (int i = 0; i < 2; ++i) {
      float lsum = 0.f;
#pragma unroll
      for (int ks2 = 0; ks2 < 2; ++ks2) {
#pragma unroll
        for (int jj = 0; jj < 8; ++jj) {
          const float p = exp2f(sacc[i][ks2 * 2 + (jj >> 2)][jj & 3]);
          lsum += p;
          paf[i][ks2][jj] = (bf16_t)p;
        }
      }
      l_i[i] += lsum;
    }

    // PV: vf reused for i=0,1; Vs column order matches paf's k order.
#pragma unroll
    for (int ks2 = 0; ks2 < 2; ++ks2) {
#pragma unroll
      for (int n = 0; n < 8; ++n) {
        const bf16x8 vf =
            *(const bf16x8*)(&Vs[cur][n * 16 + fr][ks2 * 32 + fg * 8]);
        acc[0][n] = MFMA16(paf[0][ks2], vf, acc[0][n]);
        acc[1][n] = MFMA16(paf[1][ks2], vf, acc[1][n]);
      }
    }

    if (more) {
      asm volatile("s_waitcnt vmcnt(0)" ::: "memory");  // K DMA + V regs landed
      __builtin_amdgcn_sched_barrier(0);
      writeV(nxt);  // distinct slot: no reader until after the barrier
    }
    __syncthreads();  // all waves done with cur; nxt fully populated
  }

  // epilogue: l reduce across fg groups, then fetch 1/l per output row.
#pragma unroll
  for (int i = 0; i < 2; ++i) {
    float l = l_i[i];
    l += __shfl_xor(l, 16, 64);
    l += __shfl_xor(l, 32, 64);  // lanes with same fr now hold l_full(q=fr)
#pragma unroll
    for (int r = 0; r < 4; ++r) {
      const float inv = 1.0f / __shfl(l, fg * 4 + r, 64);
      const int t = qt * 128 + wave * 32 + i * 16 + fg * 4 + r;
      bf16_t* yrow = Y + (size_t)(b * T + t) * 2048 + h * 128;
#pragma unroll
      for (int n = 0; n < 8; ++n)
        yrow[n * 16 + fr] = (bf16_t)(acc[i][n][r] * inv);
    }
  }
}

// ---------------------------------------------------------------------------
// Flash fallback (ws-lean): fused rope, exp-only softmax. (unchanged)
// ---------------------------------------------------------------------------
__global__ __launch_bounds__(256) void flash_fused_v2(
    const bf16_t* __restrict__ qkv, const bf16_t* __restrict__ cosb,
    const bf16_t* __restrict__ sinb, bf16_t* __restrict__ Y) {
  constexpr int T = 2048;
  __shared__ bf16_t Ks[64][136];
  __shared__ bf16_t Vs[128][72];
  __shared__ bf16_t Ps[128][72];
  const int tid = threadIdx.x;
  const int lane = tid & 63;
  const int wave = tid >> 6;
  const int fr = lane & 15;
  const int fg = lane >> 4;
  const int qt = blockIdx.x;
  const int bh = blockIdx.y;
  const int b = bh >> 4, h = bh & 15;

  const bf16_t* qbase = qkv + (size_t)b * T * 6144 + h * 128;
  bf16x8 qf[2][4];
#pragma unroll
  for (int i = 0; i < 2; ++i) {
    const int trow = qt * 128 + wave * 32 + i * 16 + fr;
    const bf16_t* qrow = qbase + (size_t)trow * 6144;
#pragma unroll
    for (int ks = 0; ks < 4; ++ks) {
      const int d = ks * 32 + fg * 8;
      const float sgn = (d < 64) ? -1.f : 1.f;
      const bf16x8 qv = *(const bf16x8*)(qrow + d);
      const bf16x8 qp = *(const bf16x8*)(qrow + (d ^ 64));
      const bf16x8 cv = *(const bf16x8*)(cosb + trow * 128 + d);
      const bf16x8 sv = *(const bf16x8*)(sinb + trow * 128 + d);
      bf16x8 o;
#pragma unroll
      for (int jj = 0; jj < 8; ++jj)
        o[jj] = (bf16_t)((((float)qv[jj]) * ((float)cv[jj]) +
                          sgn * ((float)qp[jj]) * ((float)sv[jj])) *
                         0.08838834764831845f);
      qf[i][ks] = o;
    }
  }

  f32x4 acc[2][8] = {};
  float l_i[2][4] = {};

  const int kr = tid >> 4;
  const int kc = (tid & 15) * 8;
  const float sgnk = (kc < 64) ? -1.f : 1.f;
  const int tp = tid & 63;

  for (int j = 0; j < T / 64; ++j) {
    const int t0 = j * 64;
#pragma unroll
    for (int it = 0; it < 4; ++it) {
      const int row = it * 16 + kr;
      const int tg = t0 + row;
      const bf16_t* krow = qkv + ((size_t)(b * T + tg)) * 6144 + 2048 + h * 128;
      const bf16x8 kv = *(const bf16x8*)(krow + kc);
      const bf16x8 kp = *(const bf16x8*)(krow + (kc ^ 64));
      const bf16x8 cv = *(const bf16x8*)(cosb + tg * 128 + kc);
      const bf16x8 sv = *(const bf16x8*)(sinb + tg * 128 + kc);
      bf16x8 o;
#pragma unroll
      for (int jj = 0; jj < 8; ++jj)
        o[jj] = (bf16_t)(((float)kv[jj]) * ((float)cv[jj]) +
                         sgnk * ((float)kp[jj]) * ((float)sv[jj]));
      *(bf16x8*)(&Ks[row][kc]) = o;
    }
#pragma unroll
    for (int cc = 0; cc < 4; ++cc) {
      const int d8 = (cc * 4 + (tid >> 6)) * 8;
      const bf16x8 vv = *(const bf16x8*)(qkv + ((size_t)(b * T + t0 + tp)) * 6144 +
                                         4096 + h * 128 + d8);
#pragma unroll
      for (int jj = 0; jj < 8; ++jj) Vs[d8 + jj][tp] = vv[jj];
    }
    __syncthreads();

    f32x4 sacc[2][4] = {};
#pragma unroll
    for (int ks = 0; ks < 4; ++ks) {
#pragma unroll
      for (int n = 0; n < 4; ++n) {
        const bf16x8 kf = *(const bf16x8*)(&Ks[n * 16 + fr][ks * 32 + fg * 8]);
        sacc[0][n] = MFMA16(qf[0][ks], kf, sacc[0][n]);
        sacc[1][n] = MFMA16(qf[1][ks], kf, sacc[1][n]);
      }
    }

#pragma unroll
    for (int i = 0; i < 2; ++i) {
#pragma unroll
      for (int r = 0; r < 4; ++r) {
        const float p0 = __expf(sacc[i][0][r]);
        const float p1 = __expf(sacc[i][1][r]);
        const float p2 = __expf(sacc[i][2][r]);
        const float p3 = __expf(sacc[i][3][r]);
        l_i[i][r] += (p0 + p1) + (p2 + p3);
        const int prow = wave * 32 + i * 16 + fg * 4 + r;
        Ps[prow][0 + fr] = (bf16_t)p0;
        Ps[prow][16 + fr] = (bf16_t)p1;
        Ps[prow][32 + fr] = (bf16_t)p2;
        Ps[prow][48 + fr] = (bf16_t)p3;
      }
    }

#pragma unroll
    for (int ks = 0; ks < 2; ++ks) {
      const bf16x8 pf0 = *(const bf16x8*)(&Ps[wave * 32 + fr][ks * 32 + fg * 8]);
      const bf16x8 pf1 = *(const bf16x8*)(&Ps[wave * 32 + 16 + fr][ks * 32 + fg * 8]);
#pragma unroll
      for (int n = 0; n < 8; ++n) {
        const bf16x8 vf = *(const bf16x8*)(&Vs[n * 16 + fr][ks * 32 + fg * 8]);
        acc[0][n] = MFMA16(pf0, vf, acc[0][n]);
        acc[1][n] = MFMA16(pf1, vf, acc[1][n]);
      }
    }
    __syncthreads();
  }

#pragma unroll
  for (int i = 0; i < 2; ++i) {
#pragma unroll
    for (int r = 0; r < 4; ++r) {
      float l = l_i[i][r];
#pragma unroll
      for (int msk = 1; msk < 16; msk <<= 1) l += __shfl_xor(l, msk, 64);
      const float inv = 1.0f / l;
      const int t = qt * 128 + wave * 32 + i * 16 + fg * 4 + r;
      bf16_t* yrow = Y + (size_t)(b * T + t) * 2048 + h * 128;
#pragma unroll
      for (int n = 0; n < 8; ++n)
        yrow[n * 16 + fr] = (bf16_t)(acc[i][n][r] * inv);
    }
  }
}

// ---------------------------------------------------------------------------
extern "C" void kernel_launch(void* const* d_in, const int* in_sizes, int n_in,
                              void* d_out, int out_size, void* d_ws, size_t ws_size,
                              hipStream_t stream) {
  const float* x = (const float*)d_in[0];
  const float* cosi = (const float*)d_in[1];
  const float* sini = (const float*)d_in[2];
  const float* Wqkv = (const float*)d_in[3];
  const float* Wproj = (const float*)d_in[4];

  const size_t NEED_FAST = sizeof(bf16_t) *
      ((size_t)12582912 + 262144 + 262144 + 25165824 + 8388608 + 8388608);
  const size_t NEED_BASE = 256 + sizeof(bf16_t) *
      ((size_t)12582912 + 4194304 + 262144 + 262144 + 25165824);

  if (ws_size >= NEED_FAST) {
    bf16_t* base = (bf16_t*)d_ws;
    bf16_t* WqkvT = base;                    // dead after gemm1
    bf16_t* y = base;                        // alias
    bf16_t* cosb = base + 12582912;
    bf16_t* sinb = cosb + 262144;
    bf16_t* qkv = sinb + 262144;             // live through flash
    bf16_t* WprojT = qkv;                    // alias head, written after flash
    bf16_t* Kr = qkv + 25165824;
    bf16_t* xb = Kr;                         // alias: x-bf16, dead before rope_k
    bf16_t* Vt = Kr + 8388608;

    conv_vec_f32<<<128, 256, 0, stream>>>(cosi, cosb, 32768);
    conv_vec_f32<<<128, 256, 0, stream>>>(sini, sinb, 32768);
    conv_vec_f32<<<4096, 256, 0, stream>>>(x, xb, 1048576);  // x -> bf16
    conv_transpose_f32<<<dim3(96, 32), 256, 0, stream>>>(Wqkv, WqkvT, 2048, 6144);
    // qkv GEMM split into two exact-one-round launches (round-11):
    //   slab 1: N in [0,4096) via gemm8 (256^2, in-block ~1110 TF), 256 blocks
    //   slab 2: N in [4096,6144) via gemm8n (128x256, block-time 44us), 256 blocks
    gemm8<false><<<256, 512, 0, stream>>>(xb, WqkvT, qkv, 4096, 6144, 2048, 16);
    gemm8n<false><<<256, 512, 0, stream>>>(xb, WqkvT + (size_t)4096 * 2048,
                                           qkv + 4096, 4096, 6144, 2048, 8);
    rope_k<<<4096, 256, 0, stream>>>(qkv, cosb, sinb, Kr);  // overwrites xb (dead)
    transpose_v<<<dim3(32, 2, 32), 256, 0, stream>>>(qkv, Vt);
    flash_q128d<<<dim3(16, 32), 256, 0, stream>>>(qkv, cosb, sinb, Kr, Vt, y);
    conv_transpose_f32<<<dim3(32, 32), 256, 0, stream>>>(Wproj, WprojT, 2048, 2048);
    gemm8n<true><<<256, 512, 0, stream>>>(y, WprojT, d_out, 4096, 2048, 2048, 8);
  } else if (ws_size >= NEED_BASE) {
    bf16_t* base = (bf16_t*)((char*)d_ws + 256);
    bf16_t* WqkvT = base;
    bf16_t* y = base;
    bf16_t* WprojT = base + 12582912;
    bf16_t* cosb = WprojT + 4194304;
    bf16_t* sinb = cosb + 262144;
    bf16_t* qkv = sinb + 262144;

    conv_vec_f32<<<128, 256, 0, stream>>>(cosi, cosb, 32768);
    conv_vec_f32<<<128, 256, 0, stream>>>(sini, sinb, 32768);
    conv_transpose_f32<<<dim3(96, 32), 256, 0, stream>>>(Wqkv, WqkvT, 2048, 6144);
    gemm_t<true, false><<<dim3(32, 48), 256, 0, stream>>>(x, WqkvT, qkv, 4096, 6144, 2048);
    flash_fused_v2<<<dim3(16, 32), 256, 0, stream>>>(qkv, cosb, sinb, y);
    conv_transpose_f32<<<dim3(32, 32), 256, 0, stream>>>(Wproj, WprojT, 2048, 2048);
    gemm_t<false, true><<<dim3(32, 16), 256, 0, stream>>>(y, WprojT, d_out, 4096, 2048, 2048);
  } else {
    fill_diag<<<(out_size + 255) / 256, 256, 0, stream>>>((uint32_t*)d_out, out_size);
  }
}